// Round 1
// baseline (698.806 us; speedup 1.0000x reference)
//
#include <hip/hip_runtime.h>
#include <cmath>

#define TEXTD 500
#define GNN_DIM 128

// ---------------- K1: fused text MLP (8 rows per block, 128 threads) ----------------
__global__ __launch_bounds__(128) void text_mlp_kernel(
    const float* __restrict__ text,
    const float* __restrict__ fc1_w, const float* __restrict__ fc1_b,
    const float* __restrict__ fc2_w, const float* __restrict__ fc2_b,
    const float* __restrict__ fc3_w, const float* __restrict__ fc3_b,
    const float* __restrict__ fc4_w, const float* __restrict__ fc4_b,
    const float* __restrict__ sc_w,  const float* __restrict__ sc_b,
    float* __restrict__ text_out, int M)
{
    __shared__ float tx[8][TEXTD];
    __shared__ float t1[8][128];
    __shared__ float t2[8][64];
    __shared__ float t3[8][16];
    const int tid = threadIdx.x;
    const int m0 = blockIdx.x * 8;

    for (int idx = tid; idx < 8 * TEXTD; idx += 128) {
        int r = idx / TEXTD, k = idx % TEXTD;
        int row = m0 + r;
        tx[r][k] = (row < M) ? text[(size_t)row * TEXTD + k] : 0.f;
    }
    __syncthreads();

    // fc1: 500 -> 128, thread j owns output column j for all 8 rows
    const int j = tid;
    float acc[8];
    {
        float b = fc1_b[j];
        #pragma unroll
        for (int r = 0; r < 8; r++) acc[r] = b;
    }
    for (int k = 0; k < TEXTD; k++) {
        float wv = fc1_w[k * 128 + j];
        #pragma unroll
        for (int r = 0; r < 8; r++) acc[r] = fmaf(tx[r][k], wv, acc[r]);
    }
    #pragma unroll
    for (int r = 0; r < 8; r++) t1[r][j] = fmaxf(acc[r], 0.f);

    // shortcut: 500 -> 16 ; thread -> (row = tid>>4, col = tid&15). reads tx only.
    const int rs = tid >> 4, cs = tid & 15;
    float scacc = sc_b[cs];
    for (int k = 0; k < TEXTD; k++)
        scacc = fmaf(tx[rs][k], sc_w[k * 16 + cs], scacc);
    __syncthreads();

    // fc2: 128 -> 64 ; thread -> (r2 = tid>>6 in {0,1}, c2 = tid&63), 4 row-pairs
    const int r2 = tid >> 6, c2 = tid & 63;
    for (int rb = 0; rb < 4; rb++) {
        int row = rb * 2 + r2;
        float a2 = fc2_b[c2];
        for (int k = 0; k < 128; k++) a2 = fmaf(t1[row][k], fc2_w[k * 64 + c2], a2);
        t2[row][c2] = fmaxf(a2, 0.f);
    }
    __syncthreads();

    // fc3: 64 -> 16
    float a3 = fc3_b[cs];
    for (int k = 0; k < 64; k++) a3 = fmaf(t2[rs][k], fc3_w[k * 16 + cs], a3);
    t3[rs][cs] = fmaxf(a3, 0.f);
    __syncthreads();

    // fc4: 16 -> 16, plus shortcut
    float a4 = fc4_b[cs];
    #pragma unroll
    for (int k = 0; k < 16; k++) a4 = fmaf(t3[rs][k], fc4_w[k * 16 + cs], a4);
    int row = m0 + rs;
    if (row < M) text_out[(size_t)row * 16 + cs] = a4 + scacc;
}

// ---------------- K2: h1 = x @ W1, plus per-node attention scalars ----------------
__global__ __launch_bounds__(128) void gat1_proj_kernel(
    const float* __restrict__ x, const float* __restrict__ W1,
    const float* __restrict__ att_src, const float* __restrict__ att_dst,
    float* __restrict__ h1, float* __restrict__ a_s, float* __restrict__ a_d, int N)
{
    __shared__ float xs[8][128];
    const int tid = threadIdx.x, j = tid;
    const int n0 = blockIdx.x * 8;

    for (int idx = tid; idx < 8 * 128; idx += 128) {
        int r = idx >> 7, k = idx & 127;
        int row = n0 + r;
        xs[r][k] = (row < N) ? x[(size_t)row * 128 + k] : 0.f;
    }
    __syncthreads();

    float acc[8];
    #pragma unroll
    for (int r = 0; r < 8; r++) acc[r] = 0.f;
    for (int k = 0; k < 128; k++) {
        float wv = W1[k * 128 + j];
        #pragma unroll
        for (int r = 0; r < 8; r++) acc[r] = fmaf(xs[r][k], wv, acc[r]);
    }

    const float atts = att_src[j], attd = att_dst[j];
    const int lane = tid & 63, head = tid >> 6;
    for (int r = 0; r < 8; r++) {
        int row = n0 + r;
        if (row < N) h1[(size_t)row * 128 + j] = acc[r];
        float ps = acc[r] * atts, pd = acc[r] * attd;
        #pragma unroll
        for (int off = 32; off > 0; off >>= 1) {
            ps += __shfl_down(ps, off, 64);
            pd += __shfl_down(pd, off, 64);
        }
        if (lane == 0 && row < N) {
            a_s[row * 2 + head] = ps;
            a_d[row * 2 + head] = pd;
        }
    }
}

// ---------------- K3: layer-1 edge scatter (2 edges / 256-thread block) ----------------
__global__ __launch_bounds__(256) void gat1_edge_kernel(
    const int* __restrict__ esrc, const int* __restrict__ edst,
    const float* __restrict__ h1, const float* __restrict__ a_s, const float* __restrict__ a_d,
    float* __restrict__ acc1, float* __restrict__ den1, int E, int EP)
{
    const int tid = threadIdx.x;
    const int eid = blockIdx.x * 2 + (tid >> 7);
    if (eid >= EP) return;
    const int d = tid & 127, head = d >> 6;
    int src, dst;
    if (eid < E) { src = esrc[eid]; dst = edst[eid]; }
    else         { src = dst = eid - E; }
    float e = a_s[src * 2 + head] + a_d[dst * 2 + head];
    float lr = e > 0.f ? e : 0.2f * e;
    float w = expf(lr);
    atomicAdd(&acc1[(size_t)dst * 128 + d], w * h1[(size_t)src * 128 + d]);
    if ((d & 63) == 0) atomicAdd(&den1[dst * 2 + head], w);
}

// ---------------- K4: g1 = relu(acc1/den1 + b1); h2 = g1 @ W2; attn scalars ----------------
__global__ __launch_bounds__(128) void gat2_proj_kernel(
    const float* __restrict__ acc1, const float* __restrict__ den1, const float* __restrict__ b1,
    const float* __restrict__ W2, const float* __restrict__ att_src2, const float* __restrict__ att_dst2,
    float* __restrict__ h2, float* __restrict__ a_s2, float* __restrict__ a_d2, int N)
{
    __shared__ float gs[8][128];
    const int tid = threadIdx.x, j = tid;
    const int n0 = blockIdx.x * 8;
    const float bj = b1[j];
    const int head = j >> 6;
    for (int r = 0; r < 8; r++) {
        int row = n0 + r;
        if (row < N) {
            float g = acc1[(size_t)row * 128 + j] / (den1[row * 2 + head] + 1e-16f) + bj;
            gs[r][j] = fmaxf(g, 0.f);
        } else gs[r][j] = 0.f;
    }
    __syncthreads();

    const int rs = tid >> 4, cs = tid & 15;
    float hacc = 0.f;
    for (int k = 0; k < 128; k++) hacc = fmaf(gs[rs][k], W2[k * 16 + cs], hacc);

    int row = n0 + rs;
    float ps = hacc * att_src2[cs], pd = hacc * att_dst2[cs];
    #pragma unroll
    for (int off = 8; off > 0; off >>= 1) {
        ps += __shfl_down(ps, off, 16);
        pd += __shfl_down(pd, off, 16);
    }
    if (row < N) {
        h2[(size_t)row * 16 + cs] = hacc;
        if (cs == 0) { a_s2[row] = ps; a_d2[row] = pd; }
    }
}

// ---------------- K5: layer-2 edge scatter (16 edges / 256-thread block) ----------------
__global__ __launch_bounds__(256) void gat2_edge_kernel(
    const int* __restrict__ esrc, const int* __restrict__ edst,
    const float* __restrict__ h2, const float* __restrict__ a_s2, const float* __restrict__ a_d2,
    float* __restrict__ acc2, float* __restrict__ den2, int E, int EP)
{
    const int tid = threadIdx.x;
    const int eid = blockIdx.x * 16 + (tid >> 4);
    if (eid >= EP) return;
    const int c = tid & 15;
    int src, dst;
    if (eid < E) { src = esrc[eid]; dst = edst[eid]; }
    else         { src = dst = eid - E; }
    float e = a_s2[src] + a_d2[dst];
    float lr = e > 0.f ? e : 0.2f * e;
    float w = expf(lr);
    atomicAdd(&acc2[(size_t)dst * 16 + c], w * h2[(size_t)src * 16 + c]);
    if (c == 0) atomicAdd(&den2[dst], w);
}

// ---------------- K6: fused head: concat -> fcf -> log_softmax ----------------
__global__ __launch_bounds__(64) void final_kernel(
    const float* __restrict__ text_out, const float* __restrict__ acc2,
    const float* __restrict__ den2, const float* __restrict__ b2,
    const int* __restrict__ mask,
    const float* __restrict__ fcf_w, const float* __restrict__ fcf_b,
    float* __restrict__ out, int M)
{
    const int lane = threadIdx.x;
    const int g = lane >> 4, j = lane & 15;
    const int m = blockIdx.x * 4 + g;
    if (m >= M) return;

    float tval = text_out[(size_t)m * 16 + j];
    int v = mask[m];
    float gval = acc2[(size_t)v * 16 + j] / (den2[v] + 1e-16f) + b2[j];

    float logit = fcf_b[j];
    #pragma unroll
    for (int k = 0; k < 16; k++) {
        logit = fmaf(__shfl(tval, k, 16), fcf_w[k * 16 + j], logit);
        logit = fmaf(__shfl(gval, k, 16), fcf_w[(16 + k) * 16 + j], logit);
    }
    float mx = logit;
    #pragma unroll
    for (int off = 8; off > 0; off >>= 1) mx = fmaxf(mx, __shfl_xor(mx, off, 16));
    float se = expf(logit - mx);
    #pragma unroll
    for (int off = 8; off > 0; off >>= 1) se += __shfl_xor(se, off, 16);
    out[(size_t)m * 16 + j] = logit - mx - logf(se);
}

extern "C" void kernel_launch(void* const* d_in, const int* in_sizes, int n_in,
                              void* d_out, int out_size, void* d_ws, size_t ws_size,
                              hipStream_t stream)
{
    const float* text  = (const float*)d_in[0];
    const float* x     = (const float*)d_in[1];
    const int*   ei    = (const int*)  d_in[2];
    const int*   mask  = (const int*)  d_in[3];
    const float* fc1_w = (const float*)d_in[4];  const float* fc1_b = (const float*)d_in[5];
    const float* fc2_w = (const float*)d_in[6];  const float* fc2_b = (const float*)d_in[7];
    const float* fc3_w = (const float*)d_in[8];  const float* fc3_b = (const float*)d_in[9];
    const float* fc4_w = (const float*)d_in[10]; const float* fc4_b = (const float*)d_in[11];
    const float* sc_w  = (const float*)d_in[12]; const float* sc_b  = (const float*)d_in[13];
    const float* W1    = (const float*)d_in[14];
    const float* as1w  = (const float*)d_in[15]; const float* ad1w  = (const float*)d_in[16];
    const float* b1    = (const float*)d_in[17];
    const float* W2    = (const float*)d_in[18];
    const float* as2w  = (const float*)d_in[19]; const float* ad2w  = (const float*)d_in[20];
    const float* b2    = (const float*)d_in[21];
    const float* fcf_w = (const float*)d_in[22]; const float* fcf_b = (const float*)d_in[23];

    const int M  = in_sizes[3];
    const int N  = in_sizes[1] / GNN_DIM;
    const int E  = in_sizes[2] / 2;
    const int EP = E + N;                 // with self-loops
    const int* esrc = ei;
    const int* edst = ei + E;

    float* ws = (float*)d_ws;
    size_t off = 0;
    auto alloc = [&](size_t n) { float* p = ws + off; off += (n + 63) & ~size_t(63); return p; };

    float* h1       = alloc((size_t)N * 128);
    float* a_s1     = alloc((size_t)2 * N);
    float* a_d1     = alloc((size_t)2 * N);
    float* h2       = alloc((size_t)N * 16);
    float* a_s2     = alloc(N);
    float* a_d2     = alloc(N);
    float* text_out = alloc((size_t)M * 16);
    // contiguous zero-init region
    float* zbase    = ws + off;
    float* acc1     = alloc((size_t)N * 128);
    float* den1     = alloc((size_t)2 * N);
    float* acc2     = alloc((size_t)N * 16);
    float* den2     = alloc(N);
    size_t zcount   = (size_t)((ws + off) - zbase);

    hipMemsetAsync(zbase, 0, zcount * sizeof(float), stream);

    text_mlp_kernel<<<(M + 7) / 8, 128, 0, stream>>>(
        text, fc1_w, fc1_b, fc2_w, fc2_b, fc3_w, fc3_b, fc4_w, fc4_b,
        sc_w, sc_b, text_out, M);

    gat1_proj_kernel<<<(N + 7) / 8, 128, 0, stream>>>(
        x, W1, as1w, ad1w, h1, a_s1, a_d1, N);

    gat1_edge_kernel<<<(EP + 1) / 2, 256, 0, stream>>>(
        esrc, edst, h1, a_s1, a_d1, acc1, den1, E, EP);

    gat2_proj_kernel<<<(N + 7) / 8, 128, 0, stream>>>(
        acc1, den1, b1, W2, as2w, ad2w, h2, a_s2, a_d2, N);

    gat2_edge_kernel<<<(EP + 15) / 16, 256, 0, stream>>>(
        esrc, edst, h2, a_s2, a_d2, acc2, den2, E, EP);

    final_kernel<<<(M + 3) / 4, 64, 0, stream>>>(
        text_out, acc2, den2, b2, mask, fcf_w, fcf_b, (float*)d_out, M);
}

// Round 2
// 503.201 us; speedup vs baseline: 1.3887x; 1.3887x over previous
//
#include <hip/hip_runtime.h>
#include <hip/hip_bf16.h>
#include <cmath>

#define TEXTD 500
#define GNN_DIM 128

// ---------------- K1: fused text MLP (8 rows per block, 128 threads) ----------------
__global__ __launch_bounds__(128) void text_mlp_kernel(
    const float* __restrict__ text,
    const float* __restrict__ fc1_w, const float* __restrict__ fc1_b,
    const float* __restrict__ fc2_w, const float* __restrict__ fc2_b,
    const float* __restrict__ fc3_w, const float* __restrict__ fc3_b,
    const float* __restrict__ fc4_w, const float* __restrict__ fc4_b,
    const float* __restrict__ sc_w,  const float* __restrict__ sc_b,
    float* __restrict__ text_out, int M)
{
    __shared__ float tx[8][TEXTD];
    __shared__ float t1[8][128];
    __shared__ float t2[8][64];
    __shared__ float t3[8][16];
    const int tid = threadIdx.x;
    const int m0 = blockIdx.x * 8;

    for (int idx = tid; idx < 8 * TEXTD; idx += 128) {
        int r = idx / TEXTD, k = idx % TEXTD;
        int row = m0 + r;
        tx[r][k] = (row < M) ? text[(size_t)row * TEXTD + k] : 0.f;
    }
    __syncthreads();

    // fc1: 500 -> 128, thread j owns output column j for all 8 rows
    const int j = tid;
    float acc[8];
    {
        float b = fc1_b[j];
        #pragma unroll
        for (int r = 0; r < 8; r++) acc[r] = b;
    }
    for (int k = 0; k < TEXTD; k++) {
        float wv = fc1_w[k * 128 + j];
        #pragma unroll
        for (int r = 0; r < 8; r++) acc[r] = fmaf(tx[r][k], wv, acc[r]);
    }
    #pragma unroll
    for (int r = 0; r < 8; r++) t1[r][j] = fmaxf(acc[r], 0.f);

    // shortcut: 500 -> 16
    const int rs = tid >> 4, cs = tid & 15;
    float scacc = sc_b[cs];
    for (int k = 0; k < TEXTD; k++)
        scacc = fmaf(tx[rs][k], sc_w[k * 16 + cs], scacc);
    __syncthreads();

    // fc2: 128 -> 64
    const int r2 = tid >> 6, c2 = tid & 63;
    for (int rb = 0; rb < 4; rb++) {
        int row = rb * 2 + r2;
        float a2 = fc2_b[c2];
        for (int k = 0; k < 128; k++) a2 = fmaf(t1[row][k], fc2_w[k * 64 + c2], a2);
        t2[row][c2] = fmaxf(a2, 0.f);
    }
    __syncthreads();

    // fc3: 64 -> 16
    float a3 = fc3_b[cs];
    for (int k = 0; k < 64; k++) a3 = fmaf(t2[rs][k], fc3_w[k * 16 + cs], a3);
    t3[rs][cs] = fmaxf(a3, 0.f);
    __syncthreads();

    // fc4: 16 -> 16, plus shortcut
    float a4 = fc4_b[cs];
    #pragma unroll
    for (int k = 0; k < 16; k++) a4 = fmaf(t3[rs][k], fc4_w[k * 16 + cs], a4);
    int row = m0 + rs;
    if (row < M) text_out[(size_t)row * 16 + cs] = a4 + scacc;
}

// ---------------- K2: h1 = x @ W1 (bf16 out), plus per-node attention scalars ----------------
__global__ __launch_bounds__(128) void gat1_proj_kernel(
    const float* __restrict__ x, const float* __restrict__ W1,
    const float* __restrict__ att_src, const float* __restrict__ att_dst,
    __hip_bfloat16* __restrict__ h1, float* __restrict__ a_s, float* __restrict__ a_d, int N)
{
    __shared__ float xs[8][128];
    const int tid = threadIdx.x, j = tid;
    const int n0 = blockIdx.x * 8;

    for (int idx = tid; idx < 8 * 128; idx += 128) {
        int r = idx >> 7, k = idx & 127;
        int row = n0 + r;
        xs[r][k] = (row < N) ? x[(size_t)row * 128 + k] : 0.f;
    }
    __syncthreads();

    float acc[8];
    #pragma unroll
    for (int r = 0; r < 8; r++) acc[r] = 0.f;
    for (int k = 0; k < 128; k++) {
        float wv = W1[k * 128 + j];
        #pragma unroll
        for (int r = 0; r < 8; r++) acc[r] = fmaf(xs[r][k], wv, acc[r]);
    }

    const float atts = att_src[j], attd = att_dst[j];
    const int lane = tid & 63, head = tid >> 6;
    for (int r = 0; r < 8; r++) {
        int row = n0 + r;
        if (row < N) h1[(size_t)row * 128 + j] = __float2bfloat16(acc[r]);
        float ps = acc[r] * atts, pd = acc[r] * attd;
        #pragma unroll
        for (int off = 32; off > 0; off >>= 1) {
            ps += __shfl_down(ps, off, 64);
            pd += __shfl_down(pd, off, 64);
        }
        if (lane == 0 && row < N) {
            a_s[row * 2 + head] = ps;
            a_d[row * 2 + head] = pd;
        }
    }
}

// ---------------- CSR build ----------------
__global__ __launch_bounds__(256) void deg_init_kernel(int* __restrict__ deg, int N)
{
    int v = blockIdx.x * 256 + threadIdx.x;
    if (v < N) deg[v] = 1;   // self-loop
}

__global__ __launch_bounds__(256) void deg_hist_kernel(
    const int* __restrict__ edst, int* __restrict__ deg, int E)
{
    int e = blockIdx.x * 256 + threadIdx.x;
    if (e < E) atomicAdd(&deg[edst[e]], 1);
}

#define SCAN_T 256
__global__ __launch_bounds__(SCAN_T) void scan_kernel(
    const int* __restrict__ deg, int* __restrict__ rowptr, int N)
{
    __shared__ int part[SCAN_T];
    const int tid = threadIdx.x;
    const int chunk = (N + SCAN_T - 1) / SCAN_T;
    const int beg = tid * chunk;
    const int end = min(beg + chunk, N);
    int s = 0;
    for (int i = beg; i < end; i++) s += deg[i];
    part[tid] = s;
    for (int off = 1; off < SCAN_T; off <<= 1) {
        __syncthreads();
        int val = (tid >= off) ? part[tid - off] : 0;
        __syncthreads();
        part[tid] += val;
    }
    __syncthreads();
    int excl = (tid == 0) ? 0 : part[tid - 1];
    for (int i = beg; i < end; i++) { rowptr[i] = excl; excl += deg[i]; }
    if (tid == SCAN_T - 1) rowptr[N] = excl;
}

__global__ __launch_bounds__(256) void cursor_init_kernel(
    const int* __restrict__ rowptr, int* __restrict__ cursor,
    int* __restrict__ csr_src, int N)
{
    int v = blockIdx.x * 256 + threadIdx.x;
    if (v < N) {
        int p = rowptr[v];
        csr_src[p] = v;        // self-loop in slot 0
        cursor[v] = p + 1;
    }
}

__global__ __launch_bounds__(256) void fill_kernel(
    const int* __restrict__ esrc, const int* __restrict__ edst,
    int* __restrict__ cursor, int* __restrict__ csr_src, int E)
{
    int e = blockIdx.x * 256 + threadIdx.x;
    if (e < E) {
        int dst = edst[e];
        int pos = atomicAdd(&cursor[dst], 1);
        csr_src[pos] = esrc[e];
    }
}

// ---------------- K3: layer-1 gather (2 nodes / 256-thread block), fused div+b1+relu ----------------
__global__ __launch_bounds__(256) void gat1_gather_kernel(
    const int* __restrict__ rowptr, const int* __restrict__ csr_src,
    const __hip_bfloat16* __restrict__ h1,
    const float* __restrict__ a_s, const float* __restrict__ a_d,
    const float* __restrict__ b1, float* __restrict__ g1, int N)
{
    const int tid = threadIdx.x;
    const int v = blockIdx.x * 2 + (tid >> 7);
    if (v >= N) return;
    const int d = tid & 127, head = d >> 6;
    const float adv = a_d[v * 2 + head];
    const int beg = rowptr[v], end = rowptr[v + 1];
    float acc = 0.f, den = 0.f;
    for (int i = beg; i < end; i++) {
        int src = csr_src[i];
        float e = a_s[src * 2 + head] + adv;
        float w = __expf(e > 0.f ? e : 0.2f * e);
        den += w;
        acc = fmaf(w, __bfloat162float(h1[(size_t)src * 128 + d]), acc);
    }
    g1[(size_t)v * 128 + d] = fmaxf(acc / (den + 1e-16f) + b1[d], 0.f);
}

// ---------------- K4: h2 = g1 @ W2; layer-2 attention scalars ----------------
__global__ __launch_bounds__(128) void gat2_proj_kernel(
    const float* __restrict__ g1,
    const float* __restrict__ W2, const float* __restrict__ att_src2, const float* __restrict__ att_dst2,
    float* __restrict__ h2, float* __restrict__ a_s2, float* __restrict__ a_d2, int N)
{
    __shared__ float gs[8][128];
    const int tid = threadIdx.x;
    const int n0 = blockIdx.x * 8;
    for (int r = 0; r < 8; r++) {
        int row = n0 + r;
        gs[r][tid] = (row < N) ? g1[(size_t)row * 128 + tid] : 0.f;
    }
    __syncthreads();

    const int rs = tid >> 4, cs = tid & 15;
    float hacc = 0.f;
    for (int k = 0; k < 128; k++) hacc = fmaf(gs[rs][k], W2[k * 16 + cs], hacc);

    int row = n0 + rs;
    float ps = hacc * att_src2[cs], pd = hacc * att_dst2[cs];
    #pragma unroll
    for (int off = 8; off > 0; off >>= 1) {
        ps += __shfl_down(ps, off, 16);
        pd += __shfl_down(pd, off, 16);
    }
    if (row < N) {
        h2[(size_t)row * 16 + cs] = hacc;
        if (cs == 0) { a_s2[row] = ps; a_d2[row] = pd; }
    }
}

// ---------------- K5: layer-2 gather for MASKED nodes only (16 per block), fused div+b2 ----------------
__global__ __launch_bounds__(256) void gat2_gather_kernel(
    const int* __restrict__ rowptr, const int* __restrict__ csr_src,
    const float* __restrict__ h2,
    const float* __restrict__ a_s2, const float* __restrict__ a_d2,
    const float* __restrict__ b2, const int* __restrict__ mask,
    float* __restrict__ g2m, int M)
{
    const int tid = threadIdx.x;
    const int m = blockIdx.x * 16 + (tid >> 4);
    if (m >= M) return;
    const int c = tid & 15;
    const int v = mask[m];
    const float adv = a_d2[v];
    const int beg = rowptr[v], end = rowptr[v + 1];
    float acc = 0.f, den = 0.f;
    for (int i = beg; i < end; i++) {
        int src = csr_src[i];
        float e = a_s2[src] + adv;
        float w = __expf(e > 0.f ? e : 0.2f * e);
        den += w;
        acc = fmaf(w, h2[(size_t)src * 16 + c], acc);
    }
    g2m[(size_t)m * 16 + c] = acc / (den + 1e-16f) + b2[c];
}

// ---------------- K6: fused head: concat -> fcf -> log_softmax ----------------
__global__ __launch_bounds__(64) void final_kernel(
    const float* __restrict__ text_out, const float* __restrict__ g2m,
    const float* __restrict__ fcf_w, const float* __restrict__ fcf_b,
    float* __restrict__ out, int M)
{
    const int lane = threadIdx.x;
    const int g = lane >> 4, j = lane & 15;
    const int m = blockIdx.x * 4 + g;
    if (m >= M) return;

    float tval = text_out[(size_t)m * 16 + j];
    float gval = g2m[(size_t)m * 16 + j];

    float logit = fcf_b[j];
    #pragma unroll
    for (int k = 0; k < 16; k++) {
        logit = fmaf(__shfl(tval, k, 16), fcf_w[k * 16 + j], logit);
        logit = fmaf(__shfl(gval, k, 16), fcf_w[(16 + k) * 16 + j], logit);
    }
    float mx = logit;
    #pragma unroll
    for (int off = 8; off > 0; off >>= 1) mx = fmaxf(mx, __shfl_xor(mx, off, 16));
    float se = expf(logit - mx);
    #pragma unroll
    for (int off = 8; off > 0; off >>= 1) se += __shfl_xor(se, off, 16);
    out[(size_t)m * 16 + j] = logit - mx - logf(se);
}

extern "C" void kernel_launch(void* const* d_in, const int* in_sizes, int n_in,
                              void* d_out, int out_size, void* d_ws, size_t ws_size,
                              hipStream_t stream)
{
    const float* text  = (const float*)d_in[0];
    const float* x     = (const float*)d_in[1];
    const int*   ei    = (const int*)  d_in[2];
    const int*   mask  = (const int*)  d_in[3];
    const float* fc1_w = (const float*)d_in[4];  const float* fc1_b = (const float*)d_in[5];
    const float* fc2_w = (const float*)d_in[6];  const float* fc2_b = (const float*)d_in[7];
    const float* fc3_w = (const float*)d_in[8];  const float* fc3_b = (const float*)d_in[9];
    const float* fc4_w = (const float*)d_in[10]; const float* fc4_b = (const float*)d_in[11];
    const float* sc_w  = (const float*)d_in[12]; const float* sc_b  = (const float*)d_in[13];
    const float* W1    = (const float*)d_in[14];
    const float* as1w  = (const float*)d_in[15]; const float* ad1w  = (const float*)d_in[16];
    const float* b1    = (const float*)d_in[17];
    const float* W2    = (const float*)d_in[18];
    const float* as2w  = (const float*)d_in[19]; const float* ad2w  = (const float*)d_in[20];
    const float* b2    = (const float*)d_in[21];
    const float* fcf_w = (const float*)d_in[22]; const float* fcf_b = (const float*)d_in[23];

    const int M  = in_sizes[3];
    const int N  = in_sizes[1] / GNN_DIM;
    const int E  = in_sizes[2] / 2;
    const int EP = E + N;                 // with self-loops
    const int* esrc = ei;
    const int* edst = ei + E;

    float* ws = (float*)d_ws;
    size_t off = 0;
    auto alloc = [&](size_t n) { float* p = ws + off; off += (n + 63) & ~size_t(63); return p; };

    __hip_bfloat16* h1 = (__hip_bfloat16*)alloc((size_t)N * 128 / 2);   // bf16: N*128*2B
    float* g1       = alloc((size_t)N * 128);
    float* a_s1     = alloc((size_t)2 * N);
    float* a_d1     = alloc((size_t)2 * N);
    float* h2       = alloc((size_t)N * 16);
    float* a_s2     = alloc(N);
    float* a_d2     = alloc(N);
    float* text_out = alloc((size_t)M * 16);
    float* g2m      = alloc((size_t)M * 16);
    int* deg        = (int*)alloc(N);
    int* cursor     = (int*)alloc(N);
    int* rowptr     = (int*)alloc(N + 1);
    int* csr_src    = (int*)alloc(EP);

    // --- CSR build (independent of feature kernels; same stream serializes) ---
    deg_init_kernel<<<(N + 255) / 256, 256, 0, stream>>>(deg, N);
    deg_hist_kernel<<<(E + 255) / 256, 256, 0, stream>>>(edst, deg, E);
    scan_kernel<<<1, SCAN_T, 0, stream>>>(deg, rowptr, N);
    cursor_init_kernel<<<(N + 255) / 256, 256, 0, stream>>>(rowptr, cursor, csr_src, N);
    fill_kernel<<<(E + 255) / 256, 256, 0, stream>>>(esrc, edst, cursor, csr_src, E);

    // --- text branch ---
    text_mlp_kernel<<<(M + 7) / 8, 128, 0, stream>>>(
        text, fc1_w, fc1_b, fc2_w, fc2_b, fc3_w, fc3_b, fc4_w, fc4_b,
        sc_w, sc_b, text_out, M);

    // --- GNN branch ---
    gat1_proj_kernel<<<(N + 7) / 8, 128, 0, stream>>>(
        x, W1, as1w, ad1w, h1, a_s1, a_d1, N);

    gat1_gather_kernel<<<(N + 1) / 2, 256, 0, stream>>>(
        rowptr, csr_src, h1, a_s1, a_d1, b1, g1, N);

    gat2_proj_kernel<<<(N + 7) / 8, 128, 0, stream>>>(
        g1, W2, as2w, ad2w, h2, a_s2, a_d2, N);

    gat2_gather_kernel<<<(M + 15) / 16, 256, 0, stream>>>(
        rowptr, csr_src, h2, a_s2, a_d2, b2, mask, g2m, M);

    final_kernel<<<(M + 3) / 4, 64, 0, stream>>>(
        text_out, g2m, fcf_w, fcf_b, (float*)d_out, M);
}

// Round 3
// 421.202 us; speedup vs baseline: 1.6591x; 1.1947x over previous
//
#include <hip/hip_runtime.h>
#include <hip/hip_bf16.h>
#include <cmath>

#define TEXTD 500
#define GNN_DIM 128

__device__ __forceinline__ float bf2f(unsigned short u) {
    union { unsigned int i; float f; } cv;
    cv.i = ((unsigned int)u) << 16;
    return cv.f;
}

// ---------------- K1: fused text MLP (8 rows per block, 128 threads) ----------------
__global__ __launch_bounds__(128) void text_mlp_kernel(
    const float* __restrict__ text,
    const float* __restrict__ fc1_w, const float* __restrict__ fc1_b,
    const float* __restrict__ fc2_w, const float* __restrict__ fc2_b,
    const float* __restrict__ fc3_w, const float* __restrict__ fc3_b,
    const float* __restrict__ fc4_w, const float* __restrict__ fc4_b,
    const float* __restrict__ sc_w,  const float* __restrict__ sc_b,
    float* __restrict__ text_out, int M)
{
    __shared__ float tx[8][TEXTD];
    __shared__ float t1[8][128];
    __shared__ float t2[8][64];
    __shared__ float t3[8][16];
    const int tid = threadIdx.x;
    const int m0 = blockIdx.x * 8;

    for (int idx = tid; idx < 8 * TEXTD; idx += 128) {
        int r = idx / TEXTD, k = idx % TEXTD;
        int row = m0 + r;
        tx[r][k] = (row < M) ? text[(size_t)row * TEXTD + k] : 0.f;
    }
    __syncthreads();

    // fc1: 500 -> 128
    const int j = tid;
    float acc[8];
    {
        float b = fc1_b[j];
        #pragma unroll
        for (int r = 0; r < 8; r++) acc[r] = b;
    }
    for (int k = 0; k < TEXTD; k++) {
        float wv = fc1_w[k * 128 + j];
        #pragma unroll
        for (int r = 0; r < 8; r++) acc[r] = fmaf(tx[r][k], wv, acc[r]);
    }
    #pragma unroll
    for (int r = 0; r < 8; r++) t1[r][j] = fmaxf(acc[r], 0.f);

    // shortcut: 500 -> 16
    const int rs = tid >> 4, cs = tid & 15;
    float scacc = sc_b[cs];
    for (int k = 0; k < TEXTD; k++)
        scacc = fmaf(tx[rs][k], sc_w[k * 16 + cs], scacc);
    __syncthreads();

    // fc2: 128 -> 64
    const int r2 = tid >> 6, c2 = tid & 63;
    for (int rb = 0; rb < 4; rb++) {
        int row = rb * 2 + r2;
        float a2 = fc2_b[c2];
        for (int k = 0; k < 128; k++) a2 = fmaf(t1[row][k], fc2_w[k * 64 + c2], a2);
        t2[row][c2] = fmaxf(a2, 0.f);
    }
    __syncthreads();

    // fc3: 64 -> 16
    float a3 = fc3_b[cs];
    for (int k = 0; k < 64; k++) a3 = fmaf(t2[rs][k], fc3_w[k * 16 + cs], a3);
    t3[rs][cs] = fmaxf(a3, 0.f);
    __syncthreads();

    // fc4: 16 -> 16, plus shortcut
    float a4 = fc4_b[cs];
    #pragma unroll
    for (int k = 0; k < 16; k++) a4 = fmaf(t3[rs][k], fc4_w[k * 16 + cs], a4);
    int row = m0 + rs;
    if (row < M) text_out[(size_t)row * 16 + cs] = a4 + scacc;
}

// ---------------- K2: h1 = x @ W1 (bf16 out), plus per-node attention scalars ----------------
__global__ __launch_bounds__(128) void gat1_proj_kernel(
    const float* __restrict__ x, const float* __restrict__ W1,
    const float* __restrict__ att_src, const float* __restrict__ att_dst,
    __hip_bfloat16* __restrict__ h1, float* __restrict__ a_s, float* __restrict__ a_d, int N)
{
    __shared__ float xs[8][128];
    const int tid = threadIdx.x, j = tid;
    const int n0 = blockIdx.x * 8;

    for (int idx = tid; idx < 8 * 128; idx += 128) {
        int r = idx >> 7, k = idx & 127;
        int row = n0 + r;
        xs[r][k] = (row < N) ? x[(size_t)row * 128 + k] : 0.f;
    }
    __syncthreads();

    float acc[8];
    #pragma unroll
    for (int r = 0; r < 8; r++) acc[r] = 0.f;
    for (int k = 0; k < 128; k++) {
        float wv = W1[k * 128 + j];
        #pragma unroll
        for (int r = 0; r < 8; r++) acc[r] = fmaf(xs[r][k], wv, acc[r]);
    }

    const float atts = att_src[j], attd = att_dst[j];
    const int lane = tid & 63, head = tid >> 6;
    for (int r = 0; r < 8; r++) {
        int row = n0 + r;
        if (row < N) h1[(size_t)row * 128 + j] = __float2bfloat16(acc[r]);
        float ps = acc[r] * atts, pd = acc[r] * attd;
        #pragma unroll
        for (int off = 32; off > 0; off >>= 1) {
            ps += __shfl_down(ps, off, 64);
            pd += __shfl_down(pd, off, 64);
        }
        if (lane == 0 && row < N) {
            a_s[row * 2 + head] = ps;
            a_d[row * 2 + head] = pd;
        }
    }
}

// ---------------- CSR build ----------------
__global__ __launch_bounds__(256) void deg_init_kernel(int* __restrict__ deg, int N)
{
    int v = blockIdx.x * 256 + threadIdx.x;
    if (v < N) deg[v] = 1;   // self-loop
}

__global__ __launch_bounds__(256) void deg_hist_kernel(
    const int* __restrict__ edst, int* __restrict__ deg, int E)
{
    int e = blockIdx.x * 256 + threadIdx.x;
    if (e < E) atomicAdd(&deg[edst[e]], 1);
}

#define SCAN_T 256
__global__ __launch_bounds__(SCAN_T) void scan_kernel(
    const int* __restrict__ deg, int* __restrict__ rowptr, int N)
{
    __shared__ int part[SCAN_T];
    const int tid = threadIdx.x;
    const int chunk = (N + SCAN_T - 1) / SCAN_T;
    const int beg = tid * chunk;
    const int end = min(beg + chunk, N);
    int s = 0;
    for (int i = beg; i < end; i++) s += deg[i];
    part[tid] = s;
    for (int off = 1; off < SCAN_T; off <<= 1) {
        __syncthreads();
        int val = (tid >= off) ? part[tid - off] : 0;
        __syncthreads();
        part[tid] += val;
    }
    __syncthreads();
    int excl = (tid == 0) ? 0 : part[tid - 1];
    for (int i = beg; i < end; i++) { rowptr[i] = excl; excl += deg[i]; }
    if (tid == SCAN_T - 1) rowptr[N] = excl;
}

__device__ __forceinline__ float edge_w(float e) {
    return __expf(e > 0.f ? e : 0.2f * e);
}

// cursor init + self-loop entry (index AND layer-1 weights)
__global__ __launch_bounds__(256) void cursor_init_kernel(
    const int* __restrict__ rowptr, int* __restrict__ cursor,
    int* __restrict__ csr_src, float* __restrict__ wcsr,
    const float* __restrict__ a_s, const float* __restrict__ a_d, int N)
{
    int v = blockIdx.x * 256 + threadIdx.x;
    if (v < N) {
        int p = rowptr[v];
        csr_src[p] = v;
        cursor[v] = p + 1;
        wcsr[2 * p]     = edge_w(a_s[2 * v]     + a_d[2 * v]);
        wcsr[2 * p + 1] = edge_w(a_s[2 * v + 1] + a_d[2 * v + 1]);
    }
}

// fill CSR slots + fused layer-1 edge weights
__global__ __launch_bounds__(256) void fill_kernel(
    const int* __restrict__ esrc, const int* __restrict__ edst,
    int* __restrict__ cursor, int* __restrict__ csr_src, float* __restrict__ wcsr,
    const float* __restrict__ a_s, const float* __restrict__ a_d, int E)
{
    int e = blockIdx.x * 256 + threadIdx.x;
    if (e < E) {
        int src = esrc[e], dst = edst[e];
        int pos = atomicAdd(&cursor[dst], 1);
        csr_src[pos] = src;
        wcsr[2 * pos]     = edge_w(a_s[2 * src]     + a_d[2 * dst]);
        wcsr[2 * pos + 1] = edge_w(a_s[2 * src + 1] + a_d[2 * dst + 1]);
    }
}

// ---------------- K3: layer-1 gather: 1 node / 256-thread block, 4 edge slots x 64 dim-pairs ----------------
__global__ __launch_bounds__(256) void gat1_gather_kernel(
    const int* __restrict__ rowptr, const int* __restrict__ csr_src,
    const float* __restrict__ wcsr, const ushort2* __restrict__ h1,
    const float* __restrict__ b1, float* __restrict__ g1, int N)
{
    __shared__ float2 accs[3][64];
    __shared__ float  dens[3][2];
    const int v = blockIdx.x;
    const int tid = threadIdx.x;
    const int slot = tid >> 6, dp = tid & 63, head = dp >> 5;
    const int beg = rowptr[v], end = rowptr[v + 1];

    float a0 = 0.f, a1 = 0.f, den = 0.f;
    for (int i = beg + slot; i < end; i += 4) {
        int src = csr_src[i];
        float w = wcsr[2 * i + head];
        ushort2 hv = h1[(size_t)src * 64 + dp];
        a0 = fmaf(w, bf2f(hv.x), a0);
        a1 = fmaf(w, bf2f(hv.y), a1);
        den += w;
    }
    if (slot > 0) {
        accs[slot - 1][dp] = make_float2(a0, a1);
        if (dp == 0 || dp == 32) dens[slot - 1][head] = den;
    }
    __syncthreads();
    if (slot == 0) {
        #pragma unroll
        for (int s = 0; s < 3; s++) {
            float2 t = accs[s][dp];
            a0 += t.x; a1 += t.y;
            den += dens[s][head];
        }
        float inv = 1.f / (den + 1e-16f);
        float2 o;
        o.x = fmaxf(fmaf(a0, inv, b1[2 * dp]),     0.f);
        o.y = fmaxf(fmaf(a1, inv, b1[2 * dp + 1]), 0.f);
        ((float2*)g1)[(size_t)v * 64 + dp] = o;
    }
}

// ---------------- K4: h2 = g1 @ W2; layer-2 attention scalars ----------------
__global__ __launch_bounds__(128) void gat2_proj_kernel(
    const float* __restrict__ g1,
    const float* __restrict__ W2, const float* __restrict__ att_src2, const float* __restrict__ att_dst2,
    float* __restrict__ h2, float* __restrict__ a_s2, float* __restrict__ a_d2, int N)
{
    __shared__ float gs[8][128];
    const int tid = threadIdx.x;
    const int n0 = blockIdx.x * 8;
    for (int r = 0; r < 8; r++) {
        int row = n0 + r;
        gs[r][tid] = (row < N) ? g1[(size_t)row * 128 + tid] : 0.f;
    }
    __syncthreads();

    const int rs = tid >> 4, cs = tid & 15;
    float hacc = 0.f;
    for (int k = 0; k < 128; k++) hacc = fmaf(gs[rs][k], W2[k * 16 + cs], hacc);

    int row = n0 + rs;
    float ps = hacc * att_src2[cs], pd = hacc * att_dst2[cs];
    #pragma unroll
    for (int off = 8; off > 0; off >>= 1) {
        ps += __shfl_down(ps, off, 16);
        pd += __shfl_down(pd, off, 16);
    }
    if (row < N) {
        h2[(size_t)row * 16 + cs] = hacc;
        if (cs == 0) { a_s2[row] = ps; a_d2[row] = pd; }
    }
}

// ---------------- K5: layer-2 gather (masked nodes): 1 wave/node, 4 slots x 16 dims ----------------
__global__ __launch_bounds__(256) void gat2_gather_kernel(
    const int* __restrict__ rowptr, const int* __restrict__ csr_src,
    const float* __restrict__ h2,
    const float* __restrict__ a_s2, const float* __restrict__ a_d2,
    const float* __restrict__ b2, const int* __restrict__ mask,
    float* __restrict__ g2m, int M)
{
    const int tid = threadIdx.x;
    const int m = blockIdx.x * 4 + (tid >> 6);
    if (m >= M) return;
    const int lane = tid & 63, slot = lane >> 4, c = lane & 15;
    const int v = mask[m];
    const float adv = a_d2[v];
    const int beg = rowptr[v], end = rowptr[v + 1];
    float acc = 0.f, den = 0.f;
    for (int i = beg + slot; i < end; i += 4) {
        int src = csr_src[i];
        float e = a_s2[src] + adv;
        float w = __expf(e > 0.f ? e : 0.2f * e);
        den += w;
        acc = fmaf(w, h2[(size_t)src * 16 + c], acc);
    }
    acc += __shfl_xor(acc, 16, 64);
    acc += __shfl_xor(acc, 32, 64);
    den += __shfl_xor(den, 16, 64);
    den += __shfl_xor(den, 32, 64);
    if (slot == 0) g2m[(size_t)m * 16 + c] = acc / (den + 1e-16f) + b2[c];
}

// ---------------- K6: fused head: concat -> fcf -> log_softmax ----------------
__global__ __launch_bounds__(64) void final_kernel(
    const float* __restrict__ text_out, const float* __restrict__ g2m,
    const float* __restrict__ fcf_w, const float* __restrict__ fcf_b,
    float* __restrict__ out, int M)
{
    const int lane = threadIdx.x;
    const int g = lane >> 4, j = lane & 15;
    const int m = blockIdx.x * 4 + g;
    if (m >= M) return;

    float tval = text_out[(size_t)m * 16 + j];
    float gval = g2m[(size_t)m * 16 + j];

    float logit = fcf_b[j];
    #pragma unroll
    for (int k = 0; k < 16; k++) {
        logit = fmaf(__shfl(tval, k, 16), fcf_w[k * 16 + j], logit);
        logit = fmaf(__shfl(gval, k, 16), fcf_w[(16 + k) * 16 + j], logit);
    }
    float mx = logit;
    #pragma unroll
    for (int off = 8; off > 0; off >>= 1) mx = fmaxf(mx, __shfl_xor(mx, off, 16));
    float se = expf(logit - mx);
    #pragma unroll
    for (int off = 8; off > 0; off >>= 1) se += __shfl_xor(se, off, 16);
    out[(size_t)m * 16 + j] = logit - mx - logf(se);
}

extern "C" void kernel_launch(void* const* d_in, const int* in_sizes, int n_in,
                              void* d_out, int out_size, void* d_ws, size_t ws_size,
                              hipStream_t stream)
{
    const float* text  = (const float*)d_in[0];
    const float* x     = (const float*)d_in[1];
    const int*   ei    = (const int*)  d_in[2];
    const int*   mask  = (const int*)  d_in[3];
    const float* fc1_w = (const float*)d_in[4];  const float* fc1_b = (const float*)d_in[5];
    const float* fc2_w = (const float*)d_in[6];  const float* fc2_b = (const float*)d_in[7];
    const float* fc3_w = (const float*)d_in[8];  const float* fc3_b = (const float*)d_in[9];
    const float* fc4_w = (const float*)d_in[10]; const float* fc4_b = (const float*)d_in[11];
    const float* sc_w  = (const float*)d_in[12]; const float* sc_b  = (const float*)d_in[13];
    const float* W1    = (const float*)d_in[14];
    const float* as1w  = (const float*)d_in[15]; const float* ad1w  = (const float*)d_in[16];
    const float* b1    = (const float*)d_in[17];
    const float* W2    = (const float*)d_in[18];
    const float* as2w  = (const float*)d_in[19]; const float* ad2w  = (const float*)d_in[20];
    const float* b2    = (const float*)d_in[21];
    const float* fcf_w = (const float*)d_in[22]; const float* fcf_b = (const float*)d_in[23];

    const int M  = in_sizes[3];
    const int N  = in_sizes[1] / GNN_DIM;
    const int E  = in_sizes[2] / 2;
    const int EP = E + N;                 // with self-loops
    const int* esrc = ei;
    const int* edst = ei + E;

    float* ws = (float*)d_ws;
    size_t off = 0;
    auto alloc = [&](size_t n) { float* p = ws + off; off += (n + 63) & ~size_t(63); return p; };

    __hip_bfloat16* h1 = (__hip_bfloat16*)alloc((size_t)N * 128 / 2);   // bf16
    float* g1       = alloc((size_t)N * 128);
    float* a_s1     = alloc((size_t)2 * N);
    float* a_d1     = alloc((size_t)2 * N);
    float* h2       = alloc((size_t)N * 16);
    float* a_s2     = alloc(N);
    float* a_d2     = alloc(N);
    float* text_out = alloc((size_t)M * 16);
    float* g2m      = alloc((size_t)M * 16);
    float* wcsr1    = alloc((size_t)2 * EP);
    int* deg        = (int*)alloc(N);
    int* cursor     = (int*)alloc(N);
    int* rowptr     = (int*)alloc(N + 1);
    int* csr_src    = (int*)alloc(EP);

    // --- degree histogram + scan (edge-index only) ---
    deg_init_kernel<<<(N + 255) / 256, 256, 0, stream>>>(deg, N);
    deg_hist_kernel<<<(E + 255) / 256, 256, 0, stream>>>(edst, deg, E);
    scan_kernel<<<1, SCAN_T, 0, stream>>>(deg, rowptr, N);

    // --- projection (produces a_s1/a_d1 needed by fused-weight fill) ---
    gat1_proj_kernel<<<(N + 7) / 8, 128, 0, stream>>>(
        x, W1, as1w, ad1w, h1, a_s1, a_d1, N);

    // --- CSR fill with fused layer-1 edge weights ---
    cursor_init_kernel<<<(N + 255) / 256, 256, 0, stream>>>(
        rowptr, cursor, csr_src, wcsr1, a_s1, a_d1, N);
    fill_kernel<<<(E + 255) / 256, 256, 0, stream>>>(
        esrc, edst, cursor, csr_src, wcsr1, a_s1, a_d1, E);

    // --- text branch ---
    text_mlp_kernel<<<(M + 7) / 8, 128, 0, stream>>>(
        text, fc1_w, fc1_b, fc2_w, fc2_b, fc3_w, fc3_b, fc4_w, fc4_b,
        sc_w, sc_b, text_out, M);

    // --- GNN aggregation / second layer ---
    gat1_gather_kernel<<<N, 256, 0, stream>>>(
        rowptr, csr_src, wcsr1, (const ushort2*)h1, b1, g1, N);

    gat2_proj_kernel<<<(N + 7) / 8, 128, 0, stream>>>(
        g1, W2, as2w, ad2w, h2, a_s2, a_d2, N);

    gat2_gather_kernel<<<(M + 3) / 4, 256, 0, stream>>>(
        rowptr, csr_src, h2, a_s2, a_d2, b2, mask, g2m, M);

    final_kernel<<<(M + 3) / 4, 64, 0, stream>>>(
        text_out, g2m, fcf_w, fcf_b, (float*)d_out, M);
}

// Round 4
// 386.029 us; speedup vs baseline: 1.8102x; 1.0911x over previous
//
#include <hip/hip_runtime.h>
#include <hip/hip_bf16.h>
#include <cmath>

#define TEXTD 500
#define GNN_DIM 128

typedef __attribute__((ext_vector_type(8))) short bf16x8;
typedef __attribute__((ext_vector_type(4))) float f32x4;

__device__ __forceinline__ float bf2f(unsigned short u) {
    union { unsigned int i; float f; } cv;
    cv.i = ((unsigned int)u) << 16;
    return cv.f;
}
__device__ __forceinline__ unsigned short f2b(float x) {
    __hip_bfloat16 b = __float2bfloat16(x);
    return *reinterpret_cast<unsigned short*>(&b);
}

// ---------------- conversions ----------------
// text [M x 500] fp32 -> [Mp x 512] bf16 (zero-padded rows & K)
__global__ __launch_bounds__(256) void conv_text_kernel(
    const float* __restrict__ text, unsigned short* __restrict__ out, int M, int Mp)
{
    int idx = blockIdx.x * 256 + threadIdx.x;          // Mp*128 threads
    int r = idx >> 7, c4 = (idx & 127) * 4;
    if (r >= Mp) return;
    ushort4 o;
    if (r < M && c4 + 3 < TEXTD) {
        float4 v = *(const float4*)(text + (size_t)r * TEXTD + c4);
        o = make_ushort4(f2b(v.x), f2b(v.y), f2b(v.z), f2b(v.w));
    } else {
        float vs[4];
        #pragma unroll
        for (int e = 0; e < 4; e++) {
            int c = c4 + e;
            vs[e] = (r < M && c < TEXTD) ? text[(size_t)r * TEXTD + c] : 0.f;
        }
        o = make_ushort4(f2b(vs[0]), f2b(vs[1]), f2b(vs[2]), f2b(vs[3]));
    }
    *(ushort4*)(out + (size_t)r * 512 + c4) = o;
}

// x [N x 128] fp32 -> [Np x 128] bf16
__global__ __launch_bounds__(256) void conv_x_kernel(
    const float* __restrict__ x, unsigned short* __restrict__ out, int N, int Np)
{
    int idx = blockIdx.x * 256 + threadIdx.x;          // Np*32 threads
    int r = idx >> 5, c4 = (idx & 31) * 4;
    if (r >= Np) return;
    ushort4 o;
    if (r < N) {
        float4 v = *(const float4*)(x + (size_t)r * 128 + c4);
        o = make_ushort4(f2b(v.x), f2b(v.y), f2b(v.z), f2b(v.w));
    } else {
        o = make_ushort4(0, 0, 0, 0);
    }
    *(ushort4*)(out + (size_t)r * 128 + c4) = o;
}

// weights: w1cat [144 x 512] = [fc1_w^T ; sc_w^T] K-padded; w1g [128 x 128] = W1^T
__global__ __launch_bounds__(256) void conv_w_kernel(
    const float* __restrict__ fc1_w, const float* __restrict__ sc_w,
    const float* __restrict__ W1,
    unsigned short* __restrict__ w1cat, unsigned short* __restrict__ w1g)
{
    int idx = blockIdx.x * 256 + threadIdx.x;
    if (idx < 144 * 512) {
        int n = idx >> 9, k = idx & 511;
        float v = 0.f;
        if (k < TEXTD) v = (n < 128) ? fc1_w[k * 128 + n] : sc_w[k * 16 + (n - 128)];
        w1cat[idx] = f2b(v);
    } else {
        int j = idx - 144 * 512;
        if (j < 128 * 128) {
            int n = j >> 7, k = j & 127;
            w1g[j] = f2b(W1[k * 128 + n]);
        }
    }
}

// ---------------- GEMM1: [Mp x 512] x [144 x 512]^T -> t1 (relu,+fc1_b) & tsc (+sc_b) ----------------
__global__ __launch_bounds__(256) void gemm_text_kernel(
    const short* __restrict__ A, const short* __restrict__ B,
    const float* __restrict__ fc1_b, const float* __restrict__ sc_b,
    float* __restrict__ t1, float* __restrict__ tsc, int M)
{
    const int tid = threadIdx.x;
    const int wave = tid >> 6, lane = tid & 63;
    const int mb = blockIdx.x * 64 + wave * 16;
    const int nb = blockIdx.y * 16;
    const short* ap = A + (size_t)(mb + (lane & 15)) * 512 + (lane >> 4) * 8;
    const short* bp = B + (size_t)(nb + (lane & 15)) * 512 + (lane >> 4) * 8;
    f32x4 acc = {0.f, 0.f, 0.f, 0.f};
    #pragma unroll 4
    for (int ks = 0; ks < 16; ks++) {
        bf16x8 a = *(const bf16x8*)(ap + ks * 32);
        bf16x8 b = *(const bf16x8*)(bp + ks * 32);
        acc = __builtin_amdgcn_mfma_f32_16x16x32_bf16(a, b, acc, 0, 0, 0);
    }
    const int col = lane & 15;
    #pragma unroll
    for (int i = 0; i < 4; i++) {
        int row = mb + (lane >> 4) * 4 + i;
        if (row < M) {
            if (nb < 128) t1[(size_t)row * 128 + nb + col] = fmaxf(acc[i] + fc1_b[nb + col], 0.f);
            else          tsc[(size_t)row * 16 + col] = acc[i] + sc_b[col];
        }
    }
}

// ---------------- GEMM2: h1 = xbf @ W1^T -> bf16 [N x 128] ----------------
__global__ __launch_bounds__(256) void gemm_h1_kernel(
    const short* __restrict__ A, const short* __restrict__ B,
    unsigned short* __restrict__ h1, int N)
{
    const int tid = threadIdx.x;
    const int wave = tid >> 6, lane = tid & 63;
    const int mb = blockIdx.x * 64 + wave * 16;
    const int nb = blockIdx.y * 16;
    const short* ap = A + (size_t)(mb + (lane & 15)) * 128 + (lane >> 4) * 8;
    const short* bp = B + (size_t)(nb + (lane & 15)) * 128 + (lane >> 4) * 8;
    f32x4 acc = {0.f, 0.f, 0.f, 0.f};
    #pragma unroll
    for (int ks = 0; ks < 4; ks++) {
        bf16x8 a = *(const bf16x8*)(ap + ks * 32);
        bf16x8 b = *(const bf16x8*)(bp + ks * 32);
        acc = __builtin_amdgcn_mfma_f32_16x16x32_bf16(a, b, acc, 0, 0, 0);
    }
    const int col = lane & 15;
    #pragma unroll
    for (int i = 0; i < 4; i++) {
        int row = mb + (lane >> 4) * 4 + i;
        if (row < N) h1[(size_t)row * 128 + nb + col] = f2b(acc[i]);
    }
}

// ---------------- attention scalars for layer 1 (1 wave / node) ----------------
__global__ __launch_bounds__(256) void attn1_kernel(
    const ushort2* __restrict__ h1,
    const float* __restrict__ att_src, const float* __restrict__ att_dst,
    float* __restrict__ a_s, float* __restrict__ a_d, int N)
{
    const int node = blockIdx.x * 4 + (threadIdx.x >> 6);
    if (node >= N) return;
    const int lane = threadIdx.x & 63;
    ushort2 hv = h1[(size_t)node * 64 + lane];
    float h0 = bf2f(hv.x), h1v = bf2f(hv.y);
    float ps = h0 * att_src[2 * lane] + h1v * att_src[2 * lane + 1];
    float pd = h0 * att_dst[2 * lane] + h1v * att_dst[2 * lane + 1];
    #pragma unroll
    for (int off = 1; off <= 16; off <<= 1) {   // reduce within each 32-lane half (one head each)
        ps += __shfl_xor(ps, off, 64);
        pd += __shfl_xor(pd, off, 64);
    }
    if (lane == 0)  { a_s[2 * node] = ps;     a_d[2 * node] = pd; }
    if (lane == 32) { a_s[2 * node + 1] = ps; a_d[2 * node + 1] = pd; }
}

// ---------------- text tail: fc2/fc3/fc4 + shortcut ----------------
__global__ __launch_bounds__(128) void text_tail_kernel(
    const float* __restrict__ t1g, const float* __restrict__ tsc,
    const float* __restrict__ fc2_w, const float* __restrict__ fc2_b,
    const float* __restrict__ fc3_w, const float* __restrict__ fc3_b,
    const float* __restrict__ fc4_w, const float* __restrict__ fc4_b,
    float* __restrict__ text_out, int M)
{
    __shared__ float t1[8][128];
    __shared__ float t2[8][64];
    __shared__ float t3[8][16];
    const int tid = threadIdx.x;
    const int m0 = blockIdx.x * 8;

    for (int r = 0; r < 8; r++) {
        int row = m0 + r;
        t1[r][tid] = (row < M) ? t1g[(size_t)row * 128 + tid] : 0.f;
    }
    __syncthreads();

    const int r2 = tid >> 6, c2 = tid & 63;
    for (int rb = 0; rb < 4; rb++) {
        int row = rb * 2 + r2;
        float a2 = fc2_b[c2];
        for (int k = 0; k < 128; k++) a2 = fmaf(t1[row][k], fc2_w[k * 64 + c2], a2);
        t2[row][c2] = fmaxf(a2, 0.f);
    }
    __syncthreads();

    const int rs = tid >> 4, cs = tid & 15;
    float a3 = fc3_b[cs];
    for (int k = 0; k < 64; k++) a3 = fmaf(t2[rs][k], fc3_w[k * 16 + cs], a3);
    t3[rs][cs] = fmaxf(a3, 0.f);
    __syncthreads();

    float a4 = fc4_b[cs];
    #pragma unroll
    for (int k = 0; k < 16; k++) a4 = fmaf(t3[rs][k], fc4_w[k * 16 + cs], a4);
    int row = m0 + rs;
    if (row < M) text_out[(size_t)row * 16 + cs] = a4 + tsc[(size_t)row * 16 + cs];
}

// ---------------- CSR build ----------------
__global__ __launch_bounds__(256) void deg_init_kernel(int* __restrict__ deg, int N)
{
    int v = blockIdx.x * 256 + threadIdx.x;
    if (v < N) deg[v] = 1;
}

__global__ __launch_bounds__(256) void deg_hist_kernel(
    const int* __restrict__ edst, int* __restrict__ deg, int E)
{
    int e = blockIdx.x * 256 + threadIdx.x;
    if (e < E) atomicAdd(&deg[edst[e]], 1);
}

#define SCAN_T 256
__global__ __launch_bounds__(SCAN_T) void scan_kernel(
    const int* __restrict__ deg, int* __restrict__ rowptr, int N)
{
    __shared__ int part[SCAN_T];
    const int tid = threadIdx.x;
    const int chunk = (N + SCAN_T - 1) / SCAN_T;
    const int beg = tid * chunk;
    const int end = min(beg + chunk, N);
    int s = 0;
    for (int i = beg; i < end; i++) s += deg[i];
    part[tid] = s;
    for (int off = 1; off < SCAN_T; off <<= 1) {
        __syncthreads();
        int val = (tid >= off) ? part[tid - off] : 0;
        __syncthreads();
        part[tid] += val;
    }
    __syncthreads();
    int excl = (tid == 0) ? 0 : part[tid - 1];
    for (int i = beg; i < end; i++) { rowptr[i] = excl; excl += deg[i]; }
    if (tid == SCAN_T - 1) rowptr[N] = excl;
}

__device__ __forceinline__ float edge_w(float e) {
    return __expf(e > 0.f ? e : 0.2f * e);
}

__global__ __launch_bounds__(256) void cursor_init_kernel(
    const int* __restrict__ rowptr, int* __restrict__ cursor,
    int* __restrict__ csr_src, float* __restrict__ wcsr,
    const float* __restrict__ a_s, const float* __restrict__ a_d, int N)
{
    int v = blockIdx.x * 256 + threadIdx.x;
    if (v < N) {
        int p = rowptr[v];
        csr_src[p] = v;
        cursor[v] = p + 1;
        wcsr[2 * p]     = edge_w(a_s[2 * v]     + a_d[2 * v]);
        wcsr[2 * p + 1] = edge_w(a_s[2 * v + 1] + a_d[2 * v + 1]);
    }
}

__global__ __launch_bounds__(256) void fill_kernel(
    const int* __restrict__ esrc, const int* __restrict__ edst,
    int* __restrict__ cursor, int* __restrict__ csr_src, float* __restrict__ wcsr,
    const float* __restrict__ a_s, const float* __restrict__ a_d, int E)
{
    int e = blockIdx.x * 256 + threadIdx.x;
    if (e < E) {
        int src = esrc[e], dst = edst[e];
        int pos = atomicAdd(&cursor[dst], 1);
        csr_src[pos] = src;
        wcsr[2 * pos]     = edge_w(a_s[2 * src]     + a_d[2 * dst]);
        wcsr[2 * pos + 1] = edge_w(a_s[2 * src + 1] + a_d[2 * dst + 1]);
    }
}

// ---------------- layer-1 gather: 1 node / 256-thread block, 4 edge slots x 64 dim-pairs ----------------
__global__ __launch_bounds__(256) void gat1_gather_kernel(
    const int* __restrict__ rowptr, const int* __restrict__ csr_src,
    const float* __restrict__ wcsr, const ushort2* __restrict__ h1,
    const float* __restrict__ b1, float* __restrict__ g1, int N)
{
    __shared__ float2 accs[3][64];
    __shared__ float  dens[3][2];
    const int v = blockIdx.x;
    const int tid = threadIdx.x;
    const int slot = tid >> 6, dp = tid & 63, head = dp >> 5;
    const int beg = rowptr[v], end = rowptr[v + 1];

    float a0 = 0.f, a1 = 0.f, den = 0.f;
    for (int i = beg + slot; i < end; i += 4) {
        int src = csr_src[i];
        float w = wcsr[2 * i + head];
        ushort2 hv = h1[(size_t)src * 64 + dp];
        a0 = fmaf(w, bf2f(hv.x), a0);
        a1 = fmaf(w, bf2f(hv.y), a1);
        den += w;
    }
    if (slot > 0) {
        accs[slot - 1][dp] = make_float2(a0, a1);
        if (dp == 0 || dp == 32) dens[slot - 1][head] = den;
    }
    __syncthreads();
    if (slot == 0) {
        #pragma unroll
        for (int s = 0; s < 3; s++) {
            float2 t = accs[s][dp];
            a0 += t.x; a1 += t.y;
            den += dens[s][head];
        }
        float inv = 1.f / (den + 1e-16f);
        float2 o;
        o.x = fmaxf(fmaf(a0, inv, b1[2 * dp]),     0.f);
        o.y = fmaxf(fmaf(a1, inv, b1[2 * dp + 1]), 0.f);
        ((float2*)g1)[(size_t)v * 64 + dp] = o;
    }
}

// ---------------- h2 = g1 @ W2; layer-2 attention scalars ----------------
__global__ __launch_bounds__(128) void gat2_proj_kernel(
    const float* __restrict__ g1,
    const float* __restrict__ W2, const float* __restrict__ att_src2, const float* __restrict__ att_dst2,
    float* __restrict__ h2, float* __restrict__ a_s2, float* __restrict__ a_d2, int N)
{
    __shared__ float gs[8][128];
    const int tid = threadIdx.x;
    const int n0 = blockIdx.x * 8;
    for (int r = 0; r < 8; r++) {
        int row = n0 + r;
        gs[r][tid] = (row < N) ? g1[(size_t)row * 128 + tid] : 0.f;
    }
    __syncthreads();

    const int rs = tid >> 4, cs = tid & 15;
    float hacc = 0.f;
    for (int k = 0; k < 128; k++) hacc = fmaf(gs[rs][k], W2[k * 16 + cs], hacc);

    int row = n0 + rs;
    float ps = hacc * att_src2[cs], pd = hacc * att_dst2[cs];
    #pragma unroll
    for (int off = 8; off > 0; off >>= 1) {
        ps += __shfl_down(ps, off, 16);
        pd += __shfl_down(pd, off, 16);
    }
    if (row < N) {
        h2[(size_t)row * 16 + cs] = hacc;
        if (cs == 0) { a_s2[row] = ps; a_d2[row] = pd; }
    }
}

// ---------------- layer-2 gather (masked nodes): 1 wave/node, 4 slots x 16 dims ----------------
__global__ __launch_bounds__(256) void gat2_gather_kernel(
    const int* __restrict__ rowptr, const int* __restrict__ csr_src,
    const float* __restrict__ h2,
    const float* __restrict__ a_s2, const float* __restrict__ a_d2,
    const float* __restrict__ b2, const int* __restrict__ mask,
    float* __restrict__ g2m, int M)
{
    const int tid = threadIdx.x;
    const int m = blockIdx.x * 4 + (tid >> 6);
    if (m >= M) return;
    const int lane = tid & 63, slot = lane >> 4, c = lane & 15;
    const int v = mask[m];
    const float adv = a_d2[v];
    const int beg = rowptr[v], end = rowptr[v + 1];
    float acc = 0.f, den = 0.f;
    for (int i = beg + slot; i < end; i += 4) {
        int src = csr_src[i];
        float e = a_s2[src] + adv;
        float w = __expf(e > 0.f ? e : 0.2f * e);
        den += w;
        acc = fmaf(w, h2[(size_t)src * 16 + c], acc);
    }
    acc += __shfl_xor(acc, 16, 64);
    acc += __shfl_xor(acc, 32, 64);
    den += __shfl_xor(den, 16, 64);
    den += __shfl_xor(den, 32, 64);
    if (slot == 0) g2m[(size_t)m * 16 + c] = acc / (den + 1e-16f) + b2[c];
}

// ---------------- fused head ----------------
__global__ __launch_bounds__(64) void final_kernel(
    const float* __restrict__ text_out, const float* __restrict__ g2m,
    const float* __restrict__ fcf_w, const float* __restrict__ fcf_b,
    float* __restrict__ out, int M)
{
    const int lane = threadIdx.x;
    const int g = lane >> 4, j = lane & 15;
    const int m = blockIdx.x * 4 + g;
    if (m >= M) return;

    float tval = text_out[(size_t)m * 16 + j];
    float gval = g2m[(size_t)m * 16 + j];

    float logit = fcf_b[j];
    #pragma unroll
    for (int k = 0; k < 16; k++) {
        logit = fmaf(__shfl(tval, k, 16), fcf_w[k * 16 + j], logit);
        logit = fmaf(__shfl(gval, k, 16), fcf_w[(16 + k) * 16 + j], logit);
    }
    float mx = logit;
    #pragma unroll
    for (int off = 8; off > 0; off >>= 1) mx = fmaxf(mx, __shfl_xor(mx, off, 16));
    float se = expf(logit - mx);
    #pragma unroll
    for (int off = 8; off > 0; off >>= 1) se += __shfl_xor(se, off, 16);
    out[(size_t)m * 16 + j] = logit - mx - logf(se);
}

extern "C" void kernel_launch(void* const* d_in, const int* in_sizes, int n_in,
                              void* d_out, int out_size, void* d_ws, size_t ws_size,
                              hipStream_t stream)
{
    const float* text  = (const float*)d_in[0];
    const float* x     = (const float*)d_in[1];
    const int*   ei    = (const int*)  d_in[2];
    const int*   mask  = (const int*)  d_in[3];
    const float* fc1_w = (const float*)d_in[4];  const float* fc1_b = (const float*)d_in[5];
    const float* fc2_w = (const float*)d_in[6];  const float* fc2_b = (const float*)d_in[7];
    const float* fc3_w = (const float*)d_in[8];  const float* fc3_b = (const float*)d_in[9];
    const float* fc4_w = (const float*)d_in[10]; const float* fc4_b = (const float*)d_in[11];
    const float* sc_w  = (const float*)d_in[12]; const float* sc_b  = (const float*)d_in[13];
    const float* W1    = (const float*)d_in[14];
    const float* as1w  = (const float*)d_in[15]; const float* ad1w  = (const float*)d_in[16];
    const float* b1    = (const float*)d_in[17];
    const float* W2    = (const float*)d_in[18];
    const float* as2w  = (const float*)d_in[19]; const float* ad2w  = (const float*)d_in[20];
    const float* b2    = (const float*)d_in[21];
    const float* fcf_w = (const float*)d_in[22]; const float* fcf_b = (const float*)d_in[23];

    const int M  = in_sizes[3];
    const int N  = in_sizes[1] / GNN_DIM;
    const int E  = in_sizes[2] / 2;
    const int EP = E + N;
    const int* esrc = ei;
    const int* edst = ei + E;

    const int Mp = ((M + 63) / 64) * 64;   // 10048
    const int Np = ((N + 63) / 64) * 64;   // 50048

    float* ws = (float*)d_ws;
    size_t off = 0;
    auto alloc = [&](size_t n) { float* p = ws + off; off += (n + 63) & ~size_t(63); return p; };

    unsigned short* h1    = (unsigned short*)alloc((size_t)Np * 64);   // bf16 [Np x 128]
    unsigned short* textb = (unsigned short*)alloc((size_t)Mp * 256);  // bf16 [Mp x 512]
    unsigned short* xb    = (unsigned short*)alloc((size_t)Np * 64);   // bf16 [Np x 128]
    unsigned short* w1cat = (unsigned short*)alloc(144 * 256);         // bf16 [144 x 512]
    unsigned short* w1g   = (unsigned short*)alloc(128 * 64);          // bf16 [128 x 128]
    float* t1       = alloc((size_t)M * 128);
    float* tsc      = alloc((size_t)M * 16);
    float* g1       = alloc((size_t)N * 128);
    float* a_s1     = alloc((size_t)2 * N);
    float* a_d1     = alloc((size_t)2 * N);
    float* h2       = alloc((size_t)N * 16);
    float* a_s2     = alloc(N);
    float* a_d2     = alloc(N);
    float* text_out = alloc((size_t)M * 16);
    float* g2m      = alloc((size_t)M * 16);
    float* wcsr1    = alloc((size_t)2 * EP);
    int* deg        = (int*)alloc(N);
    int* cursor     = (int*)alloc(N);
    int* rowptr     = (int*)alloc(N + 1);
    int* csr_src    = (int*)alloc(EP);

    // --- CSR degree/scan (edge index only) ---
    deg_init_kernel<<<(N + 255) / 256, 256, 0, stream>>>(deg, N);
    deg_hist_kernel<<<(E + 255) / 256, 256, 0, stream>>>(edst, deg, E);
    scan_kernel<<<1, SCAN_T, 0, stream>>>(deg, rowptr, N);

    // --- conversions ---
    conv_x_kernel<<<Np / 8, 256, 0, stream>>>(x, xb, N, Np);
    conv_w_kernel<<<(144 * 512 + 128 * 128 + 255) / 256, 256, 0, stream>>>(
        fc1_w, sc_w, W1, w1cat, w1g);
    conv_text_kernel<<<Mp / 2, 256, 0, stream>>>(text, textb, M, Mp);

    // --- GAT1 projection (MFMA) + attention scalars ---
    {
        dim3 grid(Np / 64, 8);
        gemm_h1_kernel<<<grid, 256, 0, stream>>>((const short*)xb, (const short*)w1g, h1, N);
    }
    attn1_kernel<<<(N + 3) / 4, 256, 0, stream>>>(
        (const ushort2*)h1, as1w, ad1w, a_s1, a_d1, N);

    // --- CSR fill with fused layer-1 edge weights ---
    cursor_init_kernel<<<(N + 255) / 256, 256, 0, stream>>>(
        rowptr, cursor, csr_src, wcsr1, a_s1, a_d1, N);
    fill_kernel<<<(E + 255) / 256, 256, 0, stream>>>(
        esrc, edst, cursor, csr_src, wcsr1, a_s1, a_d1, E);

    // --- text branch: MFMA fc1+shortcut, then tail ---
    {
        dim3 grid(Mp / 64, 9);
        gemm_text_kernel<<<grid, 256, 0, stream>>>(
            (const short*)textb, (const short*)w1cat, fc1_b, sc_b, t1, tsc, M);
    }
    text_tail_kernel<<<(M + 7) / 8, 128, 0, stream>>>(
        t1, tsc, fc2_w, fc2_b, fc3_w, fc3_b, fc4_w, fc4_b, text_out, M);

    // --- GNN aggregation / second layer ---
    gat1_gather_kernel<<<N, 256, 0, stream>>>(
        rowptr, csr_src, wcsr1, (const ushort2*)h1, b1, g1, N);

    gat2_proj_kernel<<<(N + 7) / 8, 128, 0, stream>>>(
        g1, W2, as2w, ad2w, h2, a_s2, a_d2, N);

    gat2_gather_kernel<<<(M + 3) / 4, 256, 0, stream>>>(
        rowptr, csr_src, h2, a_s2, a_d2, b2, mask, g2m, M);

    final_kernel<<<(M + 3) / 4, 64, 0, stream>>>(
        text_out, g2m, fcf_w, fcf_b, (float*)d_out, M);
}

// Round 5
// 331.963 us; speedup vs baseline: 2.1051x; 1.1629x over previous
//
#include <hip/hip_runtime.h>
#include <hip/hip_bf16.h>
#include <cmath>

#define TEXTD 500
#define GNN_DIM 128

typedef __attribute__((ext_vector_type(8))) short bf16x8;
typedef __attribute__((ext_vector_type(4))) float f32x4;

__device__ __forceinline__ float bf2f(unsigned short u) {
    union { unsigned int i; float f; } cv;
    cv.i = ((unsigned int)u) << 16;
    return cv.f;
}
__device__ __forceinline__ unsigned short f2b(float x) {
    __hip_bfloat16 b = __float2bfloat16(x);
    return *reinterpret_cast<unsigned short*>(&b);
}
// convert 8 consecutive floats at p (16B-aligned) to a bf16x8 fragment
__device__ __forceinline__ bf16x8 cvt8(const float* p) {
    float4 u = *(const float4*)p;
    float4 v = *(const float4*)(p + 4);
    bf16x8 f;
    f[0] = (short)f2b(u.x); f[1] = (short)f2b(u.y);
    f[2] = (short)f2b(u.z); f[3] = (short)f2b(u.w);
    f[4] = (short)f2b(v.x); f[5] = (short)f2b(v.y);
    f[6] = (short)f2b(v.z); f[7] = (short)f2b(v.w);
    return f;
}

// ---------------- weight conversion: w1cat [144x512], w1g [128x128], w2t [16x128] ----------------
__global__ __launch_bounds__(256) void conv_w_kernel(
    const float* __restrict__ fc1_w, const float* __restrict__ sc_w,
    const float* __restrict__ W1, const float* __restrict__ W2,
    unsigned short* __restrict__ w1cat, unsigned short* __restrict__ w1g,
    unsigned short* __restrict__ w2t)
{
    int idx = blockIdx.x * 256 + threadIdx.x;
    if (idx < 144 * 512) {
        int n = idx >> 9, k = idx & 511;
        float v = 0.f;
        if (k < TEXTD) v = (n < 128) ? fc1_w[k * 128 + n] : sc_w[k * 16 + (n - 128)];
        w1cat[idx] = f2b(v);
    } else if (idx < 144 * 512 + 128 * 128) {
        int j = idx - 144 * 512;
        int n = j >> 7, k = j & 127;
        w1g[j] = f2b(W1[k * 128 + n]);
    } else if (idx < 144 * 512 + 128 * 128 + 16 * 128) {
        int j = idx - (144 * 512 + 128 * 128);
        int n = j >> 7, k = j & 127;
        w2t[j] = f2b(W2[k * 16 + n]);
    }
}

// ---------------- GEMM1: text[fp32, Mx500] x w1cat[144x512]^T -> t1(relu+b), tsc(+b) ----------------
__global__ __launch_bounds__(256) void gemm_text_kernel(
    const float* __restrict__ text, const short* __restrict__ B,
    const float* __restrict__ fc1_b, const float* __restrict__ sc_b,
    float* __restrict__ t1, float* __restrict__ tsc, int M)
{
    const int tid = threadIdx.x;
    const int wave = tid >> 6, lane = tid & 63;
    const int q = lane >> 4, col = lane & 15;
    const int mb = blockIdx.x * 64 + wave * 16;
    const int arow = min(mb + col, M - 1);
    const float* ap = text + (size_t)arow * TEXTD + q * 8;

    bf16x8 afrag[16];
    #pragma unroll
    for (int ks = 0; ks < 15; ks++) afrag[ks] = cvt8(ap + ks * 32);
    {   // ks = 15: K 480..511, zero-pad past 500
        bf16x8 f;
        int k0 = 480 + q * 8;
        #pragma unroll
        for (int e = 0; e < 8; e++) {
            int k = k0 + e;
            f[e] = (short)((k < TEXTD) ? f2b(text[(size_t)arow * TEXTD + k]) : 0);
        }
        afrag[15] = f;
    }

    for (int nb = 0; nb < 9; nb++) {
        const short* bp = B + (size_t)(nb * 16 + col) * 512 + q * 8;
        f32x4 acc = {0.f, 0.f, 0.f, 0.f};
        #pragma unroll
        for (int ks = 0; ks < 16; ks++)
            acc = __builtin_amdgcn_mfma_f32_16x16x32_bf16(afrag[ks], *(const bf16x8*)(bp + ks * 32), acc, 0, 0, 0);
        #pragma unroll
        for (int i = 0; i < 4; i++) {
            int row = mb + q * 4 + i;
            if (row < M) {
                if (nb < 8) t1[(size_t)row * 128 + nb * 16 + col] = fmaxf(acc[i] + fc1_b[nb * 16 + col], 0.f);
                else        tsc[(size_t)row * 16 + col] = acc[i] + sc_b[col];
            }
        }
    }
}

// ---------------- GEMM2: x[fp32, Nx128] @ W1 -> h1 bf16; fused a_s1/a_d1 epilogue ----------------
__global__ __launch_bounds__(256) void gemm_h1_kernel(
    const float* __restrict__ x, const short* __restrict__ B,
    const float* __restrict__ as1w, const float* __restrict__ ad1w,
    unsigned short* __restrict__ h1, float* __restrict__ a_s, float* __restrict__ a_d, int N)
{
    const int tid = threadIdx.x;
    const int wave = tid >> 6, lane = tid & 63;
    const int q = lane >> 4, col = lane & 15;
    const int mb = blockIdx.x * 64 + wave * 16;
    const int arow = min(mb + col, N - 1);
    const float* ap = x + (size_t)arow * 128 + q * 8;

    bf16x8 afrag[4];
    #pragma unroll
    for (int ks = 0; ks < 4; ks++) afrag[ks] = cvt8(ap + ks * 32);

    float ps0[4] = {0,0,0,0}, ps1[4] = {0,0,0,0};
    float pd0[4] = {0,0,0,0}, pd1[4] = {0,0,0,0};

    #pragma unroll
    for (int nb = 0; nb < 8; nb++) {
        const short* bp = B + (size_t)(nb * 16 + col) * 128 + q * 8;
        f32x4 acc = {0.f, 0.f, 0.f, 0.f};
        #pragma unroll
        for (int ks = 0; ks < 4; ks++)
            acc = __builtin_amdgcn_mfma_f32_16x16x32_bf16(afrag[ks], *(const bf16x8*)(bp + ks * 32), acc, 0, 0, 0);
        const int j = nb * 16 + col;
        const float asj = as1w[j], adj = ad1w[j];
        #pragma unroll
        for (int i = 0; i < 4; i++) {
            int row = mb + q * 4 + i;
            if (row < N) h1[(size_t)row * 128 + j] = f2b(acc[i]);
            if (nb < 4) { ps0[i] = fmaf(acc[i], asj, ps0[i]); pd0[i] = fmaf(acc[i], adj, pd0[i]); }
            else        { ps1[i] = fmaf(acc[i], asj, ps1[i]); pd1[i] = fmaf(acc[i], adj, pd1[i]); }
        }
    }
    #pragma unroll
    for (int i = 0; i < 4; i++) {
        float v0 = ps0[i], v1 = ps1[i], w0 = pd0[i], w1 = pd1[i];
        #pragma unroll
        for (int off = 1; off < 16; off <<= 1) {
            v0 += __shfl_xor(v0, off, 16);
            v1 += __shfl_xor(v1, off, 16);
            w0 += __shfl_xor(w0, off, 16);
            w1 += __shfl_xor(w1, off, 16);
        }
        int row = mb + q * 4 + i;
        if (col == 0 && row < N) {
            a_s[2 * row] = v0; a_s[2 * row + 1] = v1;
            a_d[2 * row] = w0; a_d[2 * row + 1] = w1;
        }
    }
}

// ---------------- text tail: fc2/fc3/fc4 + shortcut ----------------
__global__ __launch_bounds__(128) void text_tail_kernel(
    const float* __restrict__ t1g, const float* __restrict__ tsc,
    const float* __restrict__ fc2_w, const float* __restrict__ fc2_b,
    const float* __restrict__ fc3_w, const float* __restrict__ fc3_b,
    const float* __restrict__ fc4_w, const float* __restrict__ fc4_b,
    float* __restrict__ text_out, int M)
{
    __shared__ float t1[8][128];
    __shared__ float t2[8][64];
    __shared__ float t3[8][16];
    const int tid = threadIdx.x;
    const int m0 = blockIdx.x * 8;

    for (int r = 0; r < 8; r++) {
        int row = m0 + r;
        t1[r][tid] = (row < M) ? t1g[(size_t)row * 128 + tid] : 0.f;
    }
    __syncthreads();

    const int r2 = tid >> 6, c2 = tid & 63;
    for (int rb = 0; rb < 4; rb++) {
        int row = rb * 2 + r2;
        float a2 = fc2_b[c2];
        for (int k = 0; k < 128; k++) a2 = fmaf(t1[row][k], fc2_w[k * 64 + c2], a2);
        t2[row][c2] = fmaxf(a2, 0.f);
    }
    __syncthreads();

    const int rs = tid >> 4, cs = tid & 15;
    float a3 = fc3_b[cs];
    for (int k = 0; k < 64; k++) a3 = fmaf(t2[rs][k], fc3_w[k * 16 + cs], a3);
    t3[rs][cs] = fmaxf(a3, 0.f);
    __syncthreads();

    float a4 = fc4_b[cs];
    #pragma unroll
    for (int k = 0; k < 16; k++) a4 = fmaf(t3[rs][k], fc4_w[k * 16 + cs], a4);
    int row = m0 + rs;
    if (row < M) text_out[(size_t)row * 16 + cs] = a4 + tsc[(size_t)row * 16 + cs];
}

// ---------------- CSR build ----------------
__global__ __launch_bounds__(256) void deg_init_kernel(int* __restrict__ deg, int N)
{
    int v = blockIdx.x * 256 + threadIdx.x;
    if (v < N) deg[v] = 1;
}

__global__ __launch_bounds__(256) void deg_hist_kernel(
    const int* __restrict__ edst, int* __restrict__ deg, int E)
{
    int e = blockIdx.x * 256 + threadIdx.x;
    if (e < E) atomicAdd(&deg[edst[e]], 1);
}

#define SCAN_T 256
__global__ __launch_bounds__(SCAN_T) void scan_kernel(
    const int* __restrict__ deg, int* __restrict__ rowptr, int N)
{
    __shared__ int part[SCAN_T];
    const int tid = threadIdx.x;
    const int chunk = (N + SCAN_T - 1) / SCAN_T;
    const int beg = tid * chunk;
    const int end = min(beg + chunk, N);
    int s = 0;
    for (int i = beg; i < end; i++) s += deg[i];
    part[tid] = s;
    for (int off = 1; off < SCAN_T; off <<= 1) {
        __syncthreads();
        int val = (tid >= off) ? part[tid - off] : 0;
        __syncthreads();
        part[tid] += val;
    }
    __syncthreads();
    int excl = (tid == 0) ? 0 : part[tid - 1];
    for (int i = beg; i < end; i++) { rowptr[i] = excl; excl += deg[i]; }
    if (tid == SCAN_T - 1) rowptr[N] = excl;
}

__global__ __launch_bounds__(256) void cursor_init_kernel(
    const int* __restrict__ rowptr, int* __restrict__ cursor,
    int* __restrict__ csr_src, int N)
{
    int v = blockIdx.x * 256 + threadIdx.x;
    if (v < N) {
        int p = rowptr[v];
        csr_src[p] = v;            // self-loop in slot 0
        cursor[v] = p + 1;
    }
}

__global__ __launch_bounds__(256) void fill_kernel(
    const int* __restrict__ esrc, const int* __restrict__ edst,
    int* __restrict__ cursor, int* __restrict__ csr_src, int E)
{
    int e = blockIdx.x * 256 + threadIdx.x;
    if (e < E) {
        int pos = atomicAdd(&cursor[edst[e]], 1);
        csr_src[pos] = esrc[e];
    }
}

// ---------------- layer-1 gather: 1 node/block, 4 slots x 64 dim-pairs, 8-deep MLP prefetch ----------------
__global__ __launch_bounds__(256) void gat1_gather_kernel(
    const int* __restrict__ rowptr, const int* __restrict__ csr_src,
    const float* __restrict__ a_s, const float* __restrict__ a_d,
    const ushort2* __restrict__ h1, const float* __restrict__ b1,
    unsigned int* __restrict__ g1b, int N)
{
    __shared__ float2 accs[3][64];
    __shared__ float  dens[3][2];
    const int v = blockIdx.x;
    const int tid = threadIdx.x;
    const int slot = tid >> 6, dp = tid & 63, head = dp >> 5;
    const int beg = rowptr[v], end = rowptr[v + 1];
    const int i0 = beg + slot;
    const float adv = a_d[2 * v + head];

    float a0 = 0.f, a1 = 0.f, den = 0.f;

    // static batch of 8 (covers deg <= 32), index-clamped, weight-masked
    int   idxs[8];
    float msk[8], as_[8];
    ushort2 hv[8];
    #pragma unroll
    for (int k = 0; k < 8; k++) {
        int i = i0 + 4 * k;
        int ic = min(i, end - 1);
        idxs[k] = csr_src[ic];
        msk[k] = (i < end) ? 1.f : 0.f;
    }
    #pragma unroll
    for (int k = 0; k < 8; k++) as_[k] = a_s[2 * idxs[k] + head];
    #pragma unroll
    for (int k = 0; k < 8; k++) hv[k] = h1[(size_t)idxs[k] * 64 + dp];
    #pragma unroll
    for (int k = 0; k < 8; k++) {
        float e = as_[k] + adv;
        float w = msk[k] * __expf(e > 0.f ? e : 0.2f * e);
        den += w;
        a0 = fmaf(w, bf2f(hv[k].x), a0);
        a1 = fmaf(w, bf2f(hv[k].y), a1);
    }
    // tail (deg > 32)
    for (int i = i0 + 32; i < end; i += 4) {
        int src = csr_src[i];
        float e = a_s[2 * src + head] + adv;
        float w = __expf(e > 0.f ? e : 0.2f * e);
        ushort2 t = h1[(size_t)src * 64 + dp];
        den += w;
        a0 = fmaf(w, bf2f(t.x), a0);
        a1 = fmaf(w, bf2f(t.y), a1);
    }

    if (slot > 0) {
        accs[slot - 1][dp] = make_float2(a0, a1);
        if (dp == 0 || dp == 32) dens[slot - 1][head] = den;
    }
    __syncthreads();
    if (slot == 0) {
        #pragma unroll
        for (int s = 0; s < 3; s++) {
            float2 t = accs[s][dp];
            a0 += t.x; a1 += t.y;
            den += dens[s][head];
        }
        float inv = 1.f / (den + 1e-16f);
        float o0 = fmaxf(fmaf(a0, inv, b1[2 * dp]),     0.f);
        float o1 = fmaxf(fmaf(a1, inv, b1[2 * dp + 1]), 0.f);
        g1b[(size_t)v * 64 + dp] = ((unsigned int)f2b(o1) << 16) | f2b(o0);
    }
}

// ---------------- gat2 projection (MFMA): h2 = g1b @ W2; fused a_s2/a_d2 ----------------
__global__ __launch_bounds__(256) void gat2_proj_kernel(
    const unsigned short* __restrict__ g1b, const short* __restrict__ w2t,
    const float* __restrict__ as2w, const float* __restrict__ ad2w,
    float* __restrict__ h2, float* __restrict__ a_s2, float* __restrict__ a_d2, int N)
{
    const int tid = threadIdx.x;
    const int wave = tid >> 6, lane = tid & 63;
    const int q = lane >> 4, col = lane & 15;
    const int mb = blockIdx.x * 64 + wave * 16;
    const int arow = min(mb + col, N - 1);
    const short* ap = (const short*)g1b + (size_t)arow * 128 + q * 8;
    const short* bp = w2t + (size_t)col * 128 + q * 8;

    f32x4 acc = {0.f, 0.f, 0.f, 0.f};
    #pragma unroll
    for (int ks = 0; ks < 4; ks++)
        acc = __builtin_amdgcn_mfma_f32_16x16x32_bf16(
            *(const bf16x8*)(ap + ks * 32), *(const bf16x8*)(bp + ks * 32), acc, 0, 0, 0);

    const float asj = as2w[col], adj = ad2w[col];
    #pragma unroll
    for (int i = 0; i < 4; i++) {
        int row = mb + q * 4 + i;
        float ps = acc[i] * asj, pd = acc[i] * adj;
        #pragma unroll
        for (int off = 1; off < 16; off <<= 1) {
            ps += __shfl_xor(ps, off, 16);
            pd += __shfl_xor(pd, off, 16);
        }
        if (row < N) {
            h2[(size_t)row * 16 + col] = acc[i];
            if (col == 0) { a_s2[row] = ps; a_d2[row] = pd; }
        }
    }
}

// ---------------- layer-2 gather (masked): 4 nodes/block, 4 slots x 16 dims, MLP-8 prefetch ----------------
__global__ __launch_bounds__(256) void gat2_gather_kernel(
    const int* __restrict__ rowptr, const int* __restrict__ csr_src,
    const float* __restrict__ h2,
    const float* __restrict__ a_s2, const float* __restrict__ a_d2,
    const float* __restrict__ b2, const int* __restrict__ mask,
    float* __restrict__ g2m, int M)
{
    const int tid = threadIdx.x;
    const int m = blockIdx.x * 4 + (tid >> 6);
    if (m >= M) return;
    const int lane = tid & 63, slot = lane >> 4, c = lane & 15;
    const int v = mask[m];
    const float adv = a_d2[v];
    const int beg = rowptr[v], end = rowptr[v + 1];
    const int i0 = beg + slot;

    float acc = 0.f, den = 0.f;
    int   idxs[8];
    float msk[8], as_[8], hval[8];
    #pragma unroll
    for (int k = 0; k < 8; k++) {
        int i = i0 + 4 * k;
        int ic = min(i, end - 1);
        idxs[k] = csr_src[ic];
        msk[k] = (i < end) ? 1.f : 0.f;
    }
    #pragma unroll
    for (int k = 0; k < 8; k++) as_[k] = a_s2[idxs[k]];
    #pragma unroll
    for (int k = 0; k < 8; k++) hval[k] = h2[(size_t)idxs[k] * 16 + c];
    #pragma unroll
    for (int k = 0; k < 8; k++) {
        float e = as_[k] + adv;
        float w = msk[k] * __expf(e > 0.f ? e : 0.2f * e);
        den += w;
        acc = fmaf(w, hval[k], acc);
    }
    for (int i = i0 + 32; i < end; i += 4) {
        int src = csr_src[i];
        float e = a_s2[src] + adv;
        float w = __expf(e > 0.f ? e : 0.2f * e);
        den += w;
        acc = fmaf(w, h2[(size_t)src * 16 + c], acc);
    }

    acc += __shfl_xor(acc, 16, 64);
    acc += __shfl_xor(acc, 32, 64);
    den += __shfl_xor(den, 16, 64);
    den += __shfl_xor(den, 32, 64);
    if (slot == 0) g2m[(size_t)m * 16 + c] = acc / (den + 1e-16f) + b2[c];
}

// ---------------- fused head ----------------
__global__ __launch_bounds__(64) void final_kernel(
    const float* __restrict__ text_out, const float* __restrict__ g2m,
    const float* __restrict__ fcf_w, const float* __restrict__ fcf_b,
    float* __restrict__ out, int M)
{
    const int lane = threadIdx.x;
    const int g = lane >> 4, j = lane & 15;
    const int m = blockIdx.x * 4 + g;
    if (m >= M) return;

    float tval = text_out[(size_t)m * 16 + j];
    float gval = g2m[(size_t)m * 16 + j];

    float logit = fcf_b[j];
    #pragma unroll
    for (int k = 0; k < 16; k++) {
        logit = fmaf(__shfl(tval, k, 16), fcf_w[k * 16 + j], logit);
        logit = fmaf(__shfl(gval, k, 16), fcf_w[(16 + k) * 16 + j], logit);
    }
    float mx = logit;
    #pragma unroll
    for (int off = 8; off > 0; off >>= 1) mx = fmaxf(mx, __shfl_xor(mx, off, 16));
    float se = expf(logit - mx);
    #pragma unroll
    for (int off = 8; off > 0; off >>= 1) se += __shfl_xor(se, off, 16);
    out[(size_t)m * 16 + j] = logit - mx - logf(se);
}

extern "C" void kernel_launch(void* const* d_in, const int* in_sizes, int n_in,
                              void* d_out, int out_size, void* d_ws, size_t ws_size,
                              hipStream_t stream)
{
    const float* text  = (const float*)d_in[0];
    const float* x     = (const float*)d_in[1];
    const int*   ei    = (const int*)  d_in[2];
    const int*   mask  = (const int*)  d_in[3];
    const float* fc1_w = (const float*)d_in[4];  const float* fc1_b = (const float*)d_in[5];
    const float* fc2_w = (const float*)d_in[6];  const float* fc2_b = (const float*)d_in[7];
    const float* fc3_w = (const float*)d_in[8];  const float* fc3_b = (const float*)d_in[9];
    const float* fc4_w = (const float*)d_in[10]; const float* fc4_b = (const float*)d_in[11];
    const float* sc_w  = (const float*)d_in[12]; const float* sc_b  = (const float*)d_in[13];
    const float* W1    = (const float*)d_in[14];
    const float* as1w  = (const float*)d_in[15]; const float* ad1w  = (const float*)d_in[16];
    const float* b1    = (const float*)d_in[17];
    const float* W2    = (const float*)d_in[18];
    const float* as2w  = (const float*)d_in[19]; const float* ad2w  = (const float*)d_in[20];
    const float* b2    = (const float*)d_in[21];
    const float* fcf_w = (const float*)d_in[22]; const float* fcf_b = (const float*)d_in[23];

    const int M  = in_sizes[3];
    const int N  = in_sizes[1] / GNN_DIM;
    const int E  = in_sizes[2] / 2;
    const int EP = E + N;
    const int* esrc = ei;
    const int* edst = ei + E;

    const int Mp = ((M + 63) / 64) * 64;
    const int Np = ((N + 63) / 64) * 64;

    float* ws = (float*)d_ws;
    size_t off = 0;
    auto alloc = [&](size_t n) { float* p = ws + off; off += (n + 63) & ~size_t(63); return p; };

    unsigned short* h1    = (unsigned short*)alloc((size_t)Np * 64);   // bf16 [Np x 128]
    unsigned int*   g1b   = (unsigned int*)  alloc((size_t)N * 64);    // bf16 [N x 128] packed
    unsigned short* w1cat = (unsigned short*)alloc(144 * 256);         // bf16 [144 x 512]
    unsigned short* w1g   = (unsigned short*)alloc(128 * 64);          // bf16 [128 x 128]
    unsigned short* w2t   = (unsigned short*)alloc(16 * 64);           // bf16 [16 x 128]
    float* t1       = alloc((size_t)M * 128);
    float* tsc      = alloc((size_t)M * 16);
    float* a_s1     = alloc((size_t)2 * N);
    float* a_d1     = alloc((size_t)2 * N);
    float* h2       = alloc((size_t)N * 16);
    float* a_s2     = alloc(N);
    float* a_d2     = alloc(N);
    float* text_out = alloc((size_t)M * 16);
    float* g2m      = alloc((size_t)M * 16);
    int* deg        = (int*)alloc(N);
    int* cursor     = (int*)alloc(N);
    int* rowptr     = (int*)alloc(N + 1);
    int* csr_src    = (int*)alloc(EP);

    // --- CSR build (index-only; independent of features) ---
    deg_init_kernel<<<(N + 255) / 256, 256, 0, stream>>>(deg, N);
    deg_hist_kernel<<<(E + 255) / 256, 256, 0, stream>>>(edst, deg, E);
    scan_kernel<<<1, SCAN_T, 0, stream>>>(deg, rowptr, N);
    cursor_init_kernel<<<(N + 255) / 256, 256, 0, stream>>>(rowptr, cursor, csr_src, N);
    fill_kernel<<<(E + 255) / 256, 256, 0, stream>>>(esrc, edst, cursor, csr_src, E);

    // --- weights to bf16 ---
    conv_w_kernel<<<(144 * 512 + 128 * 128 + 16 * 128 + 255) / 256, 256, 0, stream>>>(
        fc1_w, sc_w, W1, W2, w1cat, w1g, w2t);

    // --- text branch ---
    gemm_text_kernel<<<Mp / 64, 256, 0, stream>>>(
        text, (const short*)w1cat, fc1_b, sc_b, t1, tsc, M);
    text_tail_kernel<<<(M + 7) / 8, 128, 0, stream>>>(
        t1, tsc, fc2_w, fc2_b, fc3_w, fc3_b, fc4_w, fc4_b, text_out, M);

    // --- GNN branch ---
    gemm_h1_kernel<<<Np / 64, 256, 0, stream>>>(
        x, (const short*)w1g, as1w, ad1w, h1, a_s1, a_d1, N);

    gat1_gather_kernel<<<N, 256, 0, stream>>>(
        rowptr, csr_src, a_s1, a_d1, (const ushort2*)h1, b1, g1b, N);

    gat2_proj_kernel<<<Np / 64, 256, 0, stream>>>(
        (const unsigned short*)g1b, (const short*)w2t, as2w, ad2w, h2, a_s2, a_d2, N);

    gat2_gather_kernel<<<(M + 3) / 4, 256, 0, stream>>>(
        rowptr, csr_src, h2, a_s2, a_d2, b2, mask, g2m, M);

    final_kernel<<<(M + 3) / 4, 64, 0, stream>>>(
        text_out, g2m, fcf_w, fcf_b, (float*)d_out, M);
}

// Round 6
// 262.814 us; speedup vs baseline: 2.6589x; 1.2631x over previous
//
#include <hip/hip_runtime.h>
#include <hip/hip_bf16.h>
#include <cmath>

#define TEXTD 500
#define GNN_DIM 128

typedef __attribute__((ext_vector_type(8))) short bf16x8;
typedef __attribute__((ext_vector_type(4))) float f32x4;

__device__ __forceinline__ float bf2f(unsigned short u) {
    union { unsigned int i; float f; } cv;
    cv.i = ((unsigned int)u) << 16;
    return cv.f;
}
__device__ __forceinline__ unsigned short f2b(float x) {
    __hip_bfloat16 b = __float2bfloat16(x);
    return *reinterpret_cast<unsigned short*>(&b);
}
// convert 8 consecutive floats at p (16B-aligned) to a bf16x8 fragment
__device__ __forceinline__ bf16x8 cvt8(const float* p) {
    float4 u = *(const float4*)p;
    float4 v = *(const float4*)(p + 4);
    bf16x8 f;
    f[0] = (short)f2b(u.x); f[1] = (short)f2b(u.y);
    f[2] = (short)f2b(u.z); f[3] = (short)f2b(u.w);
    f[4] = (short)f2b(v.x); f[5] = (short)f2b(v.y);
    f[6] = (short)f2b(v.z); f[7] = (short)f2b(v.w);
    return f;
}

// ---------------- weight conversion: w1cat [144x512], w1g [128x128], w2t [16x128] ----------------
__global__ __launch_bounds__(256) void conv_w_kernel(
    const float* __restrict__ fc1_w, const float* __restrict__ sc_w,
    const float* __restrict__ W1, const float* __restrict__ W2,
    unsigned short* __restrict__ w1cat, unsigned short* __restrict__ w1g,
    unsigned short* __restrict__ w2t)
{
    int idx = blockIdx.x * 256 + threadIdx.x;
    if (idx < 144 * 512) {
        int n = idx >> 9, k = idx & 511;
        float v = 0.f;
        if (k < TEXTD) v = (n < 128) ? fc1_w[k * 128 + n] : sc_w[k * 16 + (n - 128)];
        w1cat[idx] = f2b(v);
    } else if (idx < 144 * 512 + 128 * 128) {
        int j = idx - 144 * 512;
        int n = j >> 7, k = j & 127;
        w1g[j] = f2b(W1[k * 128 + n]);
    } else if (idx < 144 * 512 + 128 * 128 + 16 * 128) {
        int j = idx - (144 * 512 + 128 * 128);
        int n = j >> 7, k = j & 127;
        w2t[j] = f2b(W2[k * 16 + n]);
    }
}

// ---------------- GEMM1: text[fp32, Mx500] x w1cat[144x512]^T -> t1(relu+b), tsc(+b) ----------------
__global__ __launch_bounds__(256) void gemm_text_kernel(
    const float* __restrict__ text, const short* __restrict__ B,
    const float* __restrict__ fc1_b, const float* __restrict__ sc_b,
    float* __restrict__ t1, float* __restrict__ tsc, int M)
{
    const int tid = threadIdx.x;
    const int wave = tid >> 6, lane = tid & 63;
    const int q = lane >> 4, col = lane & 15;
    const int mb = blockIdx.x * 64 + wave * 16;
    const int arow = min(mb + col, M - 1);
    const float* ap = text + (size_t)arow * TEXTD + q * 8;

    bf16x8 afrag[16];
    #pragma unroll
    for (int ks = 0; ks < 15; ks++) afrag[ks] = cvt8(ap + ks * 32);
    {   // ks = 15: K 480..511, zero-pad past 500
        bf16x8 f;
        int k0 = 480 + q * 8;
        #pragma unroll
        for (int e = 0; e < 8; e++) {
            int k = k0 + e;
            f[e] = (short)((k < TEXTD) ? f2b(text[(size_t)arow * TEXTD + k]) : 0);
        }
        afrag[15] = f;
    }

    for (int nb = 0; nb < 9; nb++) {
        const short* bp = B + (size_t)(nb * 16 + col) * 512 + q * 8;
        f32x4 acc = {0.f, 0.f, 0.f, 0.f};
        #pragma unroll
        for (int ks = 0; ks < 16; ks++)
            acc = __builtin_amdgcn_mfma_f32_16x16x32_bf16(afrag[ks], *(const bf16x8*)(bp + ks * 32), acc, 0, 0, 0);
        #pragma unroll
        for (int i = 0; i < 4; i++) {
            int row = mb + q * 4 + i;
            if (row < M) {
                if (nb < 8) t1[(size_t)row * 128 + nb * 16 + col] = fmaxf(acc[i] + fc1_b[nb * 16 + col], 0.f);
                else        tsc[(size_t)row * 16 + col] = acc[i] + sc_b[col];
            }
        }
    }
}

// ---------------- GEMM2: x[fp32, Nx128] @ W1 -> h1 bf16; fused a_s1/a_d1 epilogue ----------------
__global__ __launch_bounds__(256) void gemm_h1_kernel(
    const float* __restrict__ x, const short* __restrict__ B,
    const float* __restrict__ as1w, const float* __restrict__ ad1w,
    unsigned short* __restrict__ h1, float* __restrict__ a_s, float* __restrict__ a_d, int N)
{
    const int tid = threadIdx.x;
    const int wave = tid >> 6, lane = tid & 63;
    const int q = lane >> 4, col = lane & 15;
    const int mb = blockIdx.x * 64 + wave * 16;
    const int arow = min(mb + col, N - 1);
    const float* ap = x + (size_t)arow * 128 + q * 8;

    bf16x8 afrag[4];
    #pragma unroll
    for (int ks = 0; ks < 4; ks++) afrag[ks] = cvt8(ap + ks * 32);

    float ps0[4] = {0,0,0,0}, ps1[4] = {0,0,0,0};
    float pd0[4] = {0,0,0,0}, pd1[4] = {0,0,0,0};

    #pragma unroll
    for (int nb = 0; nb < 8; nb++) {
        const short* bp = B + (size_t)(nb * 16 + col) * 128 + q * 8;
        f32x4 acc = {0.f, 0.f, 0.f, 0.f};
        #pragma unroll
        for (int ks = 0; ks < 4; ks++)
            acc = __builtin_amdgcn_mfma_f32_16x16x32_bf16(afrag[ks], *(const bf16x8*)(bp + ks * 32), acc, 0, 0, 0);
        const int j = nb * 16 + col;
        const float asj = as1w[j], adj = ad1w[j];
        #pragma unroll
        for (int i = 0; i < 4; i++) {
            int row = mb + q * 4 + i;
            if (row < N) h1[(size_t)row * 128 + j] = f2b(acc[i]);
            if (nb < 4) { ps0[i] = fmaf(acc[i], asj, ps0[i]); pd0[i] = fmaf(acc[i], adj, pd0[i]); }
            else        { ps1[i] = fmaf(acc[i], asj, ps1[i]); pd1[i] = fmaf(acc[i], adj, pd1[i]); }
        }
    }
    #pragma unroll
    for (int i = 0; i < 4; i++) {
        float v0 = ps0[i], v1 = ps1[i], w0 = pd0[i], w1 = pd1[i];
        #pragma unroll
        for (int off = 1; off < 16; off <<= 1) {
            v0 += __shfl_xor(v0, off, 16);
            v1 += __shfl_xor(v1, off, 16);
            w0 += __shfl_xor(w0, off, 16);
            w1 += __shfl_xor(w1, off, 16);
        }
        int row = mb + q * 4 + i;
        if (col == 0 && row < N) {
            a_s[2 * row] = v0; a_s[2 * row + 1] = v1;
            a_d[2 * row] = w0; a_d[2 * row + 1] = w1;
        }
    }
}

// ---------------- text tail: fc2/fc3/fc4 + shortcut ----------------
__global__ __launch_bounds__(128) void text_tail_kernel(
    const float* __restrict__ t1g, const float* __restrict__ tsc,
    const float* __restrict__ fc2_w, const float* __restrict__ fc2_b,
    const float* __restrict__ fc3_w, const float* __restrict__ fc3_b,
    const float* __restrict__ fc4_w, const float* __restrict__ fc4_b,
    float* __restrict__ text_out, int M)
{
    __shared__ float t1[8][128];
    __shared__ float t2[8][64];
    __shared__ float t3[8][16];
    const int tid = threadIdx.x;
    const int m0 = blockIdx.x * 8;

    for (int r = 0; r < 8; r++) {
        int row = m0 + r;
        t1[r][tid] = (row < M) ? t1g[(size_t)row * 128 + tid] : 0.f;
    }
    __syncthreads();

    const int r2 = tid >> 6, c2 = tid & 63;
    for (int rb = 0; rb < 4; rb++) {
        int row = rb * 2 + r2;
        float a2 = fc2_b[c2];
        for (int k = 0; k < 128; k++) a2 = fmaf(t1[row][k], fc2_w[k * 64 + c2], a2);
        t2[row][c2] = fmaxf(a2, 0.f);
    }
    __syncthreads();

    const int rs = tid >> 4, cs = tid & 15;
    float a3 = fc3_b[cs];
    for (int k = 0; k < 64; k++) a3 = fmaf(t2[rs][k], fc3_w[k * 16 + cs], a3);
    t3[rs][cs] = fmaxf(a3, 0.f);
    __syncthreads();

    float a4 = fc4_b[cs];
    #pragma unroll
    for (int k = 0; k < 16; k++) a4 = fmaf(t3[rs][k], fc4_w[k * 16 + cs], a4);
    int row = m0 + rs;
    if (row < M) text_out[(size_t)row * 16 + cs] = a4 + tsc[(size_t)row * 16 + cs];
}

// ---------------- CSR build ----------------
__global__ __launch_bounds__(256) void deg_hist_kernel(
    const int* __restrict__ edst, int* __restrict__ deg, int E)
{
    int e = blockIdx.x * 256 + threadIdx.x;
    if (e < E) atomicAdd(&deg[edst[e]], 1);
}

// phase 1: per-256-tile sums of (deg[i]+1)
__global__ __launch_bounds__(256) void part_kernel(
    const int* __restrict__ deg, int* __restrict__ bsum, int N)
{
    const int tid = threadIdx.x;
    int i = blockIdx.x * 256 + tid;
    int d = (i < N) ? deg[i] + 1 : 0;
    #pragma unroll
    for (int off = 32; off > 0; off >>= 1) d += __shfl_down(d, off, 64);
    __shared__ int wsum[4];
    if ((tid & 63) == 0) wsum[tid >> 6] = d;
    __syncthreads();
    if (tid == 0) bsum[blockIdx.x] = wsum[0] + wsum[1] + wsum[2] + wsum[3];
}

// phase 2: exclusive scan of block sums (NB <= 256)
__global__ __launch_bounds__(256) void scan_bsums_kernel(
    int* __restrict__ bsum, int NB)
{
    __shared__ int sc[256];
    const int tid = threadIdx.x;
    int v = (tid < NB) ? bsum[tid] : 0;
    sc[tid] = v;
    for (int off = 1; off < 256; off <<= 1) {
        __syncthreads();
        int t = (tid >= off) ? sc[tid - off] : 0;
        __syncthreads();
        sc[tid] += t;
    }
    __syncthreads();
    if (tid < NB) bsum[tid] = sc[tid] - v;   // exclusive
}

// phase 3: in-block scan + offset -> rowptr
__global__ __launch_bounds__(256) void rowptr_kernel(
    const int* __restrict__ deg, const int* __restrict__ bsum,
    int* __restrict__ rowptr, int N)
{
    __shared__ int sc[256];
    const int tid = threadIdx.x;
    const int i = blockIdx.x * 256 + tid;
    int d = (i < N) ? deg[i] + 1 : 0;
    sc[tid] = d;
    for (int off = 1; off < 256; off <<= 1) {
        __syncthreads();
        int t = (tid >= off) ? sc[tid - off] : 0;
        __syncthreads();
        sc[tid] += t;
    }
    __syncthreads();
    int incl = sc[tid];
    int base = bsum[blockIdx.x];
    if (i < N) rowptr[i] = base + incl - d;
    if (i == N - 1) rowptr[N] = base + incl;
}

__global__ __launch_bounds__(256) void cursor_init_kernel(
    const int* __restrict__ rowptr, int* __restrict__ cursor,
    int* __restrict__ csr_src, int N)
{
    int v = blockIdx.x * 256 + threadIdx.x;
    if (v < N) {
        int p = rowptr[v];
        csr_src[p] = v;            // self-loop in slot 0
        cursor[v] = p + 1;
    }
}

__global__ __launch_bounds__(256) void fill_kernel(
    const int* __restrict__ esrc, const int* __restrict__ edst,
    int* __restrict__ cursor, int* __restrict__ csr_src, int E)
{
    int e = blockIdx.x * 256 + threadIdx.x;
    if (e < E) {
        int pos = atomicAdd(&cursor[edst[e]], 1);
        csr_src[pos] = esrc[e];
    }
}

// ---------------- layer-1 gather: 1 node/block, 4 slots x 64 dim-pairs, 8-deep MLP prefetch ----------------
__global__ __launch_bounds__(256) void gat1_gather_kernel(
    const int* __restrict__ rowptr, const int* __restrict__ csr_src,
    const float* __restrict__ a_s, const float* __restrict__ a_d,
    const ushort2* __restrict__ h1, const float* __restrict__ b1,
    unsigned int* __restrict__ g1b, int N)
{
    __shared__ float2 accs[3][64];
    __shared__ float  dens[3][2];
    const int v = blockIdx.x;
    const int tid = threadIdx.x;
    const int slot = tid >> 6, dp = tid & 63, head = dp >> 5;
    const int beg = rowptr[v], end = rowptr[v + 1];
    const int i0 = beg + slot;
    const float adv = a_d[2 * v + head];

    float a0 = 0.f, a1 = 0.f, den = 0.f;

    // static batch of 8 (covers deg <= 32), index-clamped, weight-masked
    int   idxs[8];
    float msk[8], as_[8];
    ushort2 hv[8];
    #pragma unroll
    for (int k = 0; k < 8; k++) {
        int i = i0 + 4 * k;
        int ic = min(i, end - 1);
        idxs[k] = csr_src[ic];
        msk[k] = (i < end) ? 1.f : 0.f;
    }
    #pragma unroll
    for (int k = 0; k < 8; k++) as_[k] = a_s[2 * idxs[k] + head];
    #pragma unroll
    for (int k = 0; k < 8; k++) hv[k] = h1[(size_t)idxs[k] * 64 + dp];
    #pragma unroll
    for (int k = 0; k < 8; k++) {
        float e = as_[k] + adv;
        float w = msk[k] * __expf(e > 0.f ? e : 0.2f * e);
        den += w;
        a0 = fmaf(w, bf2f(hv[k].x), a0);
        a1 = fmaf(w, bf2f(hv[k].y), a1);
    }
    // tail (deg > 32)
    for (int i = i0 + 32; i < end; i += 4) {
        int src = csr_src[i];
        float e = a_s[2 * src + head] + adv;
        float w = __expf(e > 0.f ? e : 0.2f * e);
        ushort2 t = h1[(size_t)src * 64 + dp];
        den += w;
        a0 = fmaf(w, bf2f(t.x), a0);
        a1 = fmaf(w, bf2f(t.y), a1);
    }

    if (slot > 0) {
        accs[slot - 1][dp] = make_float2(a0, a1);
        if (dp == 0 || dp == 32) dens[slot - 1][head] = den;
    }
    __syncthreads();
    if (slot == 0) {
        #pragma unroll
        for (int s = 0; s < 3; s++) {
            float2 t = accs[s][dp];
            a0 += t.x; a1 += t.y;
            den += dens[s][head];
        }
        float inv = 1.f / (den + 1e-16f);
        float o0 = fmaxf(fmaf(a0, inv, b1[2 * dp]),     0.f);
        float o1 = fmaxf(fmaf(a1, inv, b1[2 * dp + 1]), 0.f);
        g1b[(size_t)v * 64 + dp] = ((unsigned int)f2b(o1) << 16) | f2b(o0);
    }
}

// ---------------- gat2 projection (MFMA): h2 = g1b @ W2; fused a_s2/a_d2 ----------------
__global__ __launch_bounds__(256) void gat2_proj_kernel(
    const unsigned short* __restrict__ g1b, const short* __restrict__ w2t,
    const float* __restrict__ as2w, const float* __restrict__ ad2w,
    float* __restrict__ h2, float* __restrict__ a_s2, float* __restrict__ a_d2, int N)
{
    const int tid = threadIdx.x;
    const int wave = tid >> 6, lane = tid & 63;
    const int q = lane >> 4, col = lane & 15;
    const int mb = blockIdx.x * 64 + wave * 16;
    const int arow = min(mb + col, N - 1);
    const short* ap = (const short*)g1b + (size_t)arow * 128 + q * 8;
    const short* bp = w2t + (size_t)col * 128 + q * 8;

    f32x4 acc = {0.f, 0.f, 0.f, 0.f};
    #pragma unroll
    for (int ks = 0; ks < 4; ks++)
        acc = __builtin_amdgcn_mfma_f32_16x16x32_bf16(
            *(const bf16x8*)(ap + ks * 32), *(const bf16x8*)(bp + ks * 32), acc, 0, 0, 0);

    const float asj = as2w[col], adj = ad2w[col];
    #pragma unroll
    for (int i = 0; i < 4; i++) {
        int row = mb + q * 4 + i;
        float ps = acc[i] * asj, pd = acc[i] * adj;
        #pragma unroll
        for (int off = 1; off < 16; off <<= 1) {
            ps += __shfl_xor(ps, off, 16);
            pd += __shfl_xor(pd, off, 16);
        }
        if (row < N) {
            h2[(size_t)row * 16 + col] = acc[i];
            if (col == 0) { a_s2[row] = ps; a_d2[row] = pd; }
        }
    }
}

// ---------------- layer-2 gather (masked): 4 nodes/block, 4 slots x 16 dims, MLP-8 prefetch ----------------
__global__ __launch_bounds__(256) void gat2_gather_kernel(
    const int* __restrict__ rowptr, const int* __restrict__ csr_src,
    const float* __restrict__ h2,
    const float* __restrict__ a_s2, const float* __restrict__ a_d2,
    const float* __restrict__ b2, const int* __restrict__ mask,
    float* __restrict__ g2m, int M)
{
    const int tid = threadIdx.x;
    const int m = blockIdx.x * 4 + (tid >> 6);
    if (m >= M) return;
    const int lane = tid & 63, slot = lane >> 4, c = lane & 15;
    const int v = mask[m];
    const float adv = a_d2[v];
    const int beg = rowptr[v], end = rowptr[v + 1];
    const int i0 = beg + slot;

    float acc = 0.f, den = 0.f;
    int   idxs[8];
    float msk[8], as_[8], hval[8];
    #pragma unroll
    for (int k = 0; k < 8; k++) {
        int i = i0 + 4 * k;
        int ic = min(i, end - 1);
        idxs[k] = csr_src[ic];
        msk[k] = (i < end) ? 1.f : 0.f;
    }
    #pragma unroll
    for (int k = 0; k < 8; k++) as_[k] = a_s2[idxs[k]];
    #pragma unroll
    for (int k = 0; k < 8; k++) hval[k] = h2[(size_t)idxs[k] * 16 + c];
    #pragma unroll
    for (int k = 0; k < 8; k++) {
        float e = as_[k] + adv;
        float w = msk[k] * __expf(e > 0.f ? e : 0.2f * e);
        den += w;
        acc = fmaf(w, hval[k], acc);
    }
    for (int i = i0 + 32; i < end; i += 4) {
        int src = csr_src[i];
        float e = a_s2[src] + adv;
        float w = __expf(e > 0.f ? e : 0.2f * e);
        den += w;
        acc = fmaf(w, h2[(size_t)src * 16 + c], acc);
    }

    acc += __shfl_xor(acc, 16, 64);
    acc += __shfl_xor(acc, 32, 64);
    den += __shfl_xor(den, 16, 64);
    den += __shfl_xor(den, 32, 64);
    if (slot == 0) g2m[(size_t)m * 16 + c] = acc / (den + 1e-16f) + b2[c];
}

// ---------------- fused head ----------------
__global__ __launch_bounds__(64) void final_kernel(
    const float* __restrict__ text_out, const float* __restrict__ g2m,
    const float* __restrict__ fcf_w, const float* __restrict__ fcf_b,
    float* __restrict__ out, int M)
{
    const int lane = threadIdx.x;
    const int g = lane >> 4, j = lane & 15;
    const int m = blockIdx.x * 4 + g;
    if (m >= M) return;

    float tval = text_out[(size_t)m * 16 + j];
    float gval = g2m[(size_t)m * 16 + j];

    float logit = fcf_b[j];
    #pragma unroll
    for (int k = 0; k < 16; k++) {
        logit = fmaf(__shfl(tval, k, 16), fcf_w[k * 16 + j], logit);
        logit = fmaf(__shfl(gval, k, 16), fcf_w[(16 + k) * 16 + j], logit);
    }
    float mx = logit;
    #pragma unroll
    for (int off = 8; off > 0; off >>= 1) mx = fmaxf(mx, __shfl_xor(mx, off, 16));
    float se = expf(logit - mx);
    #pragma unroll
    for (int off = 8; off > 0; off >>= 1) se += __shfl_xor(se, off, 16);
    out[(size_t)m * 16 + j] = logit - mx - logf(se);
}

extern "C" void kernel_launch(void* const* d_in, const int* in_sizes, int n_in,
                              void* d_out, int out_size, void* d_ws, size_t ws_size,
                              hipStream_t stream)
{
    const float* text  = (const float*)d_in[0];
    const float* x     = (const float*)d_in[1];
    const int*   ei    = (const int*)  d_in[2];
    const int*   mask  = (const int*)  d_in[3];
    const float* fc1_w = (const float*)d_in[4];  const float* fc1_b = (const float*)d_in[5];
    const float* fc2_w = (const float*)d_in[6];  const float* fc2_b = (const float*)d_in[7];
    const float* fc3_w = (const float*)d_in[8];  const float* fc3_b = (const float*)d_in[9];
    const float* fc4_w = (const float*)d_in[10]; const float* fc4_b = (const float*)d_in[11];
    const float* sc_w  = (const float*)d_in[12]; const float* sc_b  = (const float*)d_in[13];
    const float* W1    = (const float*)d_in[14];
    const float* as1w  = (const float*)d_in[15]; const float* ad1w  = (const float*)d_in[16];
    const float* b1    = (const float*)d_in[17];
    const float* W2    = (const float*)d_in[18];
    const float* as2w  = (const float*)d_in[19]; const float* ad2w  = (const float*)d_in[20];
    const float* b2    = (const float*)d_in[21];
    const float* fcf_w = (const float*)d_in[22]; const float* fcf_b = (const float*)d_in[23];

    const int M  = in_sizes[3];
    const int N  = in_sizes[1] / GNN_DIM;
    const int E  = in_sizes[2] / 2;
    const int EP = E + N;
    const int* esrc = ei;
    const int* edst = ei + E;

    const int Mp = ((M + 63) / 64) * 64;
    const int Np = ((N + 63) / 64) * 64;
    const int NB = (N + 255) / 256;        // 196 <= 256

    float* ws = (float*)d_ws;
    size_t off = 0;
    auto alloc = [&](size_t n) { float* p = ws + off; off += (n + 63) & ~size_t(63); return p; };

    unsigned short* h1    = (unsigned short*)alloc((size_t)Np * 64);   // bf16 [Np x 128]
    unsigned int*   g1b   = (unsigned int*)  alloc((size_t)N * 64);    // bf16 [N x 128] packed
    unsigned short* w1cat = (unsigned short*)alloc(144 * 256);         // bf16 [144 x 512]
    unsigned short* w1g   = (unsigned short*)alloc(128 * 64);          // bf16 [128 x 128]
    unsigned short* w2t   = (unsigned short*)alloc(16 * 64);           // bf16 [16 x 128]
    float* t1       = alloc((size_t)M * 128);
    float* tsc      = alloc((size_t)M * 16);
    float* a_s1     = alloc((size_t)2 * N);
    float* a_d1     = alloc((size_t)2 * N);
    float* h2       = alloc((size_t)N * 16);
    float* a_s2     = alloc(N);
    float* a_d2     = alloc(N);
    float* text_out = alloc((size_t)M * 16);
    float* g2m      = alloc((size_t)M * 16);
    int* deg        = (int*)alloc(N);
    int* cursor     = (int*)alloc(N);
    int* rowptr     = (int*)alloc(N + 1);
    int* bsum       = (int*)alloc(256);
    int* csr_src    = (int*)alloc(EP);

    // --- CSR build: histogram -> hierarchical scan -> fill ---
    hipMemsetAsync(deg, 0, (size_t)N * sizeof(int), stream);
    deg_hist_kernel<<<(E + 255) / 256, 256, 0, stream>>>(edst, deg, E);
    part_kernel<<<NB, 256, 0, stream>>>(deg, bsum, N);
    scan_bsums_kernel<<<1, 256, 0, stream>>>(bsum, NB);
    rowptr_kernel<<<NB, 256, 0, stream>>>(deg, bsum, rowptr, N);
    cursor_init_kernel<<<(N + 255) / 256, 256, 0, stream>>>(rowptr, cursor, csr_src, N);
    fill_kernel<<<(E + 255) / 256, 256, 0, stream>>>(esrc, edst, cursor, csr_src, E);

    // --- weights to bf16 ---
    conv_w_kernel<<<(144 * 512 + 128 * 128 + 16 * 128 + 255) / 256, 256, 0, stream>>>(
        fc1_w, sc_w, W1, W2, w1cat, w1g, w2t);

    // --- text branch ---
    gemm_text_kernel<<<Mp / 64, 256, 0, stream>>>(
        text, (const short*)w1cat, fc1_b, sc_b, t1, tsc, M);
    text_tail_kernel<<<(M + 7) / 8, 128, 0, stream>>>(
        t1, tsc, fc2_w, fc2_b, fc3_w, fc3_b, fc4_w, fc4_b, text_out, M);

    // --- GNN branch ---
    gemm_h1_kernel<<<Np / 64, 256, 0, stream>>>(
        x, (const short*)w1g, as1w, ad1w, h1, a_s1, a_d1, N);

    gat1_gather_kernel<<<N, 256, 0, stream>>>(
        rowptr, csr_src, a_s1, a_d1, (const ushort2*)h1, b1, g1b, N);

    gat2_proj_kernel<<<Np / 64, 256, 0, stream>>>(
        (const unsigned short*)g1b, (const short*)w2t, as2w, ad2w, h2, a_s2, a_d2, N);

    gat2_gather_kernel<<<(M + 3) / 4, 256, 0, stream>>>(
        rowptr, csr_src, h2, a_s2, a_d2, b2, mask, g2m, M);

    final_kernel<<<(M + 3) / 4, 64, 0, stream>>>(
        text_out, g2m, fcf_w, fcf_b, (float*)d_out, M);
}

// Round 7
// 242.973 us; speedup vs baseline: 2.8761x; 1.0817x over previous
//
#include <hip/hip_runtime.h>
#include <hip/hip_bf16.h>
#include <cmath>

#define TEXTD 500
#define GNN_DIM 128

typedef __attribute__((ext_vector_type(8))) short bf16x8;
typedef __attribute__((ext_vector_type(4))) float f32x4;

__device__ __forceinline__ float bf2f(unsigned short u) {
    union { unsigned int i; float f; } cv;
    cv.i = ((unsigned int)u) << 16;
    return cv.f;
}
__device__ __forceinline__ unsigned short f2b(float x) {
    __hip_bfloat16 b = __float2bfloat16(x);
    return *reinterpret_cast<unsigned short*>(&b);
}
__device__ __forceinline__ float u2f(unsigned int u) {
    union { unsigned int i; float f; } cv; cv.i = u; return cv.f;
}
// convert 8 consecutive floats at p (16B-aligned) to a bf16x8 fragment
__device__ __forceinline__ bf16x8 cvt8(const float* p) {
    float4 u = *(const float4*)p;
    float4 v = *(const float4*)(p + 4);
    bf16x8 f;
    f[0] = (short)f2b(u.x); f[1] = (short)f2b(u.y);
    f[2] = (short)f2b(u.z); f[3] = (short)f2b(u.w);
    f[4] = (short)f2b(v.x); f[5] = (short)f2b(v.y);
    f[6] = (short)f2b(v.z); f[7] = (short)f2b(v.w);
    return f;
}

// ---------------- weight conversion: w1cat [144x512], w1g [128x128], w2t [16x128] ----------------
__global__ __launch_bounds__(256) void conv_w_kernel(
    const float* __restrict__ fc1_w, const float* __restrict__ sc_w,
    const float* __restrict__ W1, const float* __restrict__ W2,
    unsigned short* __restrict__ w1cat, unsigned short* __restrict__ w1g,
    unsigned short* __restrict__ w2t)
{
    int idx = blockIdx.x * 256 + threadIdx.x;
    if (idx < 144 * 512) {
        int n = idx >> 9, k = idx & 511;
        float v = 0.f;
        if (k < TEXTD) v = (n < 128) ? fc1_w[k * 128 + n] : sc_w[k * 16 + (n - 128)];
        w1cat[idx] = f2b(v);
    } else if (idx < 144 * 512 + 128 * 128) {
        int j = idx - 144 * 512;
        int n = j >> 7, k = j & 127;
        w1g[j] = f2b(W1[k * 128 + n]);
    } else if (idx < 144 * 512 + 128 * 128 + 16 * 128) {
        int j = idx - (144 * 512 + 128 * 128);
        int n = j >> 7, k = j & 127;
        w2t[j] = f2b(W2[k * 16 + n]);
    }
}

// ---------------- GEMM1: text[fp32, Mx500] x w1cat[144x512]^T -> t1(relu+b), tsc(+b) ----------------
__global__ __launch_bounds__(256) void gemm_text_kernel(
    const float* __restrict__ text, const short* __restrict__ B,
    const float* __restrict__ fc1_b, const float* __restrict__ sc_b,
    float* __restrict__ t1, float* __restrict__ tsc, int M)
{
    const int tid = threadIdx.x;
    const int wave = tid >> 6, lane = tid & 63;
    const int q = lane >> 4, col = lane & 15;
    const int mb = blockIdx.x * 64 + wave * 16;
    const int arow = min(mb + col, M - 1);
    const float* ap = text + (size_t)arow * TEXTD + q * 8;

    bf16x8 afrag[16];
    #pragma unroll
    for (int ks = 0; ks < 15; ks++) afrag[ks] = cvt8(ap + ks * 32);
    {   // ks = 15: K 480..511, zero-pad past 500
        bf16x8 f;
        int k0 = 480 + q * 8;
        #pragma unroll
        for (int e = 0; e < 8; e++) {
            int k = k0 + e;
            f[e] = (short)((k < TEXTD) ? f2b(text[(size_t)arow * TEXTD + k]) : 0);
        }
        afrag[15] = f;
    }

    for (int nb = 0; nb < 9; nb++) {
        const short* bp = B + (size_t)(nb * 16 + col) * 512 + q * 8;
        f32x4 acc = {0.f, 0.f, 0.f, 0.f};
        #pragma unroll
        for (int ks = 0; ks < 16; ks++)
            acc = __builtin_amdgcn_mfma_f32_16x16x32_bf16(afrag[ks], *(const bf16x8*)(bp + ks * 32), acc, 0, 0, 0);
        #pragma unroll
        for (int i = 0; i < 4; i++) {
            int row = mb + q * 4 + i;
            if (row < M) {
                if (nb < 8) t1[(size_t)row * 128 + nb * 16 + col] = fmaxf(acc[i] + fc1_b[nb * 16 + col], 0.f);
                else        tsc[(size_t)row * 16 + col] = acc[i] + sc_b[col];
            }
        }
    }
}

// ---------------- GEMM2: x[fp32, Nx128] @ W1 -> h1 bf16; fused a_s1/a_d1 epilogue ----------------
__global__ __launch_bounds__(256) void gemm_h1_kernel(
    const float* __restrict__ x, const short* __restrict__ B,
    const float* __restrict__ as1w, const float* __restrict__ ad1w,
    unsigned short* __restrict__ h1, float* __restrict__ a_s, float* __restrict__ a_d, int N)
{
    const int tid = threadIdx.x;
    const int wave = tid >> 6, lane = tid & 63;
    const int q = lane >> 4, col = lane & 15;
    const int mb = blockIdx.x * 64 + wave * 16;
    const int arow = min(mb + col, N - 1);
    const float* ap = x + (size_t)arow * 128 + q * 8;

    bf16x8 afrag[4];
    #pragma unroll
    for (int ks = 0; ks < 4; ks++) afrag[ks] = cvt8(ap + ks * 32);

    float ps0[4] = {0,0,0,0}, ps1[4] = {0,0,0,0};
    float pd0[4] = {0,0,0,0}, pd1[4] = {0,0,0,0};

    #pragma unroll
    for (int nb = 0; nb < 8; nb++) {
        const short* bp = B + (size_t)(nb * 16 + col) * 128 + q * 8;
        f32x4 acc = {0.f, 0.f, 0.f, 0.f};
        #pragma unroll
        for (int ks = 0; ks < 4; ks++)
            acc = __builtin_amdgcn_mfma_f32_16x16x32_bf16(afrag[ks], *(const bf16x8*)(bp + ks * 32), acc, 0, 0, 0);
        const int j = nb * 16 + col;
        const float asj = as1w[j], adj = ad1w[j];
        #pragma unroll
        for (int i = 0; i < 4; i++) {
            int row = mb + q * 4 + i;
            if (row < N) h1[(size_t)row * 128 + j] = f2b(acc[i]);
            if (nb < 4) { ps0[i] = fmaf(acc[i], asj, ps0[i]); pd0[i] = fmaf(acc[i], adj, pd0[i]); }
            else        { ps1[i] = fmaf(acc[i], asj, ps1[i]); pd1[i] = fmaf(acc[i], adj, pd1[i]); }
        }
    }
    #pragma unroll
    for (int i = 0; i < 4; i++) {
        float v0 = ps0[i], v1 = ps1[i], w0 = pd0[i], w1 = pd1[i];
        #pragma unroll
        for (int off = 1; off < 16; off <<= 1) {
            v0 += __shfl_xor(v0, off, 16);
            v1 += __shfl_xor(v1, off, 16);
            w0 += __shfl_xor(w0, off, 16);
            w1 += __shfl_xor(w1, off, 16);
        }
        int row = mb + q * 4 + i;
        if (col == 0 && row < N) {
            a_s[2 * row] = v0; a_s[2 * row + 1] = v1;
            a_d[2 * row] = w0; a_d[2 * row + 1] = w1;
        }
    }
}

// ---------------- text tail: fc2/fc3/fc4 + shortcut ----------------
__global__ __launch_bounds__(128) void text_tail_kernel(
    const float* __restrict__ t1g, const float* __restrict__ tsc,
    const float* __restrict__ fc2_w, const float* __restrict__ fc2_b,
    const float* __restrict__ fc3_w, const float* __restrict__ fc3_b,
    const float* __restrict__ fc4_w, const float* __restrict__ fc4_b,
    float* __restrict__ text_out, int M)
{
    __shared__ float t1[8][128];
    __shared__ float t2[8][64];
    __shared__ float t3[8][16];
    const int tid = threadIdx.x;
    const int m0 = blockIdx.x * 8;

    for (int r = 0; r < 8; r++) {
        int row = m0 + r;
        t1[r][tid] = (row < M) ? t1g[(size_t)row * 128 + tid] : 0.f;
    }
    __syncthreads();

    const int r2 = tid >> 6, c2 = tid & 63;
    for (int rb = 0; rb < 4; rb++) {
        int row = rb * 2 + r2;
        float a2 = fc2_b[c2];
        for (int k = 0; k < 128; k++) a2 = fmaf(t1[row][k], fc2_w[k * 64 + c2], a2);
        t2[row][c2] = fmaxf(a2, 0.f);
    }
    __syncthreads();

    const int rs = tid >> 4, cs = tid & 15;
    float a3 = fc3_b[cs];
    for (int k = 0; k < 64; k++) a3 = fmaf(t2[rs][k], fc3_w[k * 16 + cs], a3);
    t3[rs][cs] = fmaxf(a3, 0.f);
    __syncthreads();

    float a4 = fc4_b[cs];
    #pragma unroll
    for (int k = 0; k < 16; k++) a4 = fmaf(t3[rs][k], fc4_w[k * 16 + cs], a4);
    int row = m0 + rs;
    if (row < M) text_out[(size_t)row * 16 + cs] = a4 + tsc[(size_t)row * 16 + cs];
}

// ---------------- CSR build ----------------
__global__ __launch_bounds__(256) void deg_hist_kernel(
    const int* __restrict__ edst, int* __restrict__ deg, int E)
{
    int e = blockIdx.x * 256 + threadIdx.x;
    if (e < E) atomicAdd(&deg[edst[e]], 1);
}

// phase 1: per-256-tile sums of (deg[i]+1)
__global__ __launch_bounds__(256) void part_kernel(
    const int* __restrict__ deg, int* __restrict__ bsum, int N)
{
    const int tid = threadIdx.x;
    int i = blockIdx.x * 256 + tid;
    int d = (i < N) ? deg[i] + 1 : 0;
    #pragma unroll
    for (int off = 32; off > 0; off >>= 1) d += __shfl_down(d, off, 64);
    __shared__ int wsum[4];
    if ((tid & 63) == 0) wsum[tid >> 6] = d;
    __syncthreads();
    if (tid == 0) bsum[blockIdx.x] = wsum[0] + wsum[1] + wsum[2] + wsum[3];
}

// phase 2: exclusive scan of block sums (NB <= 256)
__global__ __launch_bounds__(256) void scan_bsums_kernel(
    int* __restrict__ bsum, int NB)
{
    __shared__ int sc[256];
    const int tid = threadIdx.x;
    int v = (tid < NB) ? bsum[tid] : 0;
    sc[tid] = v;
    for (int off = 1; off < 256; off <<= 1) {
        __syncthreads();
        int t = (tid >= off) ? sc[tid - off] : 0;
        __syncthreads();
        sc[tid] += t;
    }
    __syncthreads();
    if (tid < NB) bsum[tid] = sc[tid] - v;   // exclusive
}

// phase 3: in-block scan + offset -> rowptr, cursor, self-loop slot
__global__ __launch_bounds__(256) void rowptr_kernel(
    const int* __restrict__ deg, const int* __restrict__ bsum,
    int* __restrict__ rowptr, int* __restrict__ cursor,
    int* __restrict__ csr_src, int N)
{
    __shared__ int sc[256];
    const int tid = threadIdx.x;
    const int i = blockIdx.x * 256 + tid;
    int d = (i < N) ? deg[i] + 1 : 0;
    sc[tid] = d;
    for (int off = 1; off < 256; off <<= 1) {
        __syncthreads();
        int t = (tid >= off) ? sc[tid - off] : 0;
        __syncthreads();
        sc[tid] += t;
    }
    __syncthreads();
    int incl = sc[tid];
    int base = bsum[blockIdx.x];
    if (i < N) {
        int p = base + incl - d;
        rowptr[i] = p;
        cursor[i] = p + 1;
        csr_src[p] = i;         // self-loop in slot 0
    }
    if (i == N - 1) rowptr[N] = base + incl;
}

__device__ __forceinline__ float edge_w(float e) {
    return __expf(e > 0.f ? e : 0.2f * e);
}

// fill CSR slots + per-edge weights (both heads), plus self-loop weights
__global__ __launch_bounds__(256) void fillw_kernel(
    const int* __restrict__ esrc, const int* __restrict__ edst,
    int* __restrict__ cursor, const int* __restrict__ rowptr,
    int* __restrict__ csr_src, float* __restrict__ wcsr,
    const float* __restrict__ a_s, const float* __restrict__ a_d, int E, int N)
{
    int e = blockIdx.x * 256 + threadIdx.x;
    if (e < E) {
        int src = esrc[e], dst = edst[e];
        int pos = atomicAdd(&cursor[dst], 1);
        csr_src[pos] = src;
        float2 as = *(const float2*)(a_s + 2 * src);
        float2 ad = *(const float2*)(a_d + 2 * dst);
        float2 w = make_float2(edge_w(as.x + ad.x), edge_w(as.y + ad.y));
        *(float2*)(wcsr + 2 * pos) = w;
    } else if (e < E + N) {
        int v = e - E;
        int p = rowptr[v];
        float2 as = *(const float2*)(a_s + 2 * v);
        float2 ad = *(const float2*)(a_d + 2 * v);
        *(float2*)(wcsr + 2 * p) = make_float2(edge_w(as.x + ad.x), edge_w(as.y + ad.y));
    }
}

// ---------------- layer-1 gather: 1 node/block, 8 slots x 32 lanes(x4 dims) ----------------
template<int B>
__device__ __forceinline__ void gat1_batch(
    int i0, int end, int endm1, int head,
    const int* __restrict__ csr_src, const float* __restrict__ wcsr,
    const uint2* __restrict__ h1u, int dp,
    float& a0, float& a1, float& a2, float& a3, float& den)
{
    int ics[B], idxs[B];
    float wv[B];
    uint2 hv[B];
    #pragma unroll
    for (int k = 0; k < B; k++) ics[k] = min(i0 + 8 * k, endm1);
    #pragma unroll
    for (int k = 0; k < B; k++) idxs[k] = csr_src[ics[k]];
    #pragma unroll
    for (int k = 0; k < B; k++) {
        float w = wcsr[2 * ics[k] + head];
        wv[k] = (i0 + 8 * k < end) ? w : 0.f;
    }
    #pragma unroll
    for (int k = 0; k < B; k++) hv[k] = h1u[(size_t)idxs[k] * 32 + dp];
    #pragma unroll
    for (int k = 0; k < B; k++) {
        float w = wv[k];
        den += w;
        a0 = fmaf(w, u2f(hv[k].x << 16),          a0);
        a1 = fmaf(w, u2f(hv[k].x & 0xffff0000u),  a1);
        a2 = fmaf(w, u2f(hv[k].y << 16),          a2);
        a3 = fmaf(w, u2f(hv[k].y & 0xffff0000u),  a3);
    }
}

__global__ __launch_bounds__(256) void gat1_gather_kernel(
    const int* __restrict__ rowptr, const int* __restrict__ csr_src,
    const float* __restrict__ wcsr, const uint2* __restrict__ h1u,
    const float* __restrict__ b1, uint2* __restrict__ g1b, int N)
{
    __shared__ float4 accs[3][32];
    __shared__ float  dens[3][32];
    const int v = blockIdx.x;
    const int tid = threadIdx.x;
    const int wave = tid >> 6, lane = tid & 63;
    const int slot = wave * 2 + (lane >> 5);   // 0..7
    const int dp = lane & 31;                  // dims 4dp..4dp+3
    const int head = dp >> 4;
    const int beg = rowptr[v], end = rowptr[v + 1];
    const int deg = end - beg;
    const int endm1 = end - 1;
    const int i0 = beg + slot;

    float a0 = 0.f, a1 = 0.f, a2 = 0.f, a3 = 0.f, den = 0.f;

    if (deg <= 16) {
        gat1_batch<2>(i0, end, endm1, head, csr_src, wcsr, h1u, dp, a0, a1, a2, a3, den);
    } else {
        gat1_batch<4>(i0, end, endm1, head, csr_src, wcsr, h1u, dp, a0, a1, a2, a3, den);
        for (int i = i0 + 32; i < end; i += 8) {
            int idx = csr_src[i];
            float w = wcsr[2 * i + head];
            uint2 hv = h1u[(size_t)idx * 32 + dp];
            den += w;
            a0 = fmaf(w, u2f(hv.x << 16),         a0);
            a1 = fmaf(w, u2f(hv.x & 0xffff0000u), a1);
            a2 = fmaf(w, u2f(hv.y << 16),         a2);
            a3 = fmaf(w, u2f(hv.y & 0xffff0000u), a3);
        }
    }

    // combine the two slots within each wave
    a0 += __shfl_xor(a0, 32, 64);
    a1 += __shfl_xor(a1, 32, 64);
    a2 += __shfl_xor(a2, 32, 64);
    a3 += __shfl_xor(a3, 32, 64);
    den += __shfl_xor(den, 32, 64);

    if (wave > 0 && lane < 32) {
        accs[wave - 1][dp] = make_float4(a0, a1, a2, a3);
        dens[wave - 1][dp] = den;
    }
    __syncthreads();
    if (wave == 0 && lane < 32) {
        #pragma unroll
        for (int s = 0; s < 3; s++) {
            float4 t = accs[s][dp];
            a0 += t.x; a1 += t.y; a2 += t.z; a3 += t.w;
            den += dens[s][dp];
        }
        float inv = 1.f / (den + 1e-16f);
        float4 bv = *(const float4*)(b1 + 4 * dp);
        float o0 = fmaxf(fmaf(a0, inv, bv.x), 0.f);
        float o1 = fmaxf(fmaf(a1, inv, bv.y), 0.f);
        float o2 = fmaxf(fmaf(a2, inv, bv.z), 0.f);
        float o3 = fmaxf(fmaf(a3, inv, bv.w), 0.f);
        uint2 o;
        o.x = ((unsigned int)f2b(o1) << 16) | f2b(o0);
        o.y = ((unsigned int)f2b(o3) << 16) | f2b(o2);
        g1b[(size_t)v * 32 + dp] = o;
    }
}

// ---------------- gat2 projection (MFMA): h2 = g1b @ W2; fused a_s2/a_d2 ----------------
__global__ __launch_bounds__(256) void gat2_proj_kernel(
    const unsigned short* __restrict__ g1b, const short* __restrict__ w2t,
    const float* __restrict__ as2w, const float* __restrict__ ad2w,
    float* __restrict__ h2, float* __restrict__ a_s2, float* __restrict__ a_d2, int N)
{
    const int tid = threadIdx.x;
    const int wave = tid >> 6, lane = tid & 63;
    const int q = lane >> 4, col = lane & 15;
    const int mb = blockIdx.x * 64 + wave * 16;
    const int arow = min(mb + col, N - 1);
    const short* ap = (const short*)g1b + (size_t)arow * 128 + q * 8;
    const short* bp = w2t + (size_t)col * 128 + q * 8;

    f32x4 acc = {0.f, 0.f, 0.f, 0.f};
    #pragma unroll
    for (int ks = 0; ks < 4; ks++)
        acc = __builtin_amdgcn_mfma_f32_16x16x32_bf16(
            *(const bf16x8*)(ap + ks * 32), *(const bf16x8*)(bp + ks * 32), acc, 0, 0, 0);

    const float asj = as2w[col], adj = ad2w[col];
    #pragma unroll
    for (int i = 0; i < 4; i++) {
        int row = mb + q * 4 + i;
        float ps = acc[i] * asj, pd = acc[i] * adj;
        #pragma unroll
        for (int off = 1; off < 16; off <<= 1) {
            ps += __shfl_xor(ps, off, 16);
            pd += __shfl_xor(pd, off, 16);
        }
        if (row < N) {
            h2[(size_t)row * 16 + col] = acc[i];
            if (col == 0) { a_s2[row] = ps; a_d2[row] = pd; }
        }
    }
}

// ---------------- layer-2 gather (masked): 4 nodes/block, 4 slots x 16 dims, MLP-8 prefetch ----------------
__global__ __launch_bounds__(256) void gat2_gather_kernel(
    const int* __restrict__ rowptr, const int* __restrict__ csr_src,
    const float* __restrict__ h2,
    const float* __restrict__ a_s2, const float* __restrict__ a_d2,
    const float* __restrict__ b2, const int* __restrict__ mask,
    float* __restrict__ g2m, int M)
{
    const int tid = threadIdx.x;
    const int m = blockIdx.x * 4 + (tid >> 6);
    if (m >= M) return;
    const int lane = tid & 63, slot = lane >> 4, c = lane & 15;
    const int v = mask[m];
    const float adv = a_d2[v];
    const int beg = rowptr[v], end = rowptr[v + 1];
    const int i0 = beg + slot;

    float acc = 0.f, den = 0.f;
    int   idxs[8];
    float msk[8], as_[8], hval[8];
    #pragma unroll
    for (int k = 0; k < 8; k++) {
        int i = i0 + 4 * k;
        int ic = min(i, end - 1);
        idxs[k] = csr_src[ic];
        msk[k] = (i < end) ? 1.f : 0.f;
    }
    #pragma unroll
    for (int k = 0; k < 8; k++) as_[k] = a_s2[idxs[k]];
    #pragma unroll
    for (int k = 0; k < 8; k++) hval[k] = h2[(size_t)idxs[k] * 16 + c];
    #pragma unroll
    for (int k = 0; k < 8; k++) {
        float e = as_[k] + adv;
        float w = msk[k] * __expf(e > 0.f ? e : 0.2f * e);
        den += w;
        acc = fmaf(w, hval[k], acc);
    }
    for (int i = i0 + 32; i < end; i += 4) {
        int src = csr_src[i];
        float e = a_s2[src] + adv;
        float w = __expf(e > 0.f ? e : 0.2f * e);
        den += w;
        acc = fmaf(w, h2[(size_t)src * 16 + c], acc);
    }

    acc += __shfl_xor(acc, 16, 64);
    acc += __shfl_xor(acc, 32, 64);
    den += __shfl_xor(den, 16, 64);
    den += __shfl_xor(den, 32, 64);
    if (slot == 0) g2m[(size_t)m * 16 + c] = acc / (den + 1e-16f) + b2[c];
}

// ---------------- fused head ----------------
__global__ __launch_bounds__(64) void final_kernel(
    const float* __restrict__ text_out, const float* __restrict__ g2m,
    const float* __restrict__ fcf_w, const float* __restrict__ fcf_b,
    float* __restrict__ out, int M)
{
    const int lane = threadIdx.x;
    const int g = lane >> 4, j = lane & 15;
    const int m = blockIdx.x * 4 + g;
    if (m >= M) return;

    float tval = text_out[(size_t)m * 16 + j];
    float gval = g2m[(size_t)m * 16 + j];

    float logit = fcf_b[j];
    #pragma unroll
    for (int k = 0; k < 16; k++) {
        logit = fmaf(__shfl(tval, k, 16), fcf_w[k * 16 + j], logit);
        logit = fmaf(__shfl(gval, k, 16), fcf_w[(16 + k) * 16 + j], logit);
    }
    float mx = logit;
    #pragma unroll
    for (int off = 8; off > 0; off >>= 1) mx = fmaxf(mx, __shfl_xor(mx, off, 16));
    float se = expf(logit - mx);
    #pragma unroll
    for (int off = 8; off > 0; off >>= 1) se += __shfl_xor(se, off, 16);
    out[(size_t)m * 16 + j] = logit - mx - logf(se);
}

extern "C" void kernel_launch(void* const* d_in, const int* in_sizes, int n_in,
                              void* d_out, int out_size, void* d_ws, size_t ws_size,
                              hipStream_t stream)
{
    const float* text  = (const float*)d_in[0];
    const float* x     = (const float*)d_in[1];
    const int*   ei    = (const int*)  d_in[2];
    const int*   mask  = (const int*)  d_in[3];
    const float* fc1_w = (const float*)d_in[4];  const float* fc1_b = (const float*)d_in[5];
    const float* fc2_w = (const float*)d_in[6];  const float* fc2_b = (const float*)d_in[7];
    const float* fc3_w = (const float*)d_in[8];  const float* fc3_b = (const float*)d_in[9];
    const float* fc4_w = (const float*)d_in[10]; const float* fc4_b = (const float*)d_in[11];
    const float* sc_w  = (const float*)d_in[12]; const float* sc_b  = (const float*)d_in[13];
    const float* W1    = (const float*)d_in[14];
    const float* as1w  = (const float*)d_in[15]; const float* ad1w  = (const float*)d_in[16];
    const float* b1    = (const float*)d_in[17];
    const float* W2    = (const float*)d_in[18];
    const float* as2w  = (const float*)d_in[19]; const float* ad2w  = (const float*)d_in[20];
    const float* b2    = (const float*)d_in[21];
    const float* fcf_w = (const float*)d_in[22]; const float* fcf_b = (const float*)d_in[23];

    const int M  = in_sizes[3];
    const int N  = in_sizes[1] / GNN_DIM;
    const int E  = in_sizes[2] / 2;
    const int EP = E + N;
    const int* esrc = ei;
    const int* edst = ei + E;

    const int Mp = ((M + 63) / 64) * 64;
    const int Np = ((N + 63) / 64) * 64;
    const int NB = (N + 255) / 256;        // <= 256

    float* ws = (float*)d_ws;
    size_t off = 0;
    auto alloc = [&](size_t n) { float* p = ws + off; off += (n + 63) & ~size_t(63); return p; };

    unsigned short* h1    = (unsigned short*)alloc((size_t)Np * 64);   // bf16 [Np x 128]
    unsigned int*   g1b   = (unsigned int*)  alloc((size_t)N * 64);    // bf16 [N x 128] packed
    unsigned short* w1cat = (unsigned short*)alloc(144 * 256);         // bf16 [144 x 512]
    unsigned short* w1g   = (unsigned short*)alloc(128 * 64);          // bf16 [128 x 128]
    unsigned short* w2t   = (unsigned short*)alloc(16 * 64);           // bf16 [16 x 128]
    float* t1       = alloc((size_t)M * 128);
    float* tsc      = alloc((size_t)M * 16);
    float* a_s1     = alloc((size_t)2 * N);
    float* a_d1     = alloc((size_t)2 * N);
    float* h2       = alloc((size_t)N * 16);
    float* a_s2     = alloc(N);
    float* a_d2     = alloc(N);
    float* text_out = alloc((size_t)M * 16);
    float* g2m      = alloc((size_t)M * 16);
    float* wcsr1    = alloc((size_t)2 * EP);
    int* deg        = (int*)alloc(N);
    int* cursor     = (int*)alloc(N);
    int* rowptr     = (int*)alloc(N + 1);
    int* bsum       = (int*)alloc(256);
    int* csr_src    = (int*)alloc(EP);

    // --- CSR build: histogram -> hierarchical scan (+cursor+self slot) ---
    hipMemsetAsync(deg, 0, (size_t)N * sizeof(int), stream);
    deg_hist_kernel<<<(E + 255) / 256, 256, 0, stream>>>(edst, deg, E);
    part_kernel<<<NB, 256, 0, stream>>>(deg, bsum, N);
    scan_bsums_kernel<<<1, 256, 0, stream>>>(bsum, NB);
    rowptr_kernel<<<NB, 256, 0, stream>>>(deg, bsum, rowptr, cursor, csr_src, N);

    // --- weights to bf16 ---
    conv_w_kernel<<<(144 * 512 + 128 * 128 + 16 * 128 + 255) / 256, 256, 0, stream>>>(
        fc1_w, sc_w, W1, W2, w1cat, w1g, w2t);

    // --- GAT1 projection (produces a_s1/a_d1 for weight fill) ---
    gemm_h1_kernel<<<Np / 64, 256, 0, stream>>>(
        x, (const short*)w1g, as1w, ad1w, h1, a_s1, a_d1, N);

    // --- CSR fill + fused per-edge weights (edges + self-loops) ---
    fillw_kernel<<<(E + N + 255) / 256, 256, 0, stream>>>(
        esrc, edst, cursor, rowptr, csr_src, wcsr1, a_s1, a_d1, E, N);

    // --- text branch ---
    gemm_text_kernel<<<Mp / 64, 256, 0, stream>>>(
        text, (const short*)w1cat, fc1_b, sc_b, t1, tsc, M);
    text_tail_kernel<<<(M + 7) / 8, 128, 0, stream>>>(
        t1, tsc, fc2_w, fc2_b, fc3_w, fc3_b, fc4_w, fc4_b, text_out, M);

    // --- GNN aggregation / second layer ---
    gat1_gather_kernel<<<N, 256, 0, stream>>>(
        rowptr, csr_src, wcsr1, (const uint2*)h1, b1, (uint2*)g1b, N);

    gat2_proj_kernel<<<Np / 64, 256, 0, stream>>>(
        (const unsigned short*)g1b, (const short*)w2t, as2w, ad2w, h2, a_s2, a_d2, N);

    gat2_gather_kernel<<<(M + 3) / 4, 256, 0, stream>>>(
        rowptr, csr_src, h2, a_s2, a_d2, b2, mask, g2m, M);

    final_kernel<<<(M + 3) / 4, 64, 0, stream>>>(
        text_out, g2m, fcf_w, fcf_b, (float*)d_out, M);
}

// Round 8
// 213.039 us; speedup vs baseline: 3.2802x; 1.1405x over previous
//
#include <hip/hip_runtime.h>
#include <hip/hip_bf16.h>
#include <cmath>

#define TEXTD 500
#define GNN_DIM 128

typedef __attribute__((ext_vector_type(8))) short bf16x8;
typedef __attribute__((ext_vector_type(4))) float f32x4;

__device__ __forceinline__ float bf2f(unsigned short u) {
    union { unsigned int i; float f; } cv;
    cv.i = ((unsigned int)u) << 16;
    return cv.f;
}
__device__ __forceinline__ unsigned short f2b(float x) {
    __hip_bfloat16 b = __float2bfloat16(x);
    return *reinterpret_cast<unsigned short*>(&b);
}
__device__ __forceinline__ float u2f(unsigned int u) {
    union { unsigned int i; float f; } cv; cv.i = u; return cv.f;
}
// convert 8 consecutive floats at p (16B-aligned) to a bf16x8 fragment
__device__ __forceinline__ bf16x8 cvt8(const float* p) {
    float4 u = *(const float4*)p;
    float4 v = *(const float4*)(p + 4);
    bf16x8 f;
    f[0] = (short)f2b(u.x); f[1] = (short)f2b(u.y);
    f[2] = (short)f2b(u.z); f[3] = (short)f2b(u.w);
    f[4] = (short)f2b(v.x); f[5] = (short)f2b(v.y);
    f[6] = (short)f2b(v.z); f[7] = (short)f2b(v.w);
    return f;
}

// ---------------- weight conversion: w1cat [144x512], w1g [128x128], w2t [16x128] ----------------
__global__ __launch_bounds__(256) void conv_w_kernel(
    const float* __restrict__ fc1_w, const float* __restrict__ sc_w,
    const float* __restrict__ W1, const float* __restrict__ W2,
    unsigned short* __restrict__ w1cat, unsigned short* __restrict__ w1g,
    unsigned short* __restrict__ w2t)
{
    int idx = blockIdx.x * 256 + threadIdx.x;
    if (idx < 144 * 512) {
        int n = idx >> 9, k = idx & 511;
        float v = 0.f;
        if (k < TEXTD) v = (n < 128) ? fc1_w[k * 128 + n] : sc_w[k * 16 + (n - 128)];
        w1cat[idx] = f2b(v);
    } else if (idx < 144 * 512 + 128 * 128) {
        int j = idx - 144 * 512;
        int n = j >> 7, k = j & 127;
        w1g[j] = f2b(W1[k * 128 + n]);
    } else if (idx < 144 * 512 + 128 * 128 + 16 * 128) {
        int j = idx - (144 * 512 + 128 * 128);
        int n = j >> 7, k = j & 127;
        w2t[j] = f2b(W2[k * 16 + n]);
    }
}

// ---------------- GEMM1: text[fp32, Mx500] x w1cat[144x512]^T -> t1(relu+b), tsc(+b) ----------------
__global__ __launch_bounds__(256) void gemm_text_kernel(
    const float* __restrict__ text, const short* __restrict__ B,
    const float* __restrict__ fc1_b, const float* __restrict__ sc_b,
    float* __restrict__ t1, float* __restrict__ tsc, int M)
{
    const int tid = threadIdx.x;
    const int wave = tid >> 6, lane = tid & 63;
    const int q = lane >> 4, col = lane & 15;
    const int mb = blockIdx.x * 64 + wave * 16;
    const int arow = min(mb + col, M - 1);
    const float* ap = text + (size_t)arow * TEXTD + q * 8;

    bf16x8 afrag[16];
    #pragma unroll
    for (int ks = 0; ks < 15; ks++) afrag[ks] = cvt8(ap + ks * 32);
    {   // ks = 15: K 480..511, zero-pad past 500
        bf16x8 f;
        int k0 = 480 + q * 8;
        #pragma unroll
        for (int e = 0; e < 8; e++) {
            int k = k0 + e;
            f[e] = (short)((k < TEXTD) ? f2b(text[(size_t)arow * TEXTD + k]) : 0);
        }
        afrag[15] = f;
    }

    for (int nb = 0; nb < 9; nb++) {
        const short* bp = B + (size_t)(nb * 16 + col) * 512 + q * 8;
        f32x4 acc = {0.f, 0.f, 0.f, 0.f};
        #pragma unroll
        for (int ks = 0; ks < 16; ks++)
            acc = __builtin_amdgcn_mfma_f32_16x16x32_bf16(afrag[ks], *(const bf16x8*)(bp + ks * 32), acc, 0, 0, 0);
        #pragma unroll
        for (int i = 0; i < 4; i++) {
            int row = mb + q * 4 + i;
            if (row < M) {
                if (nb < 8) t1[(size_t)row * 128 + nb * 16 + col] = fmaxf(acc[i] + fc1_b[nb * 16 + col], 0.f);
                else        tsc[(size_t)row * 16 + col] = acc[i] + sc_b[col];
            }
        }
    }
}

// ---------------- GEMM2: x[fp32, Nx128] @ W1 -> h1 bf16; fused a_s1/a_d1 epilogue ----------------
__global__ __launch_bounds__(256) void gemm_h1_kernel(
    const float* __restrict__ x, const short* __restrict__ B,
    const float* __restrict__ as1w, const float* __restrict__ ad1w,
    unsigned short* __restrict__ h1, float* __restrict__ a_s, float* __restrict__ a_d, int N)
{
    const int tid = threadIdx.x;
    const int wave = tid >> 6, lane = tid & 63;
    const int q = lane >> 4, col = lane & 15;
    const int mb = blockIdx.x * 64 + wave * 16;
    const int arow = min(mb + col, N - 1);
    const float* ap = x + (size_t)arow * 128 + q * 8;

    bf16x8 afrag[4];
    #pragma unroll
    for (int ks = 0; ks < 4; ks++) afrag[ks] = cvt8(ap + ks * 32);

    float ps0[4] = {0,0,0,0}, ps1[4] = {0,0,0,0};
    float pd0[4] = {0,0,0,0}, pd1[4] = {0,0,0,0};

    #pragma unroll
    for (int nb = 0; nb < 8; nb++) {
        const short* bp = B + (size_t)(nb * 16 + col) * 128 + q * 8;
        f32x4 acc = {0.f, 0.f, 0.f, 0.f};
        #pragma unroll
        for (int ks = 0; ks < 4; ks++)
            acc = __builtin_amdgcn_mfma_f32_16x16x32_bf16(afrag[ks], *(const bf16x8*)(bp + ks * 32), acc, 0, 0, 0);
        const int j = nb * 16 + col;
        const float asj = as1w[j], adj = ad1w[j];
        #pragma unroll
        for (int i = 0; i < 4; i++) {
            int row = mb + q * 4 + i;
            if (row < N) h1[(size_t)row * 128 + j] = f2b(acc[i]);
            if (nb < 4) { ps0[i] = fmaf(acc[i], asj, ps0[i]); pd0[i] = fmaf(acc[i], adj, pd0[i]); }
            else        { ps1[i] = fmaf(acc[i], asj, ps1[i]); pd1[i] = fmaf(acc[i], adj, pd1[i]); }
        }
    }
    #pragma unroll
    for (int i = 0; i < 4; i++) {
        float v0 = ps0[i], v1 = ps1[i], w0 = pd0[i], w1 = pd1[i];
        #pragma unroll
        for (int off = 1; off < 16; off <<= 1) {
            v0 += __shfl_xor(v0, off, 16);
            v1 += __shfl_xor(v1, off, 16);
            w0 += __shfl_xor(w0, off, 16);
            w1 += __shfl_xor(w1, off, 16);
        }
        int row = mb + q * 4 + i;
        if (col == 0 && row < N) {
            a_s[2 * row] = v0; a_s[2 * row + 1] = v1;
            a_d[2 * row] = w0; a_d[2 * row + 1] = w1;
        }
    }
}

// ---------------- text tail: fc2/fc3/fc4 + shortcut ----------------
__global__ __launch_bounds__(128) void text_tail_kernel(
    const float* __restrict__ t1g, const float* __restrict__ tsc,
    const float* __restrict__ fc2_w, const float* __restrict__ fc2_b,
    const float* __restrict__ fc3_w, const float* __restrict__ fc3_b,
    const float* __restrict__ fc4_w, const float* __restrict__ fc4_b,
    float* __restrict__ text_out, int M)
{
    __shared__ float t1[8][128];
    __shared__ float t2[8][64];
    __shared__ float t3[8][16];
    const int tid = threadIdx.x;
    const int m0 = blockIdx.x * 8;

    for (int r = 0; r < 8; r++) {
        int row = m0 + r;
        t1[r][tid] = (row < M) ? t1g[(size_t)row * 128 + tid] : 0.f;
    }
    __syncthreads();

    const int r2 = tid >> 6, c2 = tid & 63;
    for (int rb = 0; rb < 4; rb++) {
        int row = rb * 2 + r2;
        float a2 = fc2_b[c2];
        for (int k = 0; k < 128; k++) a2 = fmaf(t1[row][k], fc2_w[k * 64 + c2], a2);
        t2[row][c2] = fmaxf(a2, 0.f);
    }
    __syncthreads();

    const int rs = tid >> 4, cs = tid & 15;
    float a3 = fc3_b[cs];
    for (int k = 0; k < 64; k++) a3 = fmaf(t2[rs][k], fc3_w[k * 16 + cs], a3);
    t3[rs][cs] = fmaxf(a3, 0.f);
    __syncthreads();

    float a4 = fc4_b[cs];
    #pragma unroll
    for (int k = 0; k < 16; k++) a4 = fmaf(t3[rs][k], fc4_w[k * 16 + cs], a4);
    int row = m0 + rs;
    if (row < M) text_out[(size_t)row * 16 + cs] = a4 + tsc[(size_t)row * 16 + cs];
}

// ---------------- CSR build ----------------
// histogram + per-edge rank (old count) in one atomic
__global__ __launch_bounds__(256) void deg_hist_kernel(
    const int* __restrict__ edst, int* __restrict__ deg, int* __restrict__ rank, int E)
{
    int e = blockIdx.x * 256 + threadIdx.x;
    if (e < E) rank[e] = atomicAdd(&deg[edst[e]], 1);
}

// phase 1: per-256-tile sums of (deg[i]+1)
__global__ __launch_bounds__(256) void part_kernel(
    const int* __restrict__ deg, int* __restrict__ bsum, int N)
{
    const int tid = threadIdx.x;
    int i = blockIdx.x * 256 + tid;
    int d = (i < N) ? deg[i] + 1 : 0;
    #pragma unroll
    for (int off = 32; off > 0; off >>= 1) d += __shfl_down(d, off, 64);
    __shared__ int wsum[4];
    if ((tid & 63) == 0) wsum[tid >> 6] = d;
    __syncthreads();
    if (tid == 0) bsum[blockIdx.x] = wsum[0] + wsum[1] + wsum[2] + wsum[3];
}

// phase 2: exclusive scan of block sums (NB <= 256)
__global__ __launch_bounds__(256) void scan_bsums_kernel(
    int* __restrict__ bsum, int NB)
{
    __shared__ int sc[256];
    const int tid = threadIdx.x;
    int v = (tid < NB) ? bsum[tid] : 0;
    sc[tid] = v;
    for (int off = 1; off < 256; off <<= 1) {
        __syncthreads();
        int t = (tid >= off) ? sc[tid - off] : 0;
        __syncthreads();
        sc[tid] += t;
    }
    __syncthreads();
    if (tid < NB) bsum[tid] = sc[tid] - v;   // exclusive
}

// phase 3: in-block scan + offset -> rowptr
__global__ __launch_bounds__(256) void rowptr_kernel(
    const int* __restrict__ deg, const int* __restrict__ bsum,
    int* __restrict__ rowptr, int N)
{
    __shared__ int sc[256];
    const int tid = threadIdx.x;
    const int i = blockIdx.x * 256 + tid;
    int d = (i < N) ? deg[i] + 1 : 0;
    sc[tid] = d;
    for (int off = 1; off < 256; off <<= 1) {
        __syncthreads();
        int t = (tid >= off) ? sc[tid - off] : 0;
        __syncthreads();
        sc[tid] += t;
    }
    __syncthreads();
    int incl = sc[tid];
    int base = bsum[blockIdx.x];
    if (i < N) rowptr[i] = base + incl - d;
    if (i == N - 1) rowptr[N] = base + incl;
}

__device__ __forceinline__ float edge_w(float e) {
    return __expf(e > 0.f ? e : 0.2f * e);
}

// fill CSR slots: single 8B store per edge {src, bf16 w0 | w1<<16}; no atomics
__global__ __launch_bounds__(256) void fillw_kernel(
    const int* __restrict__ esrc, const int* __restrict__ edst,
    const int* __restrict__ rank, const int* __restrict__ rowptr,
    uint2* __restrict__ eslot,
    const float* __restrict__ a_s, const float* __restrict__ a_d, int E, int N)
{
    int e = blockIdx.x * 256 + threadIdx.x;
    if (e < E) {
        int src = esrc[e], dst = edst[e];
        int pos = rowptr[dst] + 1 + rank[e];
        float2 as = *(const float2*)(a_s + 2 * src);
        float2 ad = *(const float2*)(a_d + 2 * dst);
        unsigned int w0 = f2b(edge_w(as.x + ad.x));
        unsigned int w1 = f2b(edge_w(as.y + ad.y));
        uint2 o; o.x = (unsigned int)src; o.y = (w1 << 16) | w0;
        eslot[pos] = o;
    } else if (e < E + N) {
        int v = e - E;
        float2 as = *(const float2*)(a_s + 2 * v);
        float2 ad = *(const float2*)(a_d + 2 * v);
        unsigned int w0 = f2b(edge_w(as.x + ad.x));
        unsigned int w1 = f2b(edge_w(as.y + ad.y));
        uint2 o; o.x = (unsigned int)v; o.y = (w1 << 16) | w0;
        eslot[rowptr[v]] = o;
    }
}

// ---------------- layer-1 gather: 1 node/block, 8 slots x 32 lanes(x4 dims) ----------------
template<int B>
__device__ __forceinline__ void gat1_batch(
    int i0, int end, int endm1, int wsh,
    const uint2* __restrict__ eslot, const uint2* __restrict__ h1u, int dp,
    float& a0, float& a1, float& a2, float& a3, float& den)
{
    int ics[B];
    uint2 sl[B];
    float wv[B];
    uint2 hv[B];
    #pragma unroll
    for (int k = 0; k < B; k++) ics[k] = min(i0 + 8 * k, endm1);
    #pragma unroll
    for (int k = 0; k < B; k++) sl[k] = eslot[ics[k]];
    #pragma unroll
    for (int k = 0; k < B; k++) {
        float w = u2f((sl[k].y << wsh) & 0xffff0000u);
        wv[k] = (i0 + 8 * k < end) ? w : 0.f;
    }
    #pragma unroll
    for (int k = 0; k < B; k++) hv[k] = h1u[(size_t)sl[k].x * 32 + dp];
    #pragma unroll
    for (int k = 0; k < B; k++) {
        float w = wv[k];
        den += w;
        a0 = fmaf(w, u2f(hv[k].x << 16),          a0);
        a1 = fmaf(w, u2f(hv[k].x & 0xffff0000u),  a1);
        a2 = fmaf(w, u2f(hv[k].y << 16),          a2);
        a3 = fmaf(w, u2f(hv[k].y & 0xffff0000u),  a3);
    }
}

__global__ __launch_bounds__(256) void gat1_gather_kernel(
    const int* __restrict__ rowptr, const uint2* __restrict__ eslot,
    const uint2* __restrict__ h1u,
    const float* __restrict__ b1, uint2* __restrict__ g1b, int N)
{
    __shared__ float4 accs[3][32];
    __shared__ float  dens[3][32];
    const int v = blockIdx.x;
    const int tid = threadIdx.x;
    const int wave = tid >> 6, lane = tid & 63;
    const int slot = wave * 2 + (lane >> 5);   // 0..7
    const int dp = lane & 31;                  // dims 4dp..4dp+3
    const int head = dp >> 4;
    const int wsh = head ? 0 : 16;             // bf16 weight unpack shift
    const int beg = rowptr[v], end = rowptr[v + 1];
    const int deg = end - beg;
    const int endm1 = end - 1;
    const int i0 = beg + slot;

    float a0 = 0.f, a1 = 0.f, a2 = 0.f, a3 = 0.f, den = 0.f;

    if (deg <= 16) {
        gat1_batch<2>(i0, end, endm1, wsh, eslot, h1u, dp, a0, a1, a2, a3, den);
    } else {
        gat1_batch<4>(i0, end, endm1, wsh, eslot, h1u, dp, a0, a1, a2, a3, den);
        for (int i = i0 + 32; i < end; i += 8) {
            uint2 sl = eslot[i];
            float w = u2f((sl.y << wsh) & 0xffff0000u);
            uint2 hv = h1u[(size_t)sl.x * 32 + dp];
            den += w;
            a0 = fmaf(w, u2f(hv.x << 16),         a0);
            a1 = fmaf(w, u2f(hv.x & 0xffff0000u), a1);
            a2 = fmaf(w, u2f(hv.y << 16),         a2);
            a3 = fmaf(w, u2f(hv.y & 0xffff0000u), a3);
        }
    }

    // combine the two slots within each wave
    a0 += __shfl_xor(a0, 32, 64);
    a1 += __shfl_xor(a1, 32, 64);
    a2 += __shfl_xor(a2, 32, 64);
    a3 += __shfl_xor(a3, 32, 64);
    den += __shfl_xor(den, 32, 64);

    if (wave > 0 && lane < 32) {
        accs[wave - 1][dp] = make_float4(a0, a1, a2, a3);
        dens[wave - 1][dp] = den;
    }
    __syncthreads();
    if (wave == 0 && lane < 32) {
        #pragma unroll
        for (int s = 0; s < 3; s++) {
            float4 t = accs[s][dp];
            a0 += t.x; a1 += t.y; a2 += t.z; a3 += t.w;
            den += dens[s][dp];
        }
        float inv = 1.f / (den + 1e-16f);
        float4 bv = *(const float4*)(b1 + 4 * dp);
        float o0 = fmaxf(fmaf(a0, inv, bv.x), 0.f);
        float o1 = fmaxf(fmaf(a1, inv, bv.y), 0.f);
        float o2 = fmaxf(fmaf(a2, inv, bv.z), 0.f);
        float o3 = fmaxf(fmaf(a3, inv, bv.w), 0.f);
        uint2 o;
        o.x = ((unsigned int)f2b(o1) << 16) | f2b(o0);
        o.y = ((unsigned int)f2b(o3) << 16) | f2b(o2);
        g1b[(size_t)v * 32 + dp] = o;
    }
}

// ---------------- gat2 projection (MFMA): h2 = g1b @ W2; fused a_s2/a_d2 ----------------
__global__ __launch_bounds__(256) void gat2_proj_kernel(
    const unsigned short* __restrict__ g1b, const short* __restrict__ w2t,
    const float* __restrict__ as2w, const float* __restrict__ ad2w,
    float* __restrict__ h2, float* __restrict__ a_s2, float* __restrict__ a_d2, int N)
{
    const int tid = threadIdx.x;
    const int wave = tid >> 6, lane = tid & 63;
    const int q = lane >> 4, col = lane & 15;
    const int mb = blockIdx.x * 64 + wave * 16;
    const int arow = min(mb + col, N - 1);
    const short* ap = (const short*)g1b + (size_t)arow * 128 + q * 8;
    const short* bp = w2t + (size_t)col * 128 + q * 8;

    f32x4 acc = {0.f, 0.f, 0.f, 0.f};
    #pragma unroll
    for (int ks = 0; ks < 4; ks++)
        acc = __builtin_amdgcn_mfma_f32_16x16x32_bf16(
            *(const bf16x8*)(ap + ks * 32), *(const bf16x8*)(bp + ks * 32), acc, 0, 0, 0);

    const float asj = as2w[col], adj = ad2w[col];
    #pragma unroll
    for (int i = 0; i < 4; i++) {
        int row = mb + q * 4 + i;
        float ps = acc[i] * asj, pd = acc[i] * adj;
        #pragma unroll
        for (int off = 1; off < 16; off <<= 1) {
            ps += __shfl_xor(ps, off, 16);
            pd += __shfl_xor(pd, off, 16);
        }
        if (row < N) {
            h2[(size_t)row * 16 + col] = acc[i];
            if (col == 0) { a_s2[row] = ps; a_d2[row] = pd; }
        }
    }
}

// ---------------- layer-2 gather (masked): 4 nodes/block, 4 slots x 16 dims, MLP-8 prefetch ----------------
__global__ __launch_bounds__(256) void gat2_gather_kernel(
    const int* __restrict__ rowptr, const uint2* __restrict__ eslot,
    const float* __restrict__ h2,
    const float* __restrict__ a_s2, const float* __restrict__ a_d2,
    const float* __restrict__ b2, const int* __restrict__ mask,
    float* __restrict__ g2m, int M)
{
    const int tid = threadIdx.x;
    const int m = blockIdx.x * 4 + (tid >> 6);
    if (m >= M) return;
    const int lane = tid & 63, slot = lane >> 4, c = lane & 15;
    const int v = mask[m];
    const float adv = a_d2[v];
    const int beg = rowptr[v], end = rowptr[v + 1];
    const int i0 = beg + slot;

    float acc = 0.f, den = 0.f;
    int   idxs[8];
    float msk[8], as_[8], hval[8];
    #pragma unroll
    for (int k = 0; k < 8; k++) {
        int i = i0 + 4 * k;
        int ic = min(i, end - 1);
        idxs[k] = (int)eslot[ic].x;
        msk[k] = (i < end) ? 1.f : 0.f;
    }
    #pragma unroll
    for (int k = 0; k < 8; k++) as_[k] = a_s2[idxs[k]];
    #pragma unroll
    for (int k = 0; k < 8; k++) hval[k] = h2[(size_t)idxs[k] * 16 + c];
    #pragma unroll
    for (int k = 0; k < 8; k++) {
        float e = as_[k] + adv;
        float w = msk[k] * __expf(e > 0.f ? e : 0.2f * e);
        den += w;
        acc = fmaf(w, hval[k], acc);
    }
    for (int i = i0 + 32; i < end; i += 4) {
        int src = (int)eslot[i].x;
        float e = a_s2[src] + adv;
        float w = __expf(e > 0.f ? e : 0.2f * e);
        den += w;
        acc = fmaf(w, h2[(size_t)src * 16 + c], acc);
    }

    acc += __shfl_xor(acc, 16, 64);
    acc += __shfl_xor(acc, 32, 64);
    den += __shfl_xor(den, 16, 64);
    den += __shfl_xor(den, 32, 64);
    if (slot == 0) g2m[(size_t)m * 16 + c] = acc / (den + 1e-16f) + b2[c];
}

// ---------------- fused head ----------------
__global__ __launch_bounds__(64) void final_kernel(
    const float* __restrict__ text_out, const float* __restrict__ g2m,
    const float* __restrict__ fcf_w, const float* __restrict__ fcf_b,
    float* __restrict__ out, int M)
{
    const int lane = threadIdx.x;
    const int g = lane >> 4, j = lane & 15;
    const int m = blockIdx.x * 4 + g;
    if (m >= M) return;

    float tval = text_out[(size_t)m * 16 + j];
    float gval = g2m[(size_t)m * 16 + j];

    float logit = fcf_b[j];
    #pragma unroll
    for (int k = 0; k < 16; k++) {
        logit = fmaf(__shfl(tval, k, 16), fcf_w[k * 16 + j], logit);
        logit = fmaf(__shfl(gval, k, 16), fcf_w[(16 + k) * 16 + j], logit);
    }
    float mx = logit;
    #pragma unroll
    for (int off = 8; off > 0; off >>= 1) mx = fmaxf(mx, __shfl_xor(mx, off, 16));
    float se = expf(logit - mx);
    #pragma unroll
    for (int off = 8; off > 0; off >>= 1) se += __shfl_xor(se, off, 16);
    out[(size_t)m * 16 + j] = logit - mx - logf(se);
}

extern "C" void kernel_launch(void* const* d_in, const int* in_sizes, int n_in,
                              void* d_out, int out_size, void* d_ws, size_t ws_size,
                              hipStream_t stream)
{
    const float* text  = (const float*)d_in[0];
    const float* x     = (const float*)d_in[1];
    const int*   ei    = (const int*)  d_in[2];
    const int*   mask  = (const int*)  d_in[3];
    const float* fc1_w = (const float*)d_in[4];  const float* fc1_b = (const float*)d_in[5];
    const float* fc2_w = (const float*)d_in[6];  const float* fc2_b = (const float*)d_in[7];
    const float* fc3_w = (const float*)d_in[8];  const float* fc3_b = (const float*)d_in[9];
    const float* fc4_w = (const float*)d_in[10]; const float* fc4_b = (const float*)d_in[11];
    const float* sc_w  = (const float*)d_in[12]; const float* sc_b  = (const float*)d_in[13];
    const float* W1    = (const float*)d_in[14];
    const float* as1w  = (const float*)d_in[15]; const float* ad1w  = (const float*)d_in[16];
    const float* b1    = (const float*)d_in[17];
    const float* W2    = (const float*)d_in[18];
    const float* as2w  = (const float*)d_in[19]; const float* ad2w  = (const float*)d_in[20];
    const float* b2    = (const float*)d_in[21];
    const float* fcf_w = (const float*)d_in[22]; const float* fcf_b = (const float*)d_in[23];

    const int M  = in_sizes[3];
    const int N  = in_sizes[1] / GNN_DIM;
    const int E  = in_sizes[2] / 2;
    const int EP = E + N;
    const int* esrc = ei;
    const int* edst = ei + E;

    const int Mp = ((M + 63) / 64) * 64;
    const int Np = ((N + 63) / 64) * 64;
    const int NB = (N + 255) / 256;        // <= 256

    float* ws = (float*)d_ws;
    size_t off = 0;
    auto alloc = [&](size_t n) { float* p = ws + off; off += (n + 63) & ~size_t(63); return p; };

    unsigned short* h1    = (unsigned short*)alloc((size_t)Np * 64);   // bf16 [Np x 128]
    unsigned int*   g1b   = (unsigned int*)  alloc((size_t)N * 64);    // bf16 [N x 128] packed
    unsigned short* w1cat = (unsigned short*)alloc(144 * 256);         // bf16 [144 x 512]
    unsigned short* w1g   = (unsigned short*)alloc(128 * 64);          // bf16 [128 x 128]
    unsigned short* w2t   = (unsigned short*)alloc(16 * 64);           // bf16 [16 x 128]
    float* t1       = alloc((size_t)M * 128);
    float* tsc      = alloc((size_t)M * 16);
    float* a_s1     = alloc((size_t)2 * N);
    float* a_d1     = alloc((size_t)2 * N);
    float* h2       = alloc((size_t)N * 16);
    float* a_s2     = alloc(N);
    float* a_d2     = alloc(N);
    float* text_out = alloc((size_t)M * 16);
    float* g2m      = alloc((size_t)M * 16);
    uint2* eslot    = (uint2*)alloc((size_t)2 * EP);   // {src, bf16w0|bf16w1<<16}
    int* deg        = (int*)alloc(N);
    int* rank       = (int*)alloc(E);
    int* rowptr     = (int*)alloc(N + 1);
    int* bsum       = (int*)alloc(256);

    // --- CSR build: histogram(+rank) -> hierarchical scan ---
    hipMemsetAsync(deg, 0, (size_t)N * sizeof(int), stream);
    deg_hist_kernel<<<(E + 255) / 256, 256, 0, stream>>>(edst, deg, rank, E);
    part_kernel<<<NB, 256, 0, stream>>>(deg, bsum, N);
    scan_bsums_kernel<<<1, 256, 0, stream>>>(bsum, NB);
    rowptr_kernel<<<NB, 256, 0, stream>>>(deg, bsum, rowptr, N);

    // --- weights to bf16 ---
    conv_w_kernel<<<(144 * 512 + 128 * 128 + 16 * 128 + 255) / 256, 256, 0, stream>>>(
        fc1_w, sc_w, W1, W2, w1cat, w1g, w2t);

    // --- GAT1 projection (produces a_s1/a_d1 for weight fill) ---
    gemm_h1_kernel<<<Np / 64, 256, 0, stream>>>(
        x, (const short*)w1g, as1w, ad1w, h1, a_s1, a_d1, N);

    // --- CSR fill: single 8B slot per edge, no atomics ---
    fillw_kernel<<<(E + N + 255) / 256, 256, 0, stream>>>(
        esrc, edst, rank, rowptr, eslot, a_s1, a_d1, E, N);

    // --- text branch ---
    gemm_text_kernel<<<Mp / 64, 256, 0, stream>>>(
        text, (const short*)w1cat, fc1_b, sc_b, t1, tsc, M);
    text_tail_kernel<<<(M + 7) / 8, 128, 0, stream>>>(
        t1, tsc, fc2_w, fc2_b, fc3_w, fc3_b, fc4_w, fc4_b, text_out, M);

    // --- GNN aggregation / second layer ---
    gat1_gather_kernel<<<N, 256, 0, stream>>>(
        rowptr, eslot, (const uint2*)h1, b1, (uint2*)g1b, N);

    gat2_proj_kernel<<<Np / 64, 256, 0, stream>>>(
        (const unsigned short*)g1b, (const short*)w2t, as2w, ad2w, h2, a_s2, a_d2, N);

    gat2_gather_kernel<<<(M + 3) / 4, 256, 0, stream>>>(
        rowptr, eslot, h2, a_s2, a_d2, b2, mask, g2m, M);

    final_kernel<<<(M + 3) / 4, 64, 0, stream>>>(
        text_out, g2m, fcf_w, fcf_b, (float*)d_out, M);
}

// Round 9
// 205.749 us; speedup vs baseline: 3.3964x; 1.0354x over previous
//
#include <hip/hip_runtime.h>
#include <hip/hip_bf16.h>
#include <cmath>

#define TEXTD 500
#define GNN_DIM 128

typedef __attribute__((ext_vector_type(8))) short bf16x8;
typedef __attribute__((ext_vector_type(4))) float f32x4;

__device__ __forceinline__ float bf2f(unsigned short u) {
    union { unsigned int i; float f; } cv;
    cv.i = ((unsigned int)u) << 16;
    return cv.f;
}
__device__ __forceinline__ unsigned short f2b(float x) {
    __hip_bfloat16 b = __float2bfloat16(x);
    return *reinterpret_cast<unsigned short*>(&b);
}
__device__ __forceinline__ float u2f(unsigned int u) {
    union { unsigned int i; float f; } cv; cv.i = u; return cv.f;
}
// convert 8 consecutive floats at p (16B-aligned) to a bf16x8 fragment
__device__ __forceinline__ bf16x8 cvt8(const float* p) {
    float4 u = *(const float4*)p;
    float4 v = *(const float4*)(p + 4);
    bf16x8 f;
    f[0] = (short)f2b(u.x); f[1] = (short)f2b(u.y);
    f[2] = (short)f2b(u.z); f[3] = (short)f2b(u.w);
    f[4] = (short)f2b(v.x); f[5] = (short)f2b(v.y);
    f[6] = (short)f2b(v.z); f[7] = (short)f2b(v.w);
    return f;
}

// ---------------- weight conversion: w1cat [144x512], w1g [128x128], w2t [16x128] ----------------
__global__ __launch_bounds__(256) void conv_w_kernel(
    const float* __restrict__ fc1_w, const float* __restrict__ sc_w,
    const float* __restrict__ W1, const float* __restrict__ W2,
    unsigned short* __restrict__ w1cat, unsigned short* __restrict__ w1g,
    unsigned short* __restrict__ w2t)
{
    int idx = blockIdx.x * 256 + threadIdx.x;
    if (idx < 144 * 512) {
        int n = idx >> 9, k = idx & 511;
        float v = 0.f;
        if (k < TEXTD) v = (n < 128) ? fc1_w[k * 128 + n] : sc_w[k * 16 + (n - 128)];
        w1cat[idx] = f2b(v);
    } else if (idx < 144 * 512 + 128 * 128) {
        int j = idx - 144 * 512;
        int n = j >> 7, k = j & 127;
        w1g[j] = f2b(W1[k * 128 + n]);
    } else if (idx < 144 * 512 + 128 * 128 + 16 * 128) {
        int j = idx - (144 * 512 + 128 * 128);
        int n = j >> 7, k = j & 127;
        w2t[j] = f2b(W2[k * 16 + n]);
    }
}

// ---------------- GEMM1: text[fp32, Mx500] x w1cat[144x512]^T -> t1(relu+b), tsc(+b) ----------------
__global__ __launch_bounds__(256) void gemm_text_kernel(
    const float* __restrict__ text, const short* __restrict__ B,
    const float* __restrict__ fc1_b, const float* __restrict__ sc_b,
    float* __restrict__ t1, float* __restrict__ tsc, int M)
{
    const int tid = threadIdx.x;
    const int wave = tid >> 6, lane = tid & 63;
    const int q = lane >> 4, col = lane & 15;
    const int mb = blockIdx.x * 64 + wave * 16;
    const int arow = min(mb + col, M - 1);
    const float* ap = text + (size_t)arow * TEXTD + q * 8;

    bf16x8 afrag[16];
    #pragma unroll
    for (int ks = 0; ks < 15; ks++) afrag[ks] = cvt8(ap + ks * 32);
    {   // ks = 15: K 480..511, zero-pad past 500
        bf16x8 f;
        int k0 = 480 + q * 8;
        #pragma unroll
        for (int e = 0; e < 8; e++) {
            int k = k0 + e;
            f[e] = (short)((k < TEXTD) ? f2b(text[(size_t)arow * TEXTD + k]) : 0);
        }
        afrag[15] = f;
    }

    for (int nb = 0; nb < 9; nb++) {
        const short* bp = B + (size_t)(nb * 16 + col) * 512 + q * 8;
        f32x4 acc = {0.f, 0.f, 0.f, 0.f};
        #pragma unroll
        for (int ks = 0; ks < 16; ks++)
            acc = __builtin_amdgcn_mfma_f32_16x16x32_bf16(afrag[ks], *(const bf16x8*)(bp + ks * 32), acc, 0, 0, 0);
        #pragma unroll
        for (int i = 0; i < 4; i++) {
            int row = mb + q * 4 + i;
            if (row < M) {
                if (nb < 8) t1[(size_t)row * 128 + nb * 16 + col] = fmaxf(acc[i] + fc1_b[nb * 16 + col], 0.f);
                else        tsc[(size_t)row * 16 + col] = acc[i] + sc_b[col];
            }
        }
    }
}

// ---------------- GEMM2: x[fp32, Nx128] @ W1 -> h1 bf16; fused a_s1/a_d1 epilogue ----------------
__global__ __launch_bounds__(256) void gemm_h1_kernel(
    const float* __restrict__ x, const short* __restrict__ B,
    const float* __restrict__ as1w, const float* __restrict__ ad1w,
    unsigned short* __restrict__ h1, float* __restrict__ a_s, float* __restrict__ a_d, int N)
{
    const int tid = threadIdx.x;
    const int wave = tid >> 6, lane = tid & 63;
    const int q = lane >> 4, col = lane & 15;
    const int mb = blockIdx.x * 64 + wave * 16;
    const int arow = min(mb + col, N - 1);
    const float* ap = x + (size_t)arow * 128 + q * 8;

    bf16x8 afrag[4];
    #pragma unroll
    for (int ks = 0; ks < 4; ks++) afrag[ks] = cvt8(ap + ks * 32);

    float ps0[4] = {0,0,0,0}, ps1[4] = {0,0,0,0};
    float pd0[4] = {0,0,0,0}, pd1[4] = {0,0,0,0};

    #pragma unroll
    for (int nb = 0; nb < 8; nb++) {
        const short* bp = B + (size_t)(nb * 16 + col) * 128 + q * 8;
        f32x4 acc = {0.f, 0.f, 0.f, 0.f};
        #pragma unroll
        for (int ks = 0; ks < 4; ks++)
            acc = __builtin_amdgcn_mfma_f32_16x16x32_bf16(afrag[ks], *(const bf16x8*)(bp + ks * 32), acc, 0, 0, 0);
        const int j = nb * 16 + col;
        const float asj = as1w[j], adj = ad1w[j];
        #pragma unroll
        for (int i = 0; i < 4; i++) {
            int row = mb + q * 4 + i;
            if (row < N) h1[(size_t)row * 128 + j] = f2b(acc[i]);
            if (nb < 4) { ps0[i] = fmaf(acc[i], asj, ps0[i]); pd0[i] = fmaf(acc[i], adj, pd0[i]); }
            else        { ps1[i] = fmaf(acc[i], asj, ps1[i]); pd1[i] = fmaf(acc[i], adj, pd1[i]); }
        }
    }
    #pragma unroll
    for (int i = 0; i < 4; i++) {
        float v0 = ps0[i], v1 = ps1[i], w0 = pd0[i], w1 = pd1[i];
        #pragma unroll
        for (int off = 1; off < 16; off <<= 1) {
            v0 += __shfl_xor(v0, off, 16);
            v1 += __shfl_xor(v1, off, 16);
            w0 += __shfl_xor(w0, off, 16);
            w1 += __shfl_xor(w1, off, 16);
        }
        int row = mb + q * 4 + i;
        if (col == 0 && row < N) {
            a_s[2 * row] = v0; a_s[2 * row + 1] = v1;
            a_d[2 * row] = w0; a_d[2 * row + 1] = w1;
        }
    }
}

// ---------------- text tail: fc2/fc3/fc4 + shortcut ----------------
__global__ __launch_bounds__(128) void text_tail_kernel(
    const float* __restrict__ t1g, const float* __restrict__ tsc,
    const float* __restrict__ fc2_w, const float* __restrict__ fc2_b,
    const float* __restrict__ fc3_w, const float* __restrict__ fc3_b,
    const float* __restrict__ fc4_w, const float* __restrict__ fc4_b,
    float* __restrict__ text_out, int M)
{
    __shared__ float t1[8][128];
    __shared__ float t2[8][64];
    __shared__ float t3[8][16];
    const int tid = threadIdx.x;
    const int m0 = blockIdx.x * 8;

    for (int r = 0; r < 8; r++) {
        int row = m0 + r;
        t1[r][tid] = (row < M) ? t1g[(size_t)row * 128 + tid] : 0.f;
    }
    __syncthreads();

    const int r2 = tid >> 6, c2 = tid & 63;
    for (int rb = 0; rb < 4; rb++) {
        int row = rb * 2 + r2;
        float a2 = fc2_b[c2];
        for (int k = 0; k < 128; k++) a2 = fmaf(t1[row][k], fc2_w[k * 64 + c2], a2);
        t2[row][c2] = fmaxf(a2, 0.f);
    }
    __syncthreads();

    const int rs = tid >> 4, cs = tid & 15;
    float a3 = fc3_b[cs];
    for (int k = 0; k < 64; k++) a3 = fmaf(t2[rs][k], fc3_w[k * 16 + cs], a3);
    t3[rs][cs] = fmaxf(a3, 0.f);
    __syncthreads();

    float a4 = fc4_b[cs];
    #pragma unroll
    for (int k = 0; k < 16; k++) a4 = fmaf(t3[rs][k], fc4_w[k * 16 + cs], a4);
    int row = m0 + rs;
    if (row < M) text_out[(size_t)row * 16 + cs] = a4 + tsc[(size_t)row * 16 + cs];
}

// ---------------- CSR build ----------------
// histogram + per-edge rank (old count) in one atomic
__global__ __launch_bounds__(256) void deg_hist_kernel(
    const int* __restrict__ edst, int* __restrict__ deg, int* __restrict__ rank, int E)
{
    int e = blockIdx.x * 256 + threadIdx.x;
    if (e < E) rank[e] = atomicAdd(&deg[edst[e]], 1);
}

// phase 1: per-256-tile sums of (deg[i]+1)
__global__ __launch_bounds__(256) void part_kernel(
    const int* __restrict__ deg, int* __restrict__ bsum, int N)
{
    const int tid = threadIdx.x;
    int i = blockIdx.x * 256 + tid;
    int d = (i < N) ? deg[i] + 1 : 0;
    #pragma unroll
    for (int off = 32; off > 0; off >>= 1) d += __shfl_down(d, off, 64);
    __shared__ int wsum[4];
    if ((tid & 63) == 0) wsum[tid >> 6] = d;
    __syncthreads();
    if (tid == 0) bsum[blockIdx.x] = wsum[0] + wsum[1] + wsum[2] + wsum[3];
}

// phase 2: exclusive scan of block sums (NB <= 256)
__global__ __launch_bounds__(256) void scan_bsums_kernel(
    int* __restrict__ bsum, int NB)
{
    __shared__ int sc[256];
    const int tid = threadIdx.x;
    int v = (tid < NB) ? bsum[tid] : 0;
    sc[tid] = v;
    for (int off = 1; off < 256; off <<= 1) {
        __syncthreads();
        int t = (tid >= off) ? sc[tid - off] : 0;
        __syncthreads();
        sc[tid] += t;
    }
    __syncthreads();
    if (tid < NB) bsum[tid] = sc[tid] - v;   // exclusive
}

// phase 3: in-block scan + offset -> rowptr
__global__ __launch_bounds__(256) void rowptr_kernel(
    const int* __restrict__ deg, const int* __restrict__ bsum,
    int* __restrict__ rowptr, int N)
{
    __shared__ int sc[256];
    const int tid = threadIdx.x;
    const int i = blockIdx.x * 256 + tid;
    int d = (i < N) ? deg[i] + 1 : 0;
    sc[tid] = d;
    for (int off = 1; off < 256; off <<= 1) {
        __syncthreads();
        int t = (tid >= off) ? sc[tid - off] : 0;
        __syncthreads();
        sc[tid] += t;
    }
    __syncthreads();
    int incl = sc[tid];
    int base = bsum[blockIdx.x];
    if (i < N) rowptr[i] = base + incl - d;
    if (i == N - 1) rowptr[N] = base + incl;
}

__device__ __forceinline__ float edge_w(float e) {
    return __expf(e > 0.f ? e : 0.2f * e);
}

// fill CSR slots: single 8B store per edge {src, bf16 w0 | w1<<16}; no atomics
__global__ __launch_bounds__(256) void fillw_kernel(
    const int* __restrict__ esrc, const int* __restrict__ edst,
    const int* __restrict__ rank, const int* __restrict__ rowptr,
    uint2* __restrict__ eslot,
    const float* __restrict__ a_s, const float* __restrict__ a_d, int E, int N)
{
    int e = blockIdx.x * 256 + threadIdx.x;
    if (e < E) {
        int src = esrc[e], dst = edst[e];
        int pos = rowptr[dst] + 1 + rank[e];
        float2 as = *(const float2*)(a_s + 2 * src);
        float2 ad = *(const float2*)(a_d + 2 * dst);
        unsigned int w0 = f2b(edge_w(as.x + ad.x));
        unsigned int w1 = f2b(edge_w(as.y + ad.y));
        uint2 o; o.x = (unsigned int)src; o.y = (w1 << 16) | w0;
        eslot[pos] = o;
    } else if (e < E + N) {
        int v = e - E;
        float2 as = *(const float2*)(a_s + 2 * v);
        float2 ad = *(const float2*)(a_d + 2 * v);
        unsigned int w0 = f2b(edge_w(as.x + ad.x));
        unsigned int w1 = f2b(edge_w(as.y + ad.y));
        uint2 o; o.x = (unsigned int)v; o.y = (w1 << 16) | w0;
        eslot[rowptr[v]] = o;
    }
}

// ---------------- layer-1 gather v2: 1 WAVE/node (4 nodes/block), 2 slots x 32 lanes(x4 dims) ----------------
// B edges per slot, stride 2 (2 slots per wave); clamped + weight-masked
template<int B>
__device__ __forceinline__ void gat1_batch(
    int i0, int end, int endm1, int wsh,
    const uint2* __restrict__ eslot, const uint2* __restrict__ h1u, unsigned int dp,
    float& a0, float& a1, float& a2, float& a3, float& den)
{
    int ics[B];
    uint2 sl[B];
    float wv[B];
    uint2 hv[B];
    #pragma unroll
    for (int k = 0; k < B; k++) ics[k] = min(i0 + 2 * k, endm1);
    #pragma unroll
    for (int k = 0; k < B; k++) sl[k] = eslot[ics[k]];
    #pragma unroll
    for (int k = 0; k < B; k++) {
        float w = u2f((sl[k].y << wsh) & 0xffff0000u);
        wv[k] = (i0 + 2 * k < end) ? w : 0.f;
    }
    #pragma unroll
    for (int k = 0; k < B; k++) hv[k] = h1u[(sl[k].x << 5) | dp];
    #pragma unroll
    for (int k = 0; k < B; k++) {
        float w = wv[k];
        den += w;
        a0 = fmaf(w, u2f(hv[k].x << 16),          a0);
        a1 = fmaf(w, u2f(hv[k].x & 0xffff0000u),  a1);
        a2 = fmaf(w, u2f(hv[k].y << 16),          a2);
        a3 = fmaf(w, u2f(hv[k].y & 0xffff0000u),  a3);
    }
}

__global__ __launch_bounds__(256) void gat1_gather_kernel(
    const int* __restrict__ rowptr, const uint2* __restrict__ eslot,
    const uint2* __restrict__ h1u,
    const float* __restrict__ b1, uint2* __restrict__ g1b, int N)
{
    const int v = blockIdx.x * 4 + (threadIdx.x >> 6);
    if (v >= N) return;
    const int lane = threadIdx.x & 63;
    const int slot = lane >> 5;                // 0..1
    const unsigned int dp = lane & 31;         // dims 4dp..4dp+3
    const int head = dp >> 4;
    const int wsh = head ? 0 : 16;             // bf16 weight unpack shift
    const int beg = rowptr[v], end = rowptr[v + 1];
    const int deg = end - beg;
    const int endm1 = end - 1;
    const int i0 = beg + slot;

    float a0 = 0.f, a1 = 0.f, a2 = 0.f, a3 = 0.f, den = 0.f;

    if (deg <= 8) {
        gat1_batch<4>(i0, end, endm1, wsh, eslot, h1u, dp, a0, a1, a2, a3, den);
    } else {
        gat1_batch<8>(i0, end, endm1, wsh, eslot, h1u, dp, a0, a1, a2, a3, den);
        // tail in 8-capacity chunks (deg > 16)
        for (int base = i0 + 16; base < end; base += 8)
            gat1_batch<4>(base, end, endm1, wsh, eslot, h1u, dp, a0, a1, a2, a3, den);
    }

    // combine the two slots within the wave
    a0 += __shfl_xor(a0, 32, 64);
    a1 += __shfl_xor(a1, 32, 64);
    a2 += __shfl_xor(a2, 32, 64);
    a3 += __shfl_xor(a3, 32, 64);
    den += __shfl_xor(den, 32, 64);

    if (lane < 32) {
        float inv = 1.f / (den + 1e-16f);
        float4 bv = *(const float4*)(b1 + 4 * dp);
        float o0 = fmaxf(fmaf(a0, inv, bv.x), 0.f);
        float o1 = fmaxf(fmaf(a1, inv, bv.y), 0.f);
        float o2 = fmaxf(fmaf(a2, inv, bv.z), 0.f);
        float o3 = fmaxf(fmaf(a3, inv, bv.w), 0.f);
        uint2 o;
        o.x = ((unsigned int)f2b(o1) << 16) | f2b(o0);
        o.y = ((unsigned int)f2b(o3) << 16) | f2b(o2);
        g1b[((unsigned int)v << 5) | dp] = o;
    }
}

// ---------------- gat2 projection (MFMA): h2 = g1b @ W2; fused a_s2/a_d2 ----------------
__global__ __launch_bounds__(256) void gat2_proj_kernel(
    const unsigned short* __restrict__ g1b, const short* __restrict__ w2t,
    const float* __restrict__ as2w, const float* __restrict__ ad2w,
    float* __restrict__ h2, float* __restrict__ a_s2, float* __restrict__ a_d2, int N)
{
    const int tid = threadIdx.x;
    const int wave = tid >> 6, lane = tid & 63;
    const int q = lane >> 4, col = lane & 15;
    const int mb = blockIdx.x * 64 + wave * 16;
    const int arow = min(mb + col, N - 1);
    const short* ap = (const short*)g1b + (size_t)arow * 128 + q * 8;
    const short* bp = w2t + (size_t)col * 128 + q * 8;

    f32x4 acc = {0.f, 0.f, 0.f, 0.f};
    #pragma unroll
    for (int ks = 0; ks < 4; ks++)
        acc = __builtin_amdgcn_mfma_f32_16x16x32_bf16(
            *(const bf16x8*)(ap + ks * 32), *(const bf16x8*)(bp + ks * 32), acc, 0, 0, 0);

    const float asj = as2w[col], adj = ad2w[col];
    #pragma unroll
    for (int i = 0; i < 4; i++) {
        int row = mb + q * 4 + i;
        float ps = acc[i] * asj, pd = acc[i] * adj;
        #pragma unroll
        for (int off = 1; off < 16; off <<= 1) {
            ps += __shfl_xor(ps, off, 16);
            pd += __shfl_xor(pd, off, 16);
        }
        if (row < N) {
            h2[(size_t)row * 16 + col] = acc[i];
            if (col == 0) { a_s2[row] = ps; a_d2[row] = pd; }
        }
    }
}

// ---------------- layer-2 gather (masked): 4 nodes/block, 4 slots x 16 dims, MLP-8 prefetch ----------------
__global__ __launch_bounds__(256) void gat2_gather_kernel(
    const int* __restrict__ rowptr, const uint2* __restrict__ eslot,
    const float* __restrict__ h2,
    const float* __restrict__ a_s2, const float* __restrict__ a_d2,
    const float* __restrict__ b2, const int* __restrict__ mask,
    float* __restrict__ g2m, int M)
{
    const int tid = threadIdx.x;
    const int m = blockIdx.x * 4 + (tid >> 6);
    if (m >= M) return;
    const int lane = tid & 63, slot = lane >> 4, c = lane & 15;
    const int v = mask[m];
    const float adv = a_d2[v];
    const int beg = rowptr[v], end = rowptr[v + 1];
    const int i0 = beg + slot;

    float acc = 0.f, den = 0.f;
    unsigned int idxs[8];
    float msk[8], as_[8], hval[8];
    #pragma unroll
    for (int k = 0; k < 8; k++) {
        int i = i0 + 4 * k;
        int ic = min(i, end - 1);
        idxs[k] = eslot[ic].x;
        msk[k] = (i < end) ? 1.f : 0.f;
    }
    #pragma unroll
    for (int k = 0; k < 8; k++) as_[k] = a_s2[idxs[k]];
    #pragma unroll
    for (int k = 0; k < 8; k++) hval[k] = h2[(idxs[k] << 4) | (unsigned)c];
    #pragma unroll
    for (int k = 0; k < 8; k++) {
        float e = as_[k] + adv;
        float w = msk[k] * __expf(e > 0.f ? e : 0.2f * e);
        den += w;
        acc = fmaf(w, hval[k], acc);
    }
    for (int i = i0 + 32; i < end; i += 4) {
        unsigned int src = eslot[i].x;
        float e = a_s2[src] + adv;
        float w = __expf(e > 0.f ? e : 0.2f * e);
        den += w;
        acc = fmaf(w, h2[(src << 4) | (unsigned)c], acc);
    }

    acc += __shfl_xor(acc, 16, 64);
    acc += __shfl_xor(acc, 32, 64);
    den += __shfl_xor(den, 16, 64);
    den += __shfl_xor(den, 32, 64);
    if (slot == 0) g2m[(size_t)m * 16 + c] = acc / (den + 1e-16f) + b2[c];
}

// ---------------- fused head ----------------
__global__ __launch_bounds__(64) void final_kernel(
    const float* __restrict__ text_out, const float* __restrict__ g2m,
    const float* __restrict__ fcf_w, const float* __restrict__ fcf_b,
    float* __restrict__ out, int M)
{
    const int lane = threadIdx.x;
    const int g = lane >> 4, j = lane & 15;
    const int m = blockIdx.x * 4 + g;
    if (m >= M) return;

    float tval = text_out[(size_t)m * 16 + j];
    float gval = g2m[(size_t)m * 16 + j];

    float logit = fcf_b[j];
    #pragma unroll
    for (int k = 0; k < 16; k++) {
        logit = fmaf(__shfl(tval, k, 16), fcf_w[k * 16 + j], logit);
        logit = fmaf(__shfl(gval, k, 16), fcf_w[(16 + k) * 16 + j], logit);
    }
    float mx = logit;
    #pragma unroll
    for (int off = 8; off > 0; off >>= 1) mx = fmaxf(mx, __shfl_xor(mx, off, 16));
    float se = expf(logit - mx);
    #pragma unroll
    for (int off = 8; off > 0; off >>= 1) se += __shfl_xor(se, off, 16);
    out[(size_t)m * 16 + j] = logit - mx - logf(se);
}

extern "C" void kernel_launch(void* const* d_in, const int* in_sizes, int n_in,
                              void* d_out, int out_size, void* d_ws, size_t ws_size,
                              hipStream_t stream)
{
    const float* text  = (const float*)d_in[0];
    const float* x     = (const float*)d_in[1];
    const int*   ei    = (const int*)  d_in[2];
    const int*   mask  = (const int*)  d_in[3];
    const float* fc1_w = (const float*)d_in[4];  const float* fc1_b = (const float*)d_in[5];
    const float* fc2_w = (const float*)d_in[6];  const float* fc2_b = (const float*)d_in[7];
    const float* fc3_w = (const float*)d_in[8];  const float* fc3_b = (const float*)d_in[9];
    const float* fc4_w = (const float*)d_in[10]; const float* fc4_b = (const float*)d_in[11];
    const float* sc_w  = (const float*)d_in[12]; const float* sc_b  = (const float*)d_in[13];
    const float* W1    = (const float*)d_in[14];
    const float* as1w  = (const float*)d_in[15]; const float* ad1w  = (const float*)d_in[16];
    const float* b1    = (const float*)d_in[17];
    const float* W2    = (const float*)d_in[18];
    const float* as2w  = (const float*)d_in[19]; const float* ad2w  = (const float*)d_in[20];
    const float* b2    = (const float*)d_in[21];
    const float* fcf_w = (const float*)d_in[22]; const float* fcf_b = (const float*)d_in[23];

    const int M  = in_sizes[3];
    const int N  = in_sizes[1] / GNN_DIM;
    const int E  = in_sizes[2] / 2;
    const int EP = E + N;
    const int* esrc = ei;
    const int* edst = ei + E;

    const int Mp = ((M + 63) / 64) * 64;
    const int Np = ((N + 63) / 64) * 64;
    const int NB = (N + 255) / 256;        // <= 256

    float* ws = (float*)d_ws;
    size_t off = 0;
    auto alloc = [&](size_t n) { float* p = ws + off; off += (n + 63) & ~size_t(63); return p; };

    unsigned short* h1    = (unsigned short*)alloc((size_t)Np * 64);   // bf16 [Np x 128]
    unsigned int*   g1b   = (unsigned int*)  alloc((size_t)N * 64);    // bf16 [N x 128] packed
    unsigned short* w1cat = (unsigned short*)alloc(144 * 256);         // bf16 [144 x 512]
    unsigned short* w1g   = (unsigned short*)alloc(128 * 64);          // bf16 [128 x 128]
    unsigned short* w2t   = (unsigned short*)alloc(16 * 64);           // bf16 [16 x 128]
    float* t1       = alloc((size_t)M * 128);
    float* tsc      = alloc((size_t)M * 16);
    float* a_s1     = alloc((size_t)2 * N);
    float* a_d1     = alloc((size_t)2 * N);
    float* h2       = alloc((size_t)N * 16);
    float* a_s2     = alloc(N);
    float* a_d2     = alloc(N);
    float* text_out = alloc((size_t)M * 16);
    float* g2m      = alloc((size_t)M * 16);
    uint2* eslot    = (uint2*)alloc((size_t)2 * EP);   // {src, bf16w0|bf16w1<<16}
    int* deg        = (int*)alloc(N);
    int* rank       = (int*)alloc(E);
    int* rowptr     = (int*)alloc(N + 1);
    int* bsum       = (int*)alloc(256);

    // --- CSR build: histogram(+rank) -> hierarchical scan ---
    hipMemsetAsync(deg, 0, (size_t)N * sizeof(int), stream);
    deg_hist_kernel<<<(E + 255) / 256, 256, 0, stream>>>(edst, deg, rank, E);
    part_kernel<<<NB, 256, 0, stream>>>(deg, bsum, N);
    scan_bsums_kernel<<<1, 256, 0, stream>>>(bsum, NB);
    rowptr_kernel<<<NB, 256, 0, stream>>>(deg, bsum, rowptr, N);

    // --- weights to bf16 ---
    conv_w_kernel<<<(144 * 512 + 128 * 128 + 16 * 128 + 255) / 256, 256, 0, stream>>>(
        fc1_w, sc_w, W1, W2, w1cat, w1g, w2t);

    // --- GAT1 projection (produces a_s1/a_d1 for weight fill) ---
    gemm_h1_kernel<<<Np / 64, 256, 0, stream>>>(
        x, (const short*)w1g, as1w, ad1w, h1, a_s1, a_d1, N);

    // --- CSR fill: single 8B slot per edge, no atomics ---
    fillw_kernel<<<(E + N + 255) / 256, 256, 0, stream>>>(
        esrc, edst, rank, rowptr, eslot, a_s1, a_d1, E, N);

    // --- text branch ---
    gemm_text_kernel<<<Mp / 64, 256, 0, stream>>>(
        text, (const short*)w1cat, fc1_b, sc_b, t1, tsc, M);
    text_tail_kernel<<<(M + 7) / 8, 128, 0, stream>>>(
        t1, tsc, fc2_w, fc2_b, fc3_w, fc3_b, fc4_w, fc4_b, text_out, M);

    // --- GNN aggregation / second layer ---
    gat1_gather_kernel<<<(N + 3) / 4, 256, 0, stream>>>(
        rowptr, eslot, (const uint2*)h1, b1, (uint2*)g1b, N);

    gat2_proj_kernel<<<Np / 64, 256, 0, stream>>>(
        (const unsigned short*)g1b, (const short*)w2t, as2w, ad2w, h2, a_s2, a_d2, N);

    gat2_gather_kernel<<<(M + 3) / 4, 256, 0, stream>>>(
        rowptr, eslot, h2, a_s2, a_d2, b2, mask, g2m, M);

    final_kernel<<<(M + 3) / 4, 64, 0, stream>>>(
        text_out, g2m, fcf_w, fcf_b, (float*)d_out, M);
}

// Round 10
// 200.479 us; speedup vs baseline: 3.4857x; 1.0263x over previous
//
#include <hip/hip_runtime.h>
#include <hip/hip_bf16.h>
#include <cmath>

#define TEXTD 500
#define GNN_DIM 128
#define DEGP(v) ((v) << 5)   // one counter per 128B line

typedef __attribute__((ext_vector_type(8))) short bf16x8;
typedef __attribute__((ext_vector_type(4))) float f32x4;

__device__ __forceinline__ float bf2f(unsigned short u) {
    union { unsigned int i; float f; } cv;
    cv.i = ((unsigned int)u) << 16;
    return cv.f;
}
__device__ __forceinline__ unsigned short f2b(float x) {
    __hip_bfloat16 b = __float2bfloat16(x);
    return *reinterpret_cast<unsigned short*>(&b);
}
__device__ __forceinline__ float u2f(unsigned int u) {
    union { unsigned int i; float f; } cv; cv.i = u; return cv.f;
}
// convert 8 consecutive floats at p (16B-aligned) to a bf16x8 fragment
__device__ __forceinline__ bf16x8 cvt8(const float* p) {
    float4 u = *(const float4*)p;
    float4 v = *(const float4*)(p + 4);
    bf16x8 f;
    f[0] = (short)f2b(u.x); f[1] = (short)f2b(u.y);
    f[2] = (short)f2b(u.z); f[3] = (short)f2b(u.w);
    f[4] = (short)f2b(v.x); f[5] = (short)f2b(v.y);
    f[6] = (short)f2b(v.z); f[7] = (short)f2b(v.w);
    return f;
}

// ---------------- weight conversion: w1cat [144x512], w1g [128x128], w2t [16x128] ----------------
__global__ __launch_bounds__(256) void conv_w_kernel(
    const float* __restrict__ fc1_w, const float* __restrict__ sc_w,
    const float* __restrict__ W1, const float* __restrict__ W2,
    unsigned short* __restrict__ w1cat, unsigned short* __restrict__ w1g,
    unsigned short* __restrict__ w2t)
{
    int idx = blockIdx.x * 256 + threadIdx.x;
    if (idx < 144 * 512) {
        int n = idx >> 9, k = idx & 511;
        float v = 0.f;
        if (k < TEXTD) v = (n < 128) ? fc1_w[k * 128 + n] : sc_w[k * 16 + (n - 128)];
        w1cat[idx] = f2b(v);
    } else if (idx < 144 * 512 + 128 * 128) {
        int j = idx - 144 * 512;
        int n = j >> 7, k = j & 127;
        w1g[j] = f2b(W1[k * 128 + n]);
    } else if (idx < 144 * 512 + 128 * 128 + 16 * 128) {
        int j = idx - (144 * 512 + 128 * 128);
        int n = j >> 7, k = j & 127;
        w2t[j] = f2b(W2[k * 16 + n]);
    }
}

// ---------------- GEMM1: text[fp32, Mx500] x w1cat[144x512]^T -> t1(relu+b), tsc(+b) ----------------
__global__ __launch_bounds__(256) void gemm_text_kernel(
    const float* __restrict__ text, const short* __restrict__ B,
    const float* __restrict__ fc1_b, const float* __restrict__ sc_b,
    float* __restrict__ t1, float* __restrict__ tsc, int M)
{
    const int tid = threadIdx.x;
    const int wave = tid >> 6, lane = tid & 63;
    const int q = lane >> 4, col = lane & 15;
    const int mb = blockIdx.x * 64 + wave * 16;
    const int arow = min(mb + col, M - 1);
    const float* ap = text + (size_t)arow * TEXTD + q * 8;

    bf16x8 afrag[16];
    #pragma unroll
    for (int ks = 0; ks < 15; ks++) afrag[ks] = cvt8(ap + ks * 32);
    {   // ks = 15: K 480..511, zero-pad past 500
        bf16x8 f;
        int k0 = 480 + q * 8;
        #pragma unroll
        for (int e = 0; e < 8; e++) {
            int k = k0 + e;
            f[e] = (short)((k < TEXTD) ? f2b(text[(size_t)arow * TEXTD + k]) : 0);
        }
        afrag[15] = f;
    }

    for (int nb = 0; nb < 9; nb++) {
        const short* bp = B + (size_t)(nb * 16 + col) * 512 + q * 8;
        f32x4 acc = {0.f, 0.f, 0.f, 0.f};
        #pragma unroll
        for (int ks = 0; ks < 16; ks++)
            acc = __builtin_amdgcn_mfma_f32_16x16x32_bf16(afrag[ks], *(const bf16x8*)(bp + ks * 32), acc, 0, 0, 0);
        #pragma unroll
        for (int i = 0; i < 4; i++) {
            int row = mb + q * 4 + i;
            if (row < M) {
                if (nb < 8) t1[(size_t)row * 128 + nb * 16 + col] = fmaxf(acc[i] + fc1_b[nb * 16 + col], 0.f);
                else        tsc[(size_t)row * 16 + col] = acc[i] + sc_b[col];
            }
        }
    }
}

// ---------------- GEMM2: x[fp32, Nx128] @ W1 -> h1 bf16; fused a_s1/a_d1 epilogue ----------------
__global__ __launch_bounds__(256) void gemm_h1_kernel(
    const float* __restrict__ x, const short* __restrict__ B,
    const float* __restrict__ as1w, const float* __restrict__ ad1w,
    unsigned short* __restrict__ h1, float* __restrict__ a_s, float* __restrict__ a_d, int N)
{
    const int tid = threadIdx.x;
    const int wave = tid >> 6, lane = tid & 63;
    const int q = lane >> 4, col = lane & 15;
    const int mb = blockIdx.x * 64 + wave * 16;
    const int arow = min(mb + col, N - 1);
    const float* ap = x + (size_t)arow * 128 + q * 8;

    bf16x8 afrag[4];
    #pragma unroll
    for (int ks = 0; ks < 4; ks++) afrag[ks] = cvt8(ap + ks * 32);

    float ps0[4] = {0,0,0,0}, ps1[4] = {0,0,0,0};
    float pd0[4] = {0,0,0,0}, pd1[4] = {0,0,0,0};

    #pragma unroll
    for (int nb = 0; nb < 8; nb++) {
        const short* bp = B + (size_t)(nb * 16 + col) * 128 + q * 8;
        f32x4 acc = {0.f, 0.f, 0.f, 0.f};
        #pragma unroll
        for (int ks = 0; ks < 4; ks++)
            acc = __builtin_amdgcn_mfma_f32_16x16x32_bf16(afrag[ks], *(const bf16x8*)(bp + ks * 32), acc, 0, 0, 0);
        const int j = nb * 16 + col;
        const float asj = as1w[j], adj = ad1w[j];
        #pragma unroll
        for (int i = 0; i < 4; i++) {
            int row = mb + q * 4 + i;
            if (row < N) h1[(size_t)row * 128 + j] = f2b(acc[i]);
            if (nb < 4) { ps0[i] = fmaf(acc[i], asj, ps0[i]); pd0[i] = fmaf(acc[i], adj, pd0[i]); }
            else        { ps1[i] = fmaf(acc[i], asj, ps1[i]); pd1[i] = fmaf(acc[i], adj, pd1[i]); }
        }
    }
    #pragma unroll
    for (int i = 0; i < 4; i++) {
        float v0 = ps0[i], v1 = ps1[i], w0 = pd0[i], w1 = pd1[i];
        #pragma unroll
        for (int off = 1; off < 16; off <<= 1) {
            v0 += __shfl_xor(v0, off, 16);
            v1 += __shfl_xor(v1, off, 16);
            w0 += __shfl_xor(w0, off, 16);
            w1 += __shfl_xor(w1, off, 16);
        }
        int row = mb + q * 4 + i;
        if (col == 0 && row < N) {
            a_s[2 * row] = v0; a_s[2 * row + 1] = v1;
            a_d[2 * row] = w0; a_d[2 * row + 1] = w1;
        }
    }
}

// ---------------- text tail: fc2/fc3/fc4 + shortcut ----------------
__global__ __launch_bounds__(128) void text_tail_kernel(
    const float* __restrict__ t1g, const float* __restrict__ tsc,
    const float* __restrict__ fc2_w, const float* __restrict__ fc2_b,
    const float* __restrict__ fc3_w, const float* __restrict__ fc3_b,
    const float* __restrict__ fc4_w, const float* __restrict__ fc4_b,
    float* __restrict__ text_out, int M)
{
    __shared__ float t1[8][128];
    __shared__ float t2[8][64];
    __shared__ float t3[8][16];
    const int tid = threadIdx.x;
    const int m0 = blockIdx.x * 8;

    for (int r = 0; r < 8; r++) {
        int row = m0 + r;
        t1[r][tid] = (row < M) ? t1g[(size_t)row * 128 + tid] : 0.f;
    }
    __syncthreads();

    const int r2 = tid >> 6, c2 = tid & 63;
    for (int rb = 0; rb < 4; rb++) {
        int row = rb * 2 + r2;
        float a2 = fc2_b[c2];
        for (int k = 0; k < 128; k++) a2 = fmaf(t1[row][k], fc2_w[k * 64 + c2], a2);
        t2[row][c2] = fmaxf(a2, 0.f);
    }
    __syncthreads();

    const int rs = tid >> 4, cs = tid & 15;
    float a3 = fc3_b[cs];
    for (int k = 0; k < 64; k++) a3 = fmaf(t2[rs][k], fc3_w[k * 16 + cs], a3);
    t3[rs][cs] = fmaxf(a3, 0.f);
    __syncthreads();

    float a4 = fc4_b[cs];
    #pragma unroll
    for (int k = 0; k < 16; k++) a4 = fmaf(t3[rs][k], fc4_w[k * 16 + cs], a4);
    int row = m0 + rs;
    if (row < M) text_out[(size_t)row * 16 + cs] = a4 + tsc[(size_t)row * 16 + cs];
}

// ---------------- CSR build ----------------
// histogram (padded counters, 1/128B line) + per-edge rank; 4 edges/thread for MLP
__global__ __launch_bounds__(256) void deg_hist_kernel(
    const int* __restrict__ edst, int* __restrict__ deg, int* __restrict__ rank, int E)
{
    const int base = blockIdx.x * 1024 + threadIdx.x;
    int e0 = base;
    int e1 = base + 256;
    int e2 = base + 512;
    int e3 = base + 768;
    int d0 = (e0 < E) ? edst[e0] : -1;
    int d1 = (e1 < E) ? edst[e1] : -1;
    int d2 = (e2 < E) ? edst[e2] : -1;
    int d3 = (e3 < E) ? edst[e3] : -1;
    int r0 = (d0 >= 0) ? atomicAdd(&deg[DEGP(d0)], 1) : 0;
    int r1 = (d1 >= 0) ? atomicAdd(&deg[DEGP(d1)], 1) : 0;
    int r2 = (d2 >= 0) ? atomicAdd(&deg[DEGP(d2)], 1) : 0;
    int r3 = (d3 >= 0) ? atomicAdd(&deg[DEGP(d3)], 1) : 0;
    if (d0 >= 0) rank[e0] = r0;
    if (d1 >= 0) rank[e1] = r1;
    if (d2 >= 0) rank[e2] = r2;
    if (d3 >= 0) rank[e3] = r3;
}

// phase 1: per-256-tile sums of (deg[i]+1)
__global__ __launch_bounds__(256) void part_kernel(
    const int* __restrict__ deg, int* __restrict__ bsum, int N)
{
    const int tid = threadIdx.x;
    int i = blockIdx.x * 256 + tid;
    int d = (i < N) ? deg[DEGP(i)] + 1 : 0;
    #pragma unroll
    for (int off = 32; off > 0; off >>= 1) d += __shfl_down(d, off, 64);
    __shared__ int wsum[4];
    if ((tid & 63) == 0) wsum[tid >> 6] = d;
    __syncthreads();
    if (tid == 0) bsum[blockIdx.x] = wsum[0] + wsum[1] + wsum[2] + wsum[3];
}

// phase 2: exclusive scan of block sums (NB <= 256)
__global__ __launch_bounds__(256) void scan_bsums_kernel(
    int* __restrict__ bsum, int NB)
{
    __shared__ int sc[256];
    const int tid = threadIdx.x;
    int v = (tid < NB) ? bsum[tid] : 0;
    sc[tid] = v;
    for (int off = 1; off < 256; off <<= 1) {
        __syncthreads();
        int t = (tid >= off) ? sc[tid - off] : 0;
        __syncthreads();
        sc[tid] += t;
    }
    __syncthreads();
    if (tid < NB) bsum[tid] = sc[tid] - v;   // exclusive
}

// phase 3: in-block scan + offset -> rowptr
__global__ __launch_bounds__(256) void rowptr_kernel(
    const int* __restrict__ deg, const int* __restrict__ bsum,
    int* __restrict__ rowptr, int N)
{
    __shared__ int sc[256];
    const int tid = threadIdx.x;
    const int i = blockIdx.x * 256 + tid;
    int d = (i < N) ? deg[DEGP(i)] + 1 : 0;
    sc[tid] = d;
    for (int off = 1; off < 256; off <<= 1) {
        __syncthreads();
        int t = (tid >= off) ? sc[tid - off] : 0;
        __syncthreads();
        sc[tid] += t;
    }
    __syncthreads();
    int incl = sc[tid];
    int base = bsum[blockIdx.x];
    if (i < N) rowptr[i] = base + incl - d;
    if (i == N - 1) rowptr[N] = base + incl;
}

__device__ __forceinline__ float edge_w(float e) {
    return __expf(e > 0.f ? e : 0.2f * e);
}

// fill CSR slots: single 8B store per edge {src, bf16 w0 | w1<<16}; no atomics
__global__ __launch_bounds__(256) void fillw_kernel(
    const int* __restrict__ esrc, const int* __restrict__ edst,
    const int* __restrict__ rank, const int* __restrict__ rowptr,
    uint2* __restrict__ eslot,
    const float* __restrict__ a_s, const float* __restrict__ a_d, int E, int N)
{
    int e = blockIdx.x * 256 + threadIdx.x;
    if (e < E) {
        int src = esrc[e], dst = edst[e];
        int pos = rowptr[dst] + 1 + rank[e];
        float2 as = *(const float2*)(a_s + 2 * src);
        float2 ad = *(const float2*)(a_d + 2 * dst);
        unsigned int w0 = f2b(edge_w(as.x + ad.x));
        unsigned int w1 = f2b(edge_w(as.y + ad.y));
        uint2 o; o.x = (unsigned int)src; o.y = (w1 << 16) | w0;
        eslot[pos] = o;
    } else if (e < E + N) {
        int v = e - E;
        float2 as = *(const float2*)(a_s + 2 * v);
        float2 ad = *(const float2*)(a_d + 2 * v);
        unsigned int w0 = f2b(edge_w(as.x + ad.x));
        unsigned int w1 = f2b(edge_w(as.y + ad.y));
        uint2 o; o.x = (unsigned int)v; o.y = (w1 << 16) | w0;
        eslot[rowptr[v]] = o;
    }
}

// ---------------- layer-1 gather: 1 WAVE/node (4 nodes/block), 2 slots x 32 lanes(x4 dims) ----------------
template<int B>
__device__ __forceinline__ void gat1_batch(
    int i0, int end, int endm1, int wsh,
    const uint2* __restrict__ eslot, const uint2* __restrict__ h1u, unsigned int dp,
    float& a0, float& a1, float& a2, float& a3, float& den)
{
    int ics[B];
    uint2 sl[B];
    float wv[B];
    uint2 hv[B];
    #pragma unroll
    for (int k = 0; k < B; k++) ics[k] = min(i0 + 2 * k, endm1);
    #pragma unroll
    for (int k = 0; k < B; k++) sl[k] = eslot[ics[k]];
    #pragma unroll
    for (int k = 0; k < B; k++) {
        float w = u2f((sl[k].y << wsh) & 0xffff0000u);
        wv[k] = (i0 + 2 * k < end) ? w : 0.f;
    }
    #pragma unroll
    for (int k = 0; k < B; k++) hv[k] = h1u[(sl[k].x << 5) | dp];
    #pragma unroll
    for (int k = 0; k < B; k++) {
        float w = wv[k];
        den += w;
        a0 = fmaf(w, u2f(hv[k].x << 16),          a0);
        a1 = fmaf(w, u2f(hv[k].x & 0xffff0000u),  a1);
        a2 = fmaf(w, u2f(hv[k].y << 16),          a2);
        a3 = fmaf(w, u2f(hv[k].y & 0xffff0000u),  a3);
    }
}

__global__ __launch_bounds__(256) void gat1_gather_kernel(
    const int* __restrict__ rowptr, const uint2* __restrict__ eslot,
    const uint2* __restrict__ h1u,
    const float* __restrict__ b1, uint2* __restrict__ g1b, int N)
{
    const int v = blockIdx.x * 4 + (threadIdx.x >> 6);
    if (v >= N) return;
    const int lane = threadIdx.x & 63;
    const int slot = lane >> 5;                // 0..1
    const unsigned int dp = lane & 31;         // dims 4dp..4dp+3
    const int head = dp >> 4;
    const int wsh = head ? 0 : 16;             // bf16 weight unpack shift
    const int beg = rowptr[v], end = rowptr[v + 1];
    const int deg = end - beg;
    const int endm1 = end - 1;
    const int i0 = beg + slot;

    float a0 = 0.f, a1 = 0.f, a2 = 0.f, a3 = 0.f, den = 0.f;

    if (deg <= 8) {
        gat1_batch<4>(i0, end, endm1, wsh, eslot, h1u, dp, a0, a1, a2, a3, den);
    } else {
        gat1_batch<8>(i0, end, endm1, wsh, eslot, h1u, dp, a0, a1, a2, a3, den);
        // tail in 8-capacity chunks (deg > 16)
        for (int base = i0 + 16; base < end; base += 8)
            gat1_batch<4>(base, end, endm1, wsh, eslot, h1u, dp, a0, a1, a2, a3, den);
    }

    // combine the two slots within the wave
    a0 += __shfl_xor(a0, 32, 64);
    a1 += __shfl_xor(a1, 32, 64);
    a2 += __shfl_xor(a2, 32, 64);
    a3 += __shfl_xor(a3, 32, 64);
    den += __shfl_xor(den, 32, 64);

    if (lane < 32) {
        float inv = 1.f / (den + 1e-16f);
        float4 bv = *(const float4*)(b1 + 4 * dp);
        float o0 = fmaxf(fmaf(a0, inv, bv.x), 0.f);
        float o1 = fmaxf(fmaf(a1, inv, bv.y), 0.f);
        float o2 = fmaxf(fmaf(a2, inv, bv.z), 0.f);
        float o3 = fmaxf(fmaf(a3, inv, bv.w), 0.f);
        uint2 o;
        o.x = ((unsigned int)f2b(o1) << 16) | f2b(o0);
        o.y = ((unsigned int)f2b(o3) << 16) | f2b(o2);
        g1b[((unsigned int)v << 5) | dp] = o;
    }
}

// ---------------- gat2 projection (MFMA): h2 = g1b @ W2; fused a_s2/a_d2 ----------------
__global__ __launch_bounds__(256) void gat2_proj_kernel(
    const unsigned short* __restrict__ g1b, const short* __restrict__ w2t,
    const float* __restrict__ as2w, const float* __restrict__ ad2w,
    float* __restrict__ h2, float* __restrict__ a_s2, float* __restrict__ a_d2, int N)
{
    const int tid = threadIdx.x;
    const int wave = tid >> 6, lane = tid & 63;
    const int q = lane >> 4, col = lane & 15;
    const int mb = blockIdx.x * 64 + wave * 16;
    const int arow = min(mb + col, N - 1);
    const short* ap = (const short*)g1b + (size_t)arow * 128 + q * 8;
    const short* bp = w2t + (size_t)col * 128 + q * 8;

    f32x4 acc = {0.f, 0.f, 0.f, 0.f};
    #pragma unroll
    for (int ks = 0; ks < 4; ks++)
        acc = __builtin_amdgcn_mfma_f32_16x16x32_bf16(
            *(const bf16x8*)(ap + ks * 32), *(const bf16x8*)(bp + ks * 32), acc, 0, 0, 0);

    const float asj = as2w[col], adj = ad2w[col];
    #pragma unroll
    for (int i = 0; i < 4; i++) {
        int row = mb + q * 4 + i;
        float ps = acc[i] * asj, pd = acc[i] * adj;
        #pragma unroll
        for (int off = 1; off < 16; off <<= 1) {
            ps += __shfl_xor(ps, off, 16);
            pd += __shfl_xor(pd, off, 16);
        }
        if (row < N) {
            h2[(size_t)row * 16 + col] = acc[i];
            if (col == 0) { a_s2[row] = ps; a_d2[row] = pd; }
        }
    }
}

// ---------------- layer-2 gather (masked): 4 nodes/block, 4 slots x 16 dims, MLP-8 prefetch ----------------
__global__ __launch_bounds__(256) void gat2_gather_kernel(
    const int* __restrict__ rowptr, const uint2* __restrict__ eslot,
    const float* __restrict__ h2,
    const float* __restrict__ a_s2, const float* __restrict__ a_d2,
    const float* __restrict__ b2, const int* __restrict__ mask,
    float* __restrict__ g2m, int M)
{
    const int tid = threadIdx.x;
    const int m = blockIdx.x * 4 + (tid >> 6);
    if (m >= M) return;
    const int lane = tid & 63, slot = lane >> 4, c = lane & 15;
    const int v = mask[m];
    const float adv = a_d2[v];
    const int beg = rowptr[v], end = rowptr[v + 1];
    const int i0 = beg + slot;

    float acc = 0.f, den = 0.f;
    unsigned int idxs[8];
    float msk[8], as_[8], hval[8];
    #pragma unroll
    for (int k = 0; k < 8; k++) {
        int i = i0 + 4 * k;
        int ic = min(i, end - 1);
        idxs[k] = eslot[ic].x;
        msk[k] = (i < end) ? 1.f : 0.f;
    }
    #pragma unroll
    for (int k = 0; k < 8; k++) as_[k] = a_s2[idxs[k]];
    #pragma unroll
    for (int k = 0; k < 8; k++) hval[k] = h2[(idxs[k] << 4) | (unsigned)c];
    #pragma unroll
    for (int k = 0; k < 8; k++) {
        float e = as_[k] + adv;
        float w = msk[k] * __expf(e > 0.f ? e : 0.2f * e);
        den += w;
        acc = fmaf(w, hval[k], acc);
    }
    for (int i = i0 + 32; i < end; i += 4) {
        unsigned int src = eslot[i].x;
        float e = a_s2[src] + adv;
        float w = __expf(e > 0.f ? e : 0.2f * e);
        den += w;
        acc = fmaf(w, h2[(src << 4) | (unsigned)c], acc);
    }

    acc += __shfl_xor(acc, 16, 64);
    acc += __shfl_xor(acc, 32, 64);
    den += __shfl_xor(den, 16, 64);
    den += __shfl_xor(den, 32, 64);
    if (slot == 0) g2m[(size_t)m * 16 + c] = acc / (den + 1e-16f) + b2[c];
}

// ---------------- fused head ----------------
__global__ __launch_bounds__(64) void final_kernel(
    const float* __restrict__ text_out, const float* __restrict__ g2m,
    const float* __restrict__ fcf_w, const float* __restrict__ fcf_b,
    float* __restrict__ out, int M)
{
    const int lane = threadIdx.x;
    const int g = lane >> 4, j = lane & 15;
    const int m = blockIdx.x * 4 + g;
    if (m >= M) return;

    float tval = text_out[(size_t)m * 16 + j];
    float gval = g2m[(size_t)m * 16 + j];

    float logit = fcf_b[j];
    #pragma unroll
    for (int k = 0; k < 16; k++) {
        logit = fmaf(__shfl(tval, k, 16), fcf_w[k * 16 + j], logit);
        logit = fmaf(__shfl(gval, k, 16), fcf_w[(16 + k) * 16 + j], logit);
    }
    float mx = logit;
    #pragma unroll
    for (int off = 8; off > 0; off >>= 1) mx = fmaxf(mx, __shfl_xor(mx, off, 16));
    float se = expf(logit - mx);
    #pragma unroll
    for (int off = 8; off > 0; off >>= 1) se += __shfl_xor(se, off, 16);
    out[(size_t)m * 16 + j] = logit - mx - logf(se);
}

extern "C" void kernel_launch(void* const* d_in, const int* in_sizes, int n_in,
                              void* d_out, int out_size, void* d_ws, size_t ws_size,
                              hipStream_t stream)
{
    const float* text  = (const float*)d_in[0];
    const float* x     = (const float*)d_in[1];
    const int*   ei    = (const int*)  d_in[2];
    const int*   mask  = (const int*)  d_in[3];
    const float* fc1_w = (const float*)d_in[4];  const float* fc1_b = (const float*)d_in[5];
    const float* fc2_w = (const float*)d_in[6];  const float* fc2_b = (const float*)d_in[7];
    const float* fc3_w = (const float*)d_in[8];  const float* fc3_b = (const float*)d_in[9];
    const float* fc4_w = (const float*)d_in[10]; const float* fc4_b = (const float*)d_in[11];
    const float* sc_w  = (const float*)d_in[12]; const float* sc_b  = (const float*)d_in[13];
    const float* W1    = (const float*)d_in[14];
    const float* as1w  = (const float*)d_in[15]; const float* ad1w  = (const float*)d_in[16];
    const float* b1    = (const float*)d_in[17];
    const float* W2    = (const float*)d_in[18];
    const float* as2w  = (const float*)d_in[19]; const float* ad2w  = (const float*)d_in[20];
    const float* b2    = (const float*)d_in[21];
    const float* fcf_w = (const float*)d_in[22]; const float* fcf_b = (const float*)d_in[23];

    const int M  = in_sizes[3];
    const int N  = in_sizes[1] / GNN_DIM;
    const int E  = in_sizes[2] / 2;
    const int EP = E + N;
    const int* esrc = ei;
    const int* edst = ei + E;

    const int Mp = ((M + 63) / 64) * 64;
    const int Np = ((N + 63) / 64) * 64;
    const int NB = (N + 255) / 256;        // <= 256

    float* ws = (float*)d_ws;
    size_t off = 0;
    auto alloc = [&](size_t n) { float* p = ws + off; off += (n + 63) & ~size_t(63); return p; };

    unsigned short* h1    = (unsigned short*)alloc((size_t)Np * 64);   // bf16 [Np x 128]
    unsigned int*   g1b   = (unsigned int*)  alloc((size_t)N * 64);    // bf16 [N x 128] packed
    unsigned short* w1cat = (unsigned short*)alloc(144 * 256);         // bf16 [144 x 512]
    unsigned short* w1g   = (unsigned short*)alloc(128 * 64);          // bf16 [128 x 128]
    unsigned short* w2t   = (unsigned short*)alloc(16 * 64);           // bf16 [16 x 128]
    float* t1       = alloc((size_t)M * 128);
    float* tsc      = alloc((size_t)M * 16);
    float* a_s1     = alloc((size_t)2 * N);
    float* a_d1     = alloc((size_t)2 * N);
    float* h2       = alloc((size_t)N * 16);
    float* a_s2     = alloc(N);
    float* a_d2     = alloc(N);
    float* text_out = alloc((size_t)M * 16);
    float* g2m      = alloc((size_t)M * 16);
    uint2* eslot    = (uint2*)alloc((size_t)2 * EP);   // {src, bf16w0|bf16w1<<16}
    int* deg        = (int*)alloc((size_t)N * 32);     // padded: 1 counter / 128B
    int* rank       = (int*)alloc(E);
    int* rowptr     = (int*)alloc(N + 1);
    int* bsum       = (int*)alloc(256);

    // --- CSR build: histogram(+rank, padded counters) -> hierarchical scan ---
    hipMemsetAsync(deg, 0, (size_t)N * 32 * sizeof(int), stream);
    deg_hist_kernel<<<(E + 1023) / 1024, 256, 0, stream>>>(edst, deg, rank, E);
    part_kernel<<<NB, 256, 0, stream>>>(deg, bsum, N);
    scan_bsums_kernel<<<1, 256, 0, stream>>>(bsum, NB);
    rowptr_kernel<<<NB, 256, 0, stream>>>(deg, bsum, rowptr, N);

    // --- weights to bf16 ---
    conv_w_kernel<<<(144 * 512 + 128 * 128 + 16 * 128 + 255) / 256, 256, 0, stream>>>(
        fc1_w, sc_w, W1, W2, w1cat, w1g, w2t);

    // --- GAT1 projection (produces a_s1/a_d1 for weight fill) ---
    gemm_h1_kernel<<<Np / 64, 256, 0, stream>>>(
        x, (const short*)w1g, as1w, ad1w, h1, a_s1, a_d1, N);

    // --- CSR fill: single 8B slot per edge, no atomics ---
    fillw_kernel<<<(E + N + 255) / 256, 256, 0, stream>>>(
        esrc, edst, rank, rowptr, eslot, a_s1, a_d1, E, N);

    // --- text branch ---
    gemm_text_kernel<<<Mp / 64, 256, 0, stream>>>(
        text, (const short*)w1cat, fc1_b, sc_b, t1, tsc, M);
    text_tail_kernel<<<(M + 7) / 8, 128, 0, stream>>>(
        t1, tsc, fc2_w, fc2_b, fc3_w, fc3_b, fc4_w, fc4_b, text_out, M);

    // --- GNN aggregation / second layer ---
    gat1_gather_kernel<<<(N + 3) / 4, 256, 0, stream>>>(
        rowptr, eslot, (const uint2*)h1, b1, (uint2*)g1b, N);

    gat2_proj_kernel<<<Np / 64, 256, 0, stream>>>(
        (const unsigned short*)g1b, (const short*)w2t, as2w, ad2w, h2, a_s2, a_d2, N);

    gat2_gather_kernel<<<(M + 3) / 4, 256, 0, stream>>>(
        rowptr, eslot, h2, a_s2, a_d2, b2, mask, g2m, M);

    final_kernel<<<(M + 3) / 4, 64, 0, stream>>>(
        text_out, g2m, fcf_w, fcf_b, (float*)d_out, M);
}

// Round 11
// 199.211 us; speedup vs baseline: 3.5079x; 1.0064x over previous
//
#include <hip/hip_runtime.h>
#include <hip/hip_bf16.h>
#include <cmath>

#define TEXTD 500
#define GNN_DIM 128
#define DEGP(v) ((v) << 5)   // one counter per 128B line

typedef __attribute__((ext_vector_type(8))) short bf16x8;
typedef __attribute__((ext_vector_type(4))) float f32x4;

__device__ __forceinline__ float bf2f(unsigned short u) {
    union { unsigned int i; float f; } cv;
    cv.i = ((unsigned int)u) << 16;
    return cv.f;
}
__device__ __forceinline__ unsigned short f2b(float x) {
    __hip_bfloat16 b = __float2bfloat16(x);
    return *reinterpret_cast<unsigned short*>(&b);
}
__device__ __forceinline__ float u2f(unsigned int u) {
    union { unsigned int i; float f; } cv; cv.i = u; return cv.f;
}
// convert 8 consecutive floats at p (16B-aligned) to a bf16x8 fragment
__device__ __forceinline__ bf16x8 cvt8(const float* p) {
    float4 u = *(const float4*)p;
    float4 v = *(const float4*)(p + 4);
    bf16x8 f;
    f[0] = (short)f2b(u.x); f[1] = (short)f2b(u.y);
    f[2] = (short)f2b(u.z); f[3] = (short)f2b(u.w);
    f[4] = (short)f2b(v.x); f[5] = (short)f2b(v.y);
    f[6] = (short)f2b(v.z); f[7] = (short)f2b(v.w);
    return f;
}

// ---------------- weight conversion: w1cat [144x512], w1g [128x128], w2t [16x128] ----------------
__global__ __launch_bounds__(256) void conv_w_kernel(
    const float* __restrict__ fc1_w, const float* __restrict__ sc_w,
    const float* __restrict__ W1, const float* __restrict__ W2,
    unsigned short* __restrict__ w1cat, unsigned short* __restrict__ w1g,
    unsigned short* __restrict__ w2t)
{
    int idx = blockIdx.x * 256 + threadIdx.x;
    if (idx < 144 * 512) {
        int n = idx >> 9, k = idx & 511;
        float v = 0.f;
        if (k < TEXTD) v = (n < 128) ? fc1_w[k * 128 + n] : sc_w[k * 16 + (n - 128)];
        w1cat[idx] = f2b(v);
    } else if (idx < 144 * 512 + 128 * 128) {
        int j = idx - 144 * 512;
        int n = j >> 7, k = j & 127;
        w1g[j] = f2b(W1[k * 128 + n]);
    } else if (idx < 144 * 512 + 128 * 128 + 16 * 128) {
        int j = idx - (144 * 512 + 128 * 128);
        int n = j >> 7, k = j & 127;
        w2t[j] = f2b(W2[k * 16 + n]);
    }
}

// ---------------- GEMM1: text[fp32, Mx500] x w1cat[144x512]^T -> t1(relu+b), tsc(+b) ----------------
__global__ __launch_bounds__(256) void gemm_text_kernel(
    const float* __restrict__ text, const short* __restrict__ B,
    const float* __restrict__ fc1_b, const float* __restrict__ sc_b,
    float* __restrict__ t1, float* __restrict__ tsc, int M)
{
    const int tid = threadIdx.x;
    const int wave = tid >> 6, lane = tid & 63;
    const int q = lane >> 4, col = lane & 15;
    const int mb = blockIdx.x * 64 + wave * 16;
    const int arow = min(mb + col, M - 1);
    const float* ap = text + (size_t)arow * TEXTD + q * 8;

    bf16x8 afrag[16];
    #pragma unroll
    for (int ks = 0; ks < 15; ks++) afrag[ks] = cvt8(ap + ks * 32);
    {   // ks = 15: K 480..511, zero-pad past 500
        bf16x8 f;
        int k0 = 480 + q * 8;
        #pragma unroll
        for (int e = 0; e < 8; e++) {
            int k = k0 + e;
            f[e] = (short)((k < TEXTD) ? f2b(text[(size_t)arow * TEXTD + k]) : 0);
        }
        afrag[15] = f;
    }

    for (int nb = 0; nb < 9; nb++) {
        const short* bp = B + (size_t)(nb * 16 + col) * 512 + q * 8;
        f32x4 acc = {0.f, 0.f, 0.f, 0.f};
        #pragma unroll
        for (int ks = 0; ks < 16; ks++)
            acc = __builtin_amdgcn_mfma_f32_16x16x32_bf16(afrag[ks], *(const bf16x8*)(bp + ks * 32), acc, 0, 0, 0);
        #pragma unroll
        for (int i = 0; i < 4; i++) {
            int row = mb + q * 4 + i;
            if (row < M) {
                if (nb < 8) t1[(size_t)row * 128 + nb * 16 + col] = fmaxf(acc[i] + fc1_b[nb * 16 + col], 0.f);
                else        tsc[(size_t)row * 16 + col] = acc[i] + sc_b[col];
            }
        }
    }
}

// ---------------- GEMM2: x[fp32, Nx128] @ W1 -> h1 bf16; fused a_s1/a_d1 epilogue ----------------
__global__ __launch_bounds__(256) void gemm_h1_kernel(
    const float* __restrict__ x, const short* __restrict__ B,
    const float* __restrict__ as1w, const float* __restrict__ ad1w,
    unsigned short* __restrict__ h1, float* __restrict__ a_s, float* __restrict__ a_d, int N)
{
    const int tid = threadIdx.x;
    const int wave = tid >> 6, lane = tid & 63;
    const int q = lane >> 4, col = lane & 15;
    const int mb = blockIdx.x * 64 + wave * 16;
    const int arow = min(mb + col, N - 1);
    const float* ap = x + (size_t)arow * 128 + q * 8;

    bf16x8 afrag[4];
    #pragma unroll
    for (int ks = 0; ks < 4; ks++) afrag[ks] = cvt8(ap + ks * 32);

    float ps0[4] = {0,0,0,0}, ps1[4] = {0,0,0,0};
    float pd0[4] = {0,0,0,0}, pd1[4] = {0,0,0,0};

    #pragma unroll
    for (int nb = 0; nb < 8; nb++) {
        const short* bp = B + (size_t)(nb * 16 + col) * 128 + q * 8;
        f32x4 acc = {0.f, 0.f, 0.f, 0.f};
        #pragma unroll
        for (int ks = 0; ks < 4; ks++)
            acc = __builtin_amdgcn_mfma_f32_16x16x32_bf16(afrag[ks], *(const bf16x8*)(bp + ks * 32), acc, 0, 0, 0);
        const int j = nb * 16 + col;
        const float asj = as1w[j], adj = ad1w[j];
        #pragma unroll
        for (int i = 0; i < 4; i++) {
            int row = mb + q * 4 + i;
            if (row < N) h1[(size_t)row * 128 + j] = f2b(acc[i]);
            if (nb < 4) { ps0[i] = fmaf(acc[i], asj, ps0[i]); pd0[i] = fmaf(acc[i], adj, pd0[i]); }
            else        { ps1[i] = fmaf(acc[i], asj, ps1[i]); pd1[i] = fmaf(acc[i], adj, pd1[i]); }
        }
    }
    #pragma unroll
    for (int i = 0; i < 4; i++) {
        float v0 = ps0[i], v1 = ps1[i], w0 = pd0[i], w1 = pd1[i];
        #pragma unroll
        for (int off = 1; off < 16; off <<= 1) {
            v0 += __shfl_xor(v0, off, 16);
            v1 += __shfl_xor(v1, off, 16);
            w0 += __shfl_xor(w0, off, 16);
            w1 += __shfl_xor(w1, off, 16);
        }
        int row = mb + q * 4 + i;
        if (col == 0 && row < N) {
            a_s[2 * row] = v0; a_s[2 * row + 1] = v1;
            a_d[2 * row] = w0; a_d[2 * row + 1] = w1;
        }
    }
}

// ---------------- text tail: fc2/fc3/fc4 + shortcut ----------------
__global__ __launch_bounds__(128) void text_tail_kernel(
    const float* __restrict__ t1g, const float* __restrict__ tsc,
    const float* __restrict__ fc2_w, const float* __restrict__ fc2_b,
    const float* __restrict__ fc3_w, const float* __restrict__ fc3_b,
    const float* __restrict__ fc4_w, const float* __restrict__ fc4_b,
    float* __restrict__ text_out, int M)
{
    __shared__ float t1[8][128];
    __shared__ float t2[8][64];
    __shared__ float t3[8][16];
    const int tid = threadIdx.x;
    const int m0 = blockIdx.x * 8;

    for (int r = 0; r < 8; r++) {
        int row = m0 + r;
        t1[r][tid] = (row < M) ? t1g[(size_t)row * 128 + tid] : 0.f;
    }
    __syncthreads();

    const int r2 = tid >> 6, c2 = tid & 63;
    for (int rb = 0; rb < 4; rb++) {
        int row = rb * 2 + r2;
        float a2 = fc2_b[c2];
        for (int k = 0; k < 128; k++) a2 = fmaf(t1[row][k], fc2_w[k * 64 + c2], a2);
        t2[row][c2] = fmaxf(a2, 0.f);
    }
    __syncthreads();

    const int rs = tid >> 4, cs = tid & 15;
    float a3 = fc3_b[cs];
    for (int k = 0; k < 64; k++) a3 = fmaf(t2[rs][k], fc3_w[k * 16 + cs], a3);
    t3[rs][cs] = fmaxf(a3, 0.f);
    __syncthreads();

    float a4 = fc4_b[cs];
    #pragma unroll
    for (int k = 0; k < 16; k++) a4 = fmaf(t3[rs][k], fc4_w[k * 16 + cs], a4);
    int row = m0 + rs;
    if (row < M) text_out[(size_t)row * 16 + cs] = a4 + tsc[(size_t)row * 16 + cs];
}

// ---------------- CSR build ----------------
// zero only the used (padded) counter slots: one 4B store per 128B line
__global__ __launch_bounds__(256) void zero_deg_kernel(int* __restrict__ deg, int N)
{
    int v = blockIdx.x * 256 + threadIdx.x;
    if (v < N) deg[DEGP(v)] = 0;
}

// histogram (padded counters, 1/128B line) + per-edge rank; 4 edges/thread for MLP
__global__ __launch_bounds__(256) void deg_hist_kernel(
    const int* __restrict__ edst, int* __restrict__ deg, int* __restrict__ rank, int E)
{
    const int base = blockIdx.x * 1024 + threadIdx.x;
    int e0 = base;
    int e1 = base + 256;
    int e2 = base + 512;
    int e3 = base + 768;
    int d0 = (e0 < E) ? edst[e0] : -1;
    int d1 = (e1 < E) ? edst[e1] : -1;
    int d2 = (e2 < E) ? edst[e2] : -1;
    int d3 = (e3 < E) ? edst[e3] : -1;
    int r0 = (d0 >= 0) ? atomicAdd(&deg[DEGP(d0)], 1) : 0;
    int r1 = (d1 >= 0) ? atomicAdd(&deg[DEGP(d1)], 1) : 0;
    int r2 = (d2 >= 0) ? atomicAdd(&deg[DEGP(d2)], 1) : 0;
    int r3 = (d3 >= 0) ? atomicAdd(&deg[DEGP(d3)], 1) : 0;
    if (d0 >= 0) rank[e0] = r0;
    if (d1 >= 0) rank[e1] = r1;
    if (d2 >= 0) rank[e2] = r2;
    if (d3 >= 0) rank[e3] = r3;
}

// phase 1: per-256-tile sums of (deg[i]+1)
__global__ __launch_bounds__(256) void part_kernel(
    const int* __restrict__ deg, int* __restrict__ bsum, int N)
{
    const int tid = threadIdx.x;
    int i = blockIdx.x * 256 + tid;
    int d = (i < N) ? deg[DEGP(i)] + 1 : 0;
    #pragma unroll
    for (int off = 32; off > 0; off >>= 1) d += __shfl_down(d, off, 64);
    __shared__ int wsum[4];
    if ((tid & 63) == 0) wsum[tid >> 6] = d;
    __syncthreads();
    if (tid == 0) bsum[blockIdx.x] = wsum[0] + wsum[1] + wsum[2] + wsum[3];
}

// phase 2: exclusive scan of block sums (NB <= 256)
__global__ __launch_bounds__(256) void scan_bsums_kernel(
    int* __restrict__ bsum, int NB)
{
    __shared__ int sc[256];
    const int tid = threadIdx.x;
    int v = (tid < NB) ? bsum[tid] : 0;
    sc[tid] = v;
    for (int off = 1; off < 256; off <<= 1) {
        __syncthreads();
        int t = (tid >= off) ? sc[tid - off] : 0;
        __syncthreads();
        sc[tid] += t;
    }
    __syncthreads();
    if (tid < NB) bsum[tid] = sc[tid] - v;   // exclusive
}

// phase 3: in-block scan + offset -> rowptr
__global__ __launch_bounds__(256) void rowptr_kernel(
    const int* __restrict__ deg, const int* __restrict__ bsum,
    int* __restrict__ rowptr, int N)
{
    __shared__ int sc[256];
    const int tid = threadIdx.x;
    const int i = blockIdx.x * 256 + tid;
    int d = (i < N) ? deg[DEGP(i)] + 1 : 0;
    sc[tid] = d;
    for (int off = 1; off < 256; off <<= 1) {
        __syncthreads();
        int t = (tid >= off) ? sc[tid - off] : 0;
        __syncthreads();
        sc[tid] += t;
    }
    __syncthreads();
    int incl = sc[tid];
    int base = bsum[blockIdx.x];
    if (i < N) rowptr[i] = base + incl - d;
    if (i == N - 1) rowptr[N] = base + incl;
}

__device__ __forceinline__ float edge_w(float e) {
    return __expf(e > 0.f ? e : 0.2f * e);
}

// fill CSR slots: single 8B store per edge {src, bf16 w0 | w1<<16}; no atomics
__global__ __launch_bounds__(256) void fillw_kernel(
    const int* __restrict__ esrc, const int* __restrict__ edst,
    const int* __restrict__ rank, const int* __restrict__ rowptr,
    uint2* __restrict__ eslot,
    const float* __restrict__ a_s, const float* __restrict__ a_d, int E, int N)
{
    int e = blockIdx.x * 256 + threadIdx.x;
    if (e < E) {
        int src = esrc[e], dst = edst[e];
        int pos = rowptr[dst] + 1 + rank[e];
        float2 as = *(const float2*)(a_s + 2 * src);
        float2 ad = *(const float2*)(a_d + 2 * dst);
        unsigned int w0 = f2b(edge_w(as.x + ad.x));
        unsigned int w1 = f2b(edge_w(as.y + ad.y));
        uint2 o; o.x = (unsigned int)src; o.y = (w1 << 16) | w0;
        eslot[pos] = o;
    } else if (e < E + N) {
        int v = e - E;
        float2 as = *(const float2*)(a_s + 2 * v);
        float2 ad = *(const float2*)(a_d + 2 * v);
        unsigned int w0 = f2b(edge_w(as.x + ad.x));
        unsigned int w1 = f2b(edge_w(as.y + ad.y));
        uint2 o; o.x = (unsigned int)v; o.y = (w1 << 16) | w0;
        eslot[rowptr[v]] = o;
    }
}

// ---------------- layer-1 gather: 1 WAVE/node (4 nodes/block), 2 slots x 32 lanes(x4 dims) ----------------
template<int B>
__device__ __forceinline__ void gat1_batch(
    int i0, int end, int endm1, int wsh,
    const uint2* __restrict__ eslot, const uint2* __restrict__ h1u, unsigned int dp,
    float& a0, float& a1, float& a2, float& a3, float& den)
{
    int ics[B];
    uint2 sl[B];
    float wv[B];
    uint2 hv[B];
    #pragma unroll
    for (int k = 0; k < B; k++) ics[k] = min(i0 + 2 * k, endm1);
    #pragma unroll
    for (int k = 0; k < B; k++) sl[k] = eslot[ics[k]];
    #pragma unroll
    for (int k = 0; k < B; k++) {
        float w = u2f((sl[k].y << wsh) & 0xffff0000u);
        wv[k] = (i0 + 2 * k < end) ? w : 0.f;
    }
    #pragma unroll
    for (int k = 0; k < B; k++) hv[k] = h1u[(sl[k].x << 5) | dp];
    #pragma unroll
    for (int k = 0; k < B; k++) {
        float w = wv[k];
        den += w;
        a0 = fmaf(w, u2f(hv[k].x << 16),          a0);
        a1 = fmaf(w, u2f(hv[k].x & 0xffff0000u),  a1);
        a2 = fmaf(w, u2f(hv[k].y << 16),          a2);
        a3 = fmaf(w, u2f(hv[k].y & 0xffff0000u),  a3);
    }
}

__global__ __launch_bounds__(256) void gat1_gather_kernel(
    const int* __restrict__ rowptr, const uint2* __restrict__ eslot,
    const uint2* __restrict__ h1u,
    const float* __restrict__ b1, uint2* __restrict__ g1b, int N)
{
    const int v = blockIdx.x * 4 + (threadIdx.x >> 6);
    if (v >= N) return;
    const int lane = threadIdx.x & 63;
    const int slot = lane >> 5;                // 0..1
    const unsigned int dp = lane & 31;         // dims 4dp..4dp+3
    const int head = dp >> 4;
    const int wsh = head ? 0 : 16;             // bf16 weight unpack shift
    const int beg = rowptr[v], end = rowptr[v + 1];
    const int deg = end - beg;
    const int endm1 = end - 1;
    const int i0 = beg + slot;

    float a0 = 0.f, a1 = 0.f, a2 = 0.f, a3 = 0.f, den = 0.f;

    if (deg <= 8) {
        gat1_batch<4>(i0, end, endm1, wsh, eslot, h1u, dp, a0, a1, a2, a3, den);
    } else {
        gat1_batch<8>(i0, end, endm1, wsh, eslot, h1u, dp, a0, a1, a2, a3, den);
        // tail in 8-capacity chunks (deg > 16)
        for (int base = i0 + 16; base < end; base += 8)
            gat1_batch<4>(base, end, endm1, wsh, eslot, h1u, dp, a0, a1, a2, a3, den);
    }

    // combine the two slots within the wave
    a0 += __shfl_xor(a0, 32, 64);
    a1 += __shfl_xor(a1, 32, 64);
    a2 += __shfl_xor(a2, 32, 64);
    a3 += __shfl_xor(a3, 32, 64);
    den += __shfl_xor(den, 32, 64);

    if (lane < 32) {
        float inv = 1.f / (den + 1e-16f);
        float4 bv = *(const float4*)(b1 + 4 * dp);
        float o0 = fmaxf(fmaf(a0, inv, bv.x), 0.f);
        float o1 = fmaxf(fmaf(a1, inv, bv.y), 0.f);
        float o2 = fmaxf(fmaf(a2, inv, bv.z), 0.f);
        float o3 = fmaxf(fmaf(a3, inv, bv.w), 0.f);
        uint2 o;
        o.x = ((unsigned int)f2b(o1) << 16) | f2b(o0);
        o.y = ((unsigned int)f2b(o3) << 16) | f2b(o2);
        g1b[((unsigned int)v << 5) | dp] = o;
    }
}

// ---------------- gat2 projection (MFMA): h2 = g1b @ W2; fused a_s2/a_d2 ----------------
__global__ __launch_bounds__(256) void gat2_proj_kernel(
    const unsigned short* __restrict__ g1b, const short* __restrict__ w2t,
    const float* __restrict__ as2w, const float* __restrict__ ad2w,
    float* __restrict__ h2, float* __restrict__ a_s2, float* __restrict__ a_d2, int N)
{
    const int tid = threadIdx.x;
    const int wave = tid >> 6, lane = tid & 63;
    const int q = lane >> 4, col = lane & 15;
    const int mb = blockIdx.x * 64 + wave * 16;
    const int arow = min(mb + col, N - 1);
    const short* ap = (const short*)g1b + (size_t)arow * 128 + q * 8;
    const short* bp = w2t + (size_t)col * 128 + q * 8;

    f32x4 acc = {0.f, 0.f, 0.f, 0.f};
    #pragma unroll
    for (int ks = 0; ks < 4; ks++)
        acc = __builtin_amdgcn_mfma_f32_16x16x32_bf16(
            *(const bf16x8*)(ap + ks * 32), *(const bf16x8*)(bp + ks * 32), acc, 0, 0, 0);

    const float asj = as2w[col], adj = ad2w[col];
    #pragma unroll
    for (int i = 0; i < 4; i++) {
        int row = mb + q * 4 + i;
        float ps = acc[i] * asj, pd = acc[i] * adj;
        #pragma unroll
        for (int off = 1; off < 16; off <<= 1) {
            ps += __shfl_xor(ps, off, 16);
            pd += __shfl_xor(pd, off, 16);
        }
        if (row < N) {
            h2[(size_t)row * 16 + col] = acc[i];
            if (col == 0) { a_s2[row] = ps; a_d2[row] = pd; }
        }
    }
}

// ---------------- layer-2 gather (masked): 4 nodes/block, 4 slots x 16 dims, MLP-8 prefetch ----------------
__global__ __launch_bounds__(256) void gat2_gather_kernel(
    const int* __restrict__ rowptr, const uint2* __restrict__ eslot,
    const float* __restrict__ h2,
    const float* __restrict__ a_s2, const float* __restrict__ a_d2,
    const float* __restrict__ b2, const int* __restrict__ mask,
    float* __restrict__ g2m, int M)
{
    const int tid = threadIdx.x;
    const int m = blockIdx.x * 4 + (tid >> 6);
    if (m >= M) return;
    const int lane = tid & 63, slot = lane >> 4, c = lane & 15;
    const int v = mask[m];
    const float adv = a_d2[v];
    const int beg = rowptr[v], end = rowptr[v + 1];
    const int i0 = beg + slot;

    float acc = 0.f, den = 0.f;
    unsigned int idxs[8];
    float msk[8], as_[8], hval[8];
    #pragma unroll
    for (int k = 0; k < 8; k++) {
        int i = i0 + 4 * k;
        int ic = min(i, end - 1);
        idxs[k] = eslot[ic].x;
        msk[k] = (i < end) ? 1.f : 0.f;
    }
    #pragma unroll
    for (int k = 0; k < 8; k++) as_[k] = a_s2[idxs[k]];
    #pragma unroll
    for (int k = 0; k < 8; k++) hval[k] = h2[(idxs[k] << 4) | (unsigned)c];
    #pragma unroll
    for (int k = 0; k < 8; k++) {
        float e = as_[k] + adv;
        float w = msk[k] * __expf(e > 0.f ? e : 0.2f * e);
        den += w;
        acc = fmaf(w, hval[k], acc);
    }
    for (int i = i0 + 32; i < end; i += 4) {
        unsigned int src = eslot[i].x;
        float e = a_s2[src] + adv;
        float w = __expf(e > 0.f ? e : 0.2f * e);
        den += w;
        acc = fmaf(w, h2[(src << 4) | (unsigned)c], acc);
    }

    acc += __shfl_xor(acc, 16, 64);
    acc += __shfl_xor(acc, 32, 64);
    den += __shfl_xor(den, 16, 64);
    den += __shfl_xor(den, 32, 64);
    if (slot == 0) g2m[(size_t)m * 16 + c] = acc / (den + 1e-16f) + b2[c];
}

// ---------------- fused head ----------------
__global__ __launch_bounds__(64) void final_kernel(
    const float* __restrict__ text_out, const float* __restrict__ g2m,
    const float* __restrict__ fcf_w, const float* __restrict__ fcf_b,
    float* __restrict__ out, int M)
{
    const int lane = threadIdx.x;
    const int g = lane >> 4, j = lane & 15;
    const int m = blockIdx.x * 4 + g;
    if (m >= M) return;

    float tval = text_out[(size_t)m * 16 + j];
    float gval = g2m[(size_t)m * 16 + j];

    float logit = fcf_b[j];
    #pragma unroll
    for (int k = 0; k < 16; k++) {
        logit = fmaf(__shfl(tval, k, 16), fcf_w[k * 16 + j], logit);
        logit = fmaf(__shfl(gval, k, 16), fcf_w[(16 + k) * 16 + j], logit);
    }
    float mx = logit;
    #pragma unroll
    for (int off = 8; off > 0; off >>= 1) mx = fmaxf(mx, __shfl_xor(mx, off, 16));
    float se = expf(logit - mx);
    #pragma unroll
    for (int off = 8; off > 0; off >>= 1) se += __shfl_xor(se, off, 16);
    out[(size_t)m * 16 + j] = logit - mx - logf(se);
}

extern "C" void kernel_launch(void* const* d_in, const int* in_sizes, int n_in,
                              void* d_out, int out_size, void* d_ws, size_t ws_size,
                              hipStream_t stream)
{
    const float* text  = (const float*)d_in[0];
    const float* x     = (const float*)d_in[1];
    const int*   ei    = (const int*)  d_in[2];
    const int*   mask  = (const int*)  d_in[3];
    const float* fc1_w = (const float*)d_in[4];  const float* fc1_b = (const float*)d_in[5];
    const float* fc2_w = (const float*)d_in[6];  const float* fc2_b = (const float*)d_in[7];
    const float* fc3_w = (const float*)d_in[8];  const float* fc3_b = (const float*)d_in[9];
    const float* fc4_w = (const float*)d_in[10]; const float* fc4_b = (const float*)d_in[11];
    const float* sc_w  = (const float*)d_in[12]; const float* sc_b  = (const float*)d_in[13];
    const float* W1    = (const float*)d_in[14];
    const float* as1w  = (const float*)d_in[15]; const float* ad1w  = (const float*)d_in[16];
    const float* b1    = (const float*)d_in[17];
    const float* W2    = (const float*)d_in[18];
    const float* as2w  = (const float*)d_in[19]; const float* ad2w  = (const float*)d_in[20];
    const float* b2    = (const float*)d_in[21];
    const float* fcf_w = (const float*)d_in[22]; const float* fcf_b = (const float*)d_in[23];

    const int M  = in_sizes[3];
    const int N  = in_sizes[1] / GNN_DIM;
    const int E  = in_sizes[2] / 2;
    const int EP = E + N;
    const int* esrc = ei;
    const int* edst = ei + E;

    const int Mp = ((M + 63) / 64) * 64;
    const int Np = ((N + 63) / 64) * 64;
    const int NB = (N + 255) / 256;        // <= 256

    float* ws = (float*)d_ws;
    size_t off = 0;
    auto alloc = [&](size_t n) { float* p = ws + off; off += (n + 63) & ~size_t(63); return p; };

    unsigned short* h1    = (unsigned short*)alloc((size_t)Np * 64);   // bf16 [Np x 128]
    unsigned int*   g1b   = (unsigned int*)  alloc((size_t)N * 64);    // bf16 [N x 128] packed
    unsigned short* w1cat = (unsigned short*)alloc(144 * 256);         // bf16 [144 x 512]
    unsigned short* w1g   = (unsigned short*)alloc(128 * 64);          // bf16 [128 x 128]
    unsigned short* w2t   = (unsigned short*)alloc(16 * 64);           // bf16 [16 x 128]
    float* t1       = alloc((size_t)M * 128);
    float* tsc      = alloc((size_t)M * 16);
    float* a_s1     = alloc((size_t)2 * N);
    float* a_d1     = alloc((size_t)2 * N);
    float* h2       = alloc((size_t)N * 16);
    float* a_s2     = alloc(N);
    float* a_d2     = alloc(N);
    float* text_out = alloc((size_t)M * 16);
    float* g2m      = alloc((size_t)M * 16);
    uint2* eslot    = (uint2*)alloc((size_t)2 * EP);   // {src, bf16w0|bf16w1<<16}
    int* deg        = (int*)alloc((size_t)N * 32);     // padded: 1 counter / 128B
    int* rank       = (int*)alloc(E);
    int* rowptr     = (int*)alloc(N + 1);
    int* bsum       = (int*)alloc(256);

    // --- CSR build: zero used counters -> histogram(+rank) -> hierarchical scan ---
    zero_deg_kernel<<<NB, 256, 0, stream>>>(deg, N);
    deg_hist_kernel<<<(E + 1023) / 1024, 256, 0, stream>>>(edst, deg, rank, E);
    part_kernel<<<NB, 256, 0, stream>>>(deg, bsum, N);
    scan_bsums_kernel<<<1, 256, 0, stream>>>(bsum, NB);
    rowptr_kernel<<<NB, 256, 0, stream>>>(deg, bsum, rowptr, N);

    // --- weights to bf16 ---
    conv_w_kernel<<<(144 * 512 + 128 * 128 + 16 * 128 + 255) / 256, 256, 0, stream>>>(
        fc1_w, sc_w, W1, W2, w1cat, w1g, w2t);

    // --- GAT1 projection (produces a_s1/a_d1 for weight fill) ---
    gemm_h1_kernel<<<Np / 64, 256, 0, stream>>>(
        x, (const short*)w1g, as1w, ad1w, h1, a_s1, a_d1, N);

    // --- CSR fill: single 8B slot per edge, no atomics ---
    fillw_kernel<<<(E + N + 255) / 256, 256, 0, stream>>>(
        esrc, edst, rank, rowptr, eslot, a_s1, a_d1, E, N);

    // --- text branch ---
    gemm_text_kernel<<<Mp / 64, 256, 0, stream>>>(
        text, (const short*)w1cat, fc1_b, sc_b, t1, tsc, M);
    text_tail_kernel<<<(M + 7) / 8, 128, 0, stream>>>(
        t1, tsc, fc2_w, fc2_b, fc3_w, fc3_b, fc4_w, fc4_b, text_out, M);

    // --- GNN aggregation / second layer ---
    gat1_gather_kernel<<<(N + 3) / 4, 256, 0, stream>>>(
        rowptr, eslot, (const uint2*)h1, b1, (uint2*)g1b, N);

    gat2_proj_kernel<<<Np / 64, 256, 0, stream>>>(
        (const unsigned short*)g1b, (const short*)w2t, as2w, ad2w, h2, a_s2, a_d2, N);

    gat2_gather_kernel<<<(M + 3) / 4, 256, 0, stream>>>(
        rowptr, eslot, h2, a_s2, a_d2, b2, mask, g2m, M);

    final_kernel<<<(M + 3) / 4, 64, 0, stream>>>(
        text_out, g2m, fcf_w, fcf_b, (float*)d_out, M);
}

// Round 12
// 189.277 us; speedup vs baseline: 3.6920x; 1.0525x over previous
//
#include <hip/hip_runtime.h>
#include <hip/hip_bf16.h>
#include <cmath>

#define TEXTD 500
#define GNN_DIM 128
#define DEGP(v) ((v) << 5)   // one counter per 128B line

typedef __attribute__((ext_vector_type(8))) short bf16x8;
typedef __attribute__((ext_vector_type(4))) float f32x4;

__device__ __forceinline__ float bf2f(unsigned short u) {
    union { unsigned int i; float f; } cv;
    cv.i = ((unsigned int)u) << 16;
    return cv.f;
}
__device__ __forceinline__ unsigned short f2b(float x) {
    __hip_bfloat16 b = __float2bfloat16(x);
    return *reinterpret_cast<unsigned short*>(&b);
}
__device__ __forceinline__ float u2f(unsigned int u) {
    union { unsigned int i; float f; } cv; cv.i = u; return cv.f;
}
__device__ __forceinline__ bf16x8 cvt8(const float* p) {
    float4 u = *(const float4*)p;
    float4 v = *(const float4*)(p + 4);
    bf16x8 f;
    f[0] = (short)f2b(u.x); f[1] = (short)f2b(u.y);
    f[2] = (short)f2b(u.z); f[3] = (short)f2b(u.w);
    f[4] = (short)f2b(v.x); f[5] = (short)f2b(v.y);
    f[6] = (short)f2b(v.z); f[7] = (short)f2b(v.w);
    return f;
}

// ---------------- setup: zero padded deg counters + weight conversion ----------------
__global__ __launch_bounds__(256) void setup_kernel(
    int* __restrict__ deg, int N, int NB,
    const float* __restrict__ fc1_w, const float* __restrict__ sc_w,
    const float* __restrict__ W1, const float* __restrict__ W2,
    unsigned short* __restrict__ w1cat, unsigned short* __restrict__ w1g,
    unsigned short* __restrict__ w2t)
{
    if ((int)blockIdx.x < NB) {
        int v = blockIdx.x * 256 + threadIdx.x;
        if (v < N) deg[DEGP(v)] = 0;
        return;
    }
    int idx = (blockIdx.x - NB) * 256 + threadIdx.x;
    if (idx < 144 * 512) {
        int n = idx >> 9, k = idx & 511;
        float v = 0.f;
        if (k < TEXTD) v = (n < 128) ? fc1_w[k * 128 + n] : sc_w[k * 16 + (n - 128)];
        w1cat[idx] = f2b(v);
    } else if (idx < 144 * 512 + 128 * 128) {
        int j = idx - 144 * 512;
        int n = j >> 7, k = j & 127;
        w1g[j] = f2b(W1[k * 128 + n]);
    } else if (idx < 144 * 512 + 128 * 128 + 16 * 128) {
        int j = idx - (144 * 512 + 128 * 128);
        int n = j >> 7, k = j & 127;
        w2t[j] = f2b(W2[k * 16 + n]);
    }
}

// ---------------- fused text branch: MFMA fc1+shortcut, then fc2/3/4 in-LDS ----------------
__global__ __launch_bounds__(256) void text_fused_kernel(
    const float* __restrict__ text, const short* __restrict__ B,
    const float* __restrict__ fc1_b, const float* __restrict__ sc_b,
    const float* __restrict__ fc2_w, const float* __restrict__ fc2_b,
    const float* __restrict__ fc3_w, const float* __restrict__ fc3_b,
    const float* __restrict__ fc4_w, const float* __restrict__ fc4_b,
    float* __restrict__ text_out, int M)
{
    __shared__ float t1s[64][128];
    __shared__ float tscs[64][16];
    __shared__ float t2s[64][64];
    __shared__ float t3s[64][16];

    const int tid = threadIdx.x;
    const int wave = tid >> 6, lane = tid & 63;
    const int q = lane >> 4, col = lane & 15;
    const int mb = blockIdx.x * 64;
    const int rbase = wave * 16;
    const int arow = min(mb + rbase + col, M - 1);
    const float* ap = text + (size_t)arow * TEXTD + q * 8;

    bf16x8 afrag[16];
    #pragma unroll
    for (int ks = 0; ks < 15; ks++) afrag[ks] = cvt8(ap + ks * 32);
    {   // K 480..511, zero-pad past 500
        bf16x8 f;
        int k0 = 480 + q * 8;
        #pragma unroll
        for (int e = 0; e < 8; e++) {
            int k = k0 + e;
            f[e] = (short)((k < TEXTD) ? f2b(text[(size_t)arow * TEXTD + k]) : 0);
        }
        afrag[15] = f;
    }

    for (int nb = 0; nb < 9; nb++) {
        const short* bp = B + (size_t)(nb * 16 + col) * 512 + q * 8;
        f32x4 acc = {0.f, 0.f, 0.f, 0.f};
        #pragma unroll
        for (int ks = 0; ks < 16; ks++)
            acc = __builtin_amdgcn_mfma_f32_16x16x32_bf16(afrag[ks], *(const bf16x8*)(bp + ks * 32), acc, 0, 0, 0);
        #pragma unroll
        for (int i = 0; i < 4; i++) {
            int rl = rbase + q * 4 + i;
            if (nb < 8) t1s[rl][nb * 16 + col] = fmaxf(acc[i] + fc1_b[nb * 16 + col], 0.f);
            else        tscs[rl][col] = acc[i] + sc_b[col];
        }
    }
    __syncthreads();

    // fc2: 64 rows x 64 cols; thread -> col2 = tid&63, rows rgrp2, rgrp2+4, ...
    const int c2 = tid & 63, rg2 = tid >> 6;
    for (int rb = 0; rb < 16; rb++) {
        int row = rb * 4 + rg2;
        float a2 = fc2_b[c2];
        for (int k = 0; k < 128; k++) a2 = fmaf(t1s[row][k], fc2_w[k * 64 + c2], a2);
        t2s[row][c2] = fmaxf(a2, 0.f);
    }
    __syncthreads();

    // fc3: 64 rows x 16 cols; thread -> cs = tid&15, rows rg3, rg3+16, rg3+32, rg3+48
    const int cs = tid & 15, rg3 = tid >> 4;
    for (int rb = 0; rb < 4; rb++) {
        int row = rb * 16 + rg3;
        float a3 = fc3_b[cs];
        for (int k = 0; k < 64; k++) a3 = fmaf(t2s[row][k], fc3_w[k * 16 + cs], a3);
        t3s[row][cs] = fmaxf(a3, 0.f);
    }
    __syncthreads();

    // fc4 + shortcut + store
    for (int rb = 0; rb < 4; rb++) {
        int row = rb * 16 + rg3;
        float a4 = fc4_b[cs];
        #pragma unroll
        for (int k = 0; k < 16; k++) a4 = fmaf(t3s[row][k], fc4_w[k * 16 + cs], a4);
        int rg = mb + row;
        if (rg < M) text_out[(size_t)rg * 16 + cs] = a4 + tscs[row][cs];
    }
}

// ---------------- GEMM2: x[fp32, Nx128] @ W1 -> h1 bf16; fused a_s1/a_d1 epilogue ----------------
__global__ __launch_bounds__(256) void gemm_h1_kernel(
    const float* __restrict__ x, const short* __restrict__ B,
    const float* __restrict__ as1w, const float* __restrict__ ad1w,
    unsigned short* __restrict__ h1, float* __restrict__ a_s, float* __restrict__ a_d, int N)
{
    const int tid = threadIdx.x;
    const int wave = tid >> 6, lane = tid & 63;
    const int q = lane >> 4, col = lane & 15;
    const int mb = blockIdx.x * 64 + wave * 16;
    const int arow = min(mb + col, N - 1);
    const float* ap = x + (size_t)arow * 128 + q * 8;

    bf16x8 afrag[4];
    #pragma unroll
    for (int ks = 0; ks < 4; ks++) afrag[ks] = cvt8(ap + ks * 32);

    float ps0[4] = {0,0,0,0}, ps1[4] = {0,0,0,0};
    float pd0[4] = {0,0,0,0}, pd1[4] = {0,0,0,0};

    #pragma unroll
    for (int nb = 0; nb < 8; nb++) {
        const short* bp = B + (size_t)(nb * 16 + col) * 128 + q * 8;
        f32x4 acc = {0.f, 0.f, 0.f, 0.f};
        #pragma unroll
        for (int ks = 0; ks < 4; ks++)
            acc = __builtin_amdgcn_mfma_f32_16x16x32_bf16(afrag[ks], *(const bf16x8*)(bp + ks * 32), acc, 0, 0, 0);
        const int j = nb * 16 + col;
        const float asj = as1w[j], adj = ad1w[j];
        #pragma unroll
        for (int i = 0; i < 4; i++) {
            int row = mb + q * 4 + i;
            if (row < N) h1[(size_t)row * 128 + j] = f2b(acc[i]);
            if (nb < 4) { ps0[i] = fmaf(acc[i], asj, ps0[i]); pd0[i] = fmaf(acc[i], adj, pd0[i]); }
            else        { ps1[i] = fmaf(acc[i], asj, ps1[i]); pd1[i] = fmaf(acc[i], adj, pd1[i]); }
        }
    }
    #pragma unroll
    for (int i = 0; i < 4; i++) {
        float v0 = ps0[i], v1 = ps1[i], w0 = pd0[i], w1 = pd1[i];
        #pragma unroll
        for (int off = 1; off < 16; off <<= 1) {
            v0 += __shfl_xor(v0, off, 16);
            v1 += __shfl_xor(v1, off, 16);
            w0 += __shfl_xor(w0, off, 16);
            w1 += __shfl_xor(w1, off, 16);
        }
        int row = mb + q * 4 + i;
        if (col == 0 && row < N) {
            a_s[2 * row] = v0; a_s[2 * row + 1] = v1;
            a_d[2 * row] = w0; a_d[2 * row + 1] = w1;
        }
    }
}

// ---------------- CSR build ----------------
__global__ __launch_bounds__(256) void deg_hist_kernel(
    const int* __restrict__ edst, int* __restrict__ deg, int* __restrict__ rank, int E)
{
    const int base = blockIdx.x * 1024 + threadIdx.x;
    int e0 = base;
    int e1 = base + 256;
    int e2 = base + 512;
    int e3 = base + 768;
    int d0 = (e0 < E) ? edst[e0] : -1;
    int d1 = (e1 < E) ? edst[e1] : -1;
    int d2 = (e2 < E) ? edst[e2] : -1;
    int d3 = (e3 < E) ? edst[e3] : -1;
    int r0 = (d0 >= 0) ? atomicAdd(&deg[DEGP(d0)], 1) : 0;
    int r1 = (d1 >= 0) ? atomicAdd(&deg[DEGP(d1)], 1) : 0;
    int r2 = (d2 >= 0) ? atomicAdd(&deg[DEGP(d2)], 1) : 0;
    int r3 = (d3 >= 0) ? atomicAdd(&deg[DEGP(d3)], 1) : 0;
    if (d0 >= 0) rank[e0] = r0;
    if (d1 >= 0) rank[e1] = r1;
    if (d2 >= 0) rank[e2] = r2;
    if (d3 >= 0) rank[e3] = r3;
}

// phase 1: per-256-tile sums of (deg[i]+1)
__global__ __launch_bounds__(256) void part_kernel(
    const int* __restrict__ deg, int* __restrict__ bsum, int N)
{
    const int tid = threadIdx.x;
    int i = blockIdx.x * 256 + tid;
    int d = (i < N) ? deg[DEGP(i)] + 1 : 0;
    #pragma unroll
    for (int off = 32; off > 0; off >>= 1) d += __shfl_down(d, off, 64);
    __shared__ int wsum[4];
    if ((tid & 63) == 0) wsum[tid >> 6] = d;
    __syncthreads();
    if (tid == 0) bsum[blockIdx.x] = wsum[0] + wsum[1] + wsum[2] + wsum[3];
}

// phase 2 (fused): each block scans bsum in LDS, then in-block element scan -> rowptr
__global__ __launch_bounds__(256) void rowptr_kernel(
    const int* __restrict__ deg, const int* __restrict__ bsum,
    int* __restrict__ rowptr, int N, int NB)
{
    __shared__ int bsc[256];
    __shared__ int sc[256];
    const int tid = threadIdx.x;

    // scan block sums (inclusive)
    int bv = (tid < NB) ? bsum[tid] : 0;
    bsc[tid] = bv;
    for (int off = 1; off < 256; off <<= 1) {
        __syncthreads();
        int t = (tid >= off) ? bsc[tid - off] : 0;
        __syncthreads();
        bsc[tid] += t;
    }
    __syncthreads();
    const int base = (blockIdx.x == 0) ? 0 : bsc[blockIdx.x - 1];

    const int i = blockIdx.x * 256 + tid;
    int d = (i < N) ? deg[DEGP(i)] + 1 : 0;
    sc[tid] = d;
    for (int off = 1; off < 256; off <<= 1) {
        __syncthreads();
        int t = (tid >= off) ? sc[tid - off] : 0;
        __syncthreads();
        sc[tid] += t;
    }
    __syncthreads();
    int incl = sc[tid];
    if (i < N) rowptr[i] = base + incl - d;
    if (i == N - 1) rowptr[N] = base + incl;
}

__device__ __forceinline__ float edge_w(float e) {
    return __expf(e > 0.f ? e : 0.2f * e);
}

// fill CSR slots: single 8B store per edge {src, bf16 w0 | w1<<16}; no atomics
__global__ __launch_bounds__(256) void fillw_kernel(
    const int* __restrict__ esrc, const int* __restrict__ edst,
    const int* __restrict__ rank, const int* __restrict__ rowptr,
    uint2* __restrict__ eslot,
    const float* __restrict__ a_s, const float* __restrict__ a_d, int E, int N)
{
    int e = blockIdx.x * 256 + threadIdx.x;
    if (e < E) {
        int src = esrc[e], dst = edst[e];
        int pos = rowptr[dst] + 1 + rank[e];
        float2 as = *(const float2*)(a_s + 2 * src);
        float2 ad = *(const float2*)(a_d + 2 * dst);
        unsigned int w0 = f2b(edge_w(as.x + ad.x));
        unsigned int w1 = f2b(edge_w(as.y + ad.y));
        uint2 o; o.x = (unsigned int)src; o.y = (w1 << 16) | w0;
        eslot[pos] = o;
    } else if (e < E + N) {
        int v = e - E;
        float2 as = *(const float2*)(a_s + 2 * v);
        float2 ad = *(const float2*)(a_d + 2 * v);
        unsigned int w0 = f2b(edge_w(as.x + ad.x));
        unsigned int w1 = f2b(edge_w(as.y + ad.y));
        uint2 o; o.x = (unsigned int)v; o.y = (w1 << 16) | w0;
        eslot[rowptr[v]] = o;
    }
}

// ---------------- layer-1 gather: 1 WAVE/node (4 nodes/block), 2 slots x 32 lanes(x4 dims) ----------------
template<int B>
__device__ __forceinline__ void gat1_batch(
    int i0, int end, int endm1, int wsh,
    const uint2* __restrict__ eslot, const uint2* __restrict__ h1u, unsigned int dp,
    float& a0, float& a1, float& a2, float& a3, float& den)
{
    int ics[B];
    uint2 sl[B];
    float wv[B];
    uint2 hv[B];
    #pragma unroll
    for (int k = 0; k < B; k++) ics[k] = min(i0 + 2 * k, endm1);
    #pragma unroll
    for (int k = 0; k < B; k++) sl[k] = eslot[ics[k]];
    #pragma unroll
    for (int k = 0; k < B; k++) {
        float w = u2f((sl[k].y << wsh) & 0xffff0000u);
        wv[k] = (i0 + 2 * k < end) ? w : 0.f;
    }
    #pragma unroll
    for (int k = 0; k < B; k++) hv[k] = h1u[(sl[k].x << 5) | dp];
    #pragma unroll
    for (int k = 0; k < B; k++) {
        float w = wv[k];
        den += w;
        a0 = fmaf(w, u2f(hv[k].x << 16),          a0);
        a1 = fmaf(w, u2f(hv[k].x & 0xffff0000u),  a1);
        a2 = fmaf(w, u2f(hv[k].y << 16),          a2);
        a3 = fmaf(w, u2f(hv[k].y & 0xffff0000u),  a3);
    }
}

__global__ __launch_bounds__(256) void gat1_gather_kernel(
    const int* __restrict__ rowptr, const uint2* __restrict__ eslot,
    const uint2* __restrict__ h1u,
    const float* __restrict__ b1, uint2* __restrict__ g1b, int N)
{
    const int v = blockIdx.x * 4 + (threadIdx.x >> 6);
    if (v >= N) return;
    const int lane = threadIdx.x & 63;
    const int slot = lane >> 5;                // 0..1
    const unsigned int dp = lane & 31;         // dims 4dp..4dp+3
    const int head = dp >> 4;
    const int wsh = head ? 0 : 16;             // bf16 weight unpack shift
    const int beg = rowptr[v], end = rowptr[v + 1];
    const int deg = end - beg;
    const int endm1 = end - 1;
    const int i0 = beg + slot;

    float a0 = 0.f, a1 = 0.f, a2 = 0.f, a3 = 0.f, den = 0.f;

    if (deg <= 8) {
        gat1_batch<4>(i0, end, endm1, wsh, eslot, h1u, dp, a0, a1, a2, a3, den);
    } else {
        gat1_batch<8>(i0, end, endm1, wsh, eslot, h1u, dp, a0, a1, a2, a3, den);
        for (int base = i0 + 16; base < end; base += 8)
            gat1_batch<4>(base, end, endm1, wsh, eslot, h1u, dp, a0, a1, a2, a3, den);
    }

    a0 += __shfl_xor(a0, 32, 64);
    a1 += __shfl_xor(a1, 32, 64);
    a2 += __shfl_xor(a2, 32, 64);
    a3 += __shfl_xor(a3, 32, 64);
    den += __shfl_xor(den, 32, 64);

    if (lane < 32) {
        float inv = 1.f / (den + 1e-16f);
        float4 bv = *(const float4*)(b1 + 4 * dp);
        float o0 = fmaxf(fmaf(a0, inv, bv.x), 0.f);
        float o1 = fmaxf(fmaf(a1, inv, bv.y), 0.f);
        float o2 = fmaxf(fmaf(a2, inv, bv.z), 0.f);
        float o3 = fmaxf(fmaf(a3, inv, bv.w), 0.f);
        uint2 o;
        o.x = ((unsigned int)f2b(o1) << 16) | f2b(o0);
        o.y = ((unsigned int)f2b(o3) << 16) | f2b(o2);
        g1b[((unsigned int)v << 5) | dp] = o;
    }
}

// ---------------- gat2 projection (MFMA): h2 = g1b @ W2; fused a_s2/a_d2 ----------------
__global__ __launch_bounds__(256) void gat2_proj_kernel(
    const unsigned short* __restrict__ g1b, const short* __restrict__ w2t,
    const float* __restrict__ as2w, const float* __restrict__ ad2w,
    float* __restrict__ h2, float* __restrict__ a_s2, float* __restrict__ a_d2, int N)
{
    const int tid = threadIdx.x;
    const int wave = tid >> 6, lane = tid & 63;
    const int q = lane >> 4, col = lane & 15;
    const int mb = blockIdx.x * 64 + wave * 16;
    const int arow = min(mb + col, N - 1);
    const short* ap = (const short*)g1b + (size_t)arow * 128 + q * 8;
    const short* bp = w2t + (size_t)col * 128 + q * 8;

    f32x4 acc = {0.f, 0.f, 0.f, 0.f};
    #pragma unroll
    for (int ks = 0; ks < 4; ks++)
        acc = __builtin_amdgcn_mfma_f32_16x16x32_bf16(
            *(const bf16x8*)(ap + ks * 32), *(const bf16x8*)(bp + ks * 32), acc, 0, 0, 0);

    const float asj = as2w[col], adj = ad2w[col];
    #pragma unroll
    for (int i = 0; i < 4; i++) {
        int row = mb + q * 4 + i;
        float ps = acc[i] * asj, pd = acc[i] * adj;
        #pragma unroll
        for (int off = 1; off < 16; off <<= 1) {
            ps += __shfl_xor(ps, off, 16);
            pd += __shfl_xor(pd, off, 16);
        }
        if (row < N) {
            h2[(size_t)row * 16 + col] = acc[i];
            if (col == 0) { a_s2[row] = ps; a_d2[row] = pd; }
        }
    }
}

// ---------------- fused layer-2 gather + head (4 masked nodes/block) ----------------
__global__ __launch_bounds__(256) void gat2_final_kernel(
    const int* __restrict__ rowptr, const uint2* __restrict__ eslot,
    const float* __restrict__ h2,
    const float* __restrict__ a_s2, const float* __restrict__ a_d2,
    const float* __restrict__ b2, const int* __restrict__ mask,
    const float* __restrict__ text_out,
    const float* __restrict__ fcf_w, const float* __restrict__ fcf_b,
    float* __restrict__ out, int M)
{
    const int tid = threadIdx.x;
    const int m = blockIdx.x * 4 + (tid >> 6);
    if (m >= M) return;
    const int lane = tid & 63, slot = lane >> 4, c = lane & 15;
    const int v = mask[m];
    const float adv = a_d2[v];
    const int beg = rowptr[v], end = rowptr[v + 1];
    const int i0 = beg + slot;

    float acc = 0.f, den = 0.f;
    unsigned int idxs[8];
    float msk[8], as_[8], hval[8];
    #pragma unroll
    for (int k = 0; k < 8; k++) {
        int i = i0 + 4 * k;
        int ic = min(i, end - 1);
        idxs[k] = eslot[ic].x;
        msk[k] = (i < end) ? 1.f : 0.f;
    }
    #pragma unroll
    for (int k = 0; k < 8; k++) as_[k] = a_s2[idxs[k]];
    #pragma unroll
    for (int k = 0; k < 8; k++) hval[k] = h2[(idxs[k] << 4) | (unsigned)c];
    #pragma unroll
    for (int k = 0; k < 8; k++) {
        float e = as_[k] + adv;
        float w = msk[k] * __expf(e > 0.f ? e : 0.2f * e);
        den += w;
        acc = fmaf(w, hval[k], acc);
    }
    for (int i = i0 + 32; i < end; i += 4) {
        unsigned int src = eslot[i].x;
        float e = a_s2[src] + adv;
        float w = __expf(e > 0.f ? e : 0.2f * e);
        den += w;
        acc = fmaf(w, h2[(src << 4) | (unsigned)c], acc);
    }

    acc += __shfl_xor(acc, 16, 64);
    acc += __shfl_xor(acc, 32, 64);
    den += __shfl_xor(den, 16, 64);
    den += __shfl_xor(den, 32, 64);

    if (slot == 0) {
        float gval = acc / (den + 1e-16f) + b2[c];
        float tval = text_out[(size_t)m * 16 + c];

        float logit = fcf_b[c];
        #pragma unroll
        for (int k = 0; k < 16; k++) {
            logit = fmaf(__shfl(tval, k, 16), fcf_w[k * 16 + c], logit);
            logit = fmaf(__shfl(gval, k, 16), fcf_w[(16 + k) * 16 + c], logit);
        }
        float mx = logit;
        #pragma unroll
        for (int off = 8; off > 0; off >>= 1) mx = fmaxf(mx, __shfl_xor(mx, off, 16));
        float se = expf(logit - mx);
        #pragma unroll
        for (int off = 8; off > 0; off >>= 1) se += __shfl_xor(se, off, 16);
        out[(size_t)m * 16 + c] = logit - mx - logf(se);
    }
}

extern "C" void kernel_launch(void* const* d_in, const int* in_sizes, int n_in,
                              void* d_out, int out_size, void* d_ws, size_t ws_size,
                              hipStream_t stream)
{
    const float* text  = (const float*)d_in[0];
    const float* x     = (const float*)d_in[1];
    const int*   ei    = (const int*)  d_in[2];
    const int*   mask  = (const int*)  d_in[3];
    const float* fc1_w = (const float*)d_in[4];  const float* fc1_b = (const float*)d_in[5];
    const float* fc2_w = (const float*)d_in[6];  const float* fc2_b = (const float*)d_in[7];
    const float* fc3_w = (const float*)d_in[8];  const float* fc3_b = (const float*)d_in[9];
    const float* fc4_w = (const float*)d_in[10]; const float* fc4_b = (const float*)d_in[11];
    const float* sc_w  = (const float*)d_in[12]; const float* sc_b  = (const float*)d_in[13];
    const float* W1    = (const float*)d_in[14];
    const float* as1w  = (const float*)d_in[15]; const float* ad1w  = (const float*)d_in[16];
    const float* b1    = (const float*)d_in[17];
    const float* W2    = (const float*)d_in[18];
    const float* as2w  = (const float*)d_in[19]; const float* ad2w  = (const float*)d_in[20];
    const float* b2    = (const float*)d_in[21];
    const float* fcf_w = (const float*)d_in[22]; const float* fcf_b = (const float*)d_in[23];

    const int M  = in_sizes[3];
    const int N  = in_sizes[1] / GNN_DIM;
    const int E  = in_sizes[2] / 2;
    const int EP = E + N;
    const int* esrc = ei;
    const int* edst = ei + E;

    const int Mp = ((M + 63) / 64) * 64;
    const int Np = ((N + 63) / 64) * 64;
    const int NB = (N + 255) / 256;        // <= 256

    float* ws = (float*)d_ws;
    size_t off = 0;
    auto alloc = [&](size_t n) { float* p = ws + off; off += (n + 63) & ~size_t(63); return p; };

    unsigned short* h1    = (unsigned short*)alloc((size_t)Np * 64);   // bf16 [Np x 128]
    unsigned int*   g1b   = (unsigned int*)  alloc((size_t)N * 64);    // bf16 [N x 128] packed
    unsigned short* w1cat = (unsigned short*)alloc(144 * 256);         // bf16 [144 x 512]
    unsigned short* w1g   = (unsigned short*)alloc(128 * 64);          // bf16 [128 x 128]
    unsigned short* w2t   = (unsigned short*)alloc(16 * 64);           // bf16 [16 x 128]
    float* a_s1     = alloc((size_t)2 * N);
    float* a_d1     = alloc((size_t)2 * N);
    float* h2       = alloc((size_t)N * 16);
    float* a_s2     = alloc(N);
    float* a_d2     = alloc(N);
    float* text_out = alloc((size_t)M * 16);
    uint2* eslot    = (uint2*)alloc((size_t)2 * EP);   // {src, bf16w0|bf16w1<<16}
    int* deg        = (int*)alloc((size_t)N * 32);     // padded: 1 counter / 128B
    int* rank       = (int*)alloc(E);
    int* rowptr     = (int*)alloc(N + 1);
    int* bsum       = (int*)alloc(256);

    const int convBlocks = (144 * 512 + 128 * 128 + 16 * 128 + 255) / 256;

    // --- setup: zero counters + weights to bf16 (one kernel) ---
    setup_kernel<<<NB + convBlocks, 256, 0, stream>>>(
        deg, N, NB, fc1_w, sc_w, W1, W2, w1cat, w1g, w2t);

    // --- CSR: histogram(+rank) -> part sums -> rowptr (inline bsum scan) ---
    deg_hist_kernel<<<(E + 1023) / 1024, 256, 0, stream>>>(edst, deg, rank, E);
    part_kernel<<<NB, 256, 0, stream>>>(deg, bsum, N);
    rowptr_kernel<<<NB, 256, 0, stream>>>(deg, bsum, rowptr, N, NB);

    // --- GAT1 projection (produces a_s1/a_d1 for weight fill) ---
    gemm_h1_kernel<<<Np / 64, 256, 0, stream>>>(
        x, (const short*)w1g, as1w, ad1w, h1, a_s1, a_d1, N);

    // --- CSR fill: single 8B slot per edge, no atomics ---
    fillw_kernel<<<(E + N + 255) / 256, 256, 0, stream>>>(
        esrc, edst, rank, rowptr, eslot, a_s1, a_d1, E, N);

    // --- fused text branch ---
    text_fused_kernel<<<Mp / 64, 256, 0, stream>>>(
        text, (const short*)w1cat, fc1_b, sc_b,
        fc2_w, fc2_b, fc3_w, fc3_b, fc4_w, fc4_b, text_out, M);

    // --- GNN aggregation / second layer ---
    gat1_gather_kernel<<<(N + 3) / 4, 256, 0, stream>>>(
        rowptr, eslot, (const uint2*)h1, b1, (uint2*)g1b, N);

    gat2_proj_kernel<<<Np / 64, 256, 0, stream>>>(
        (const unsigned short*)g1b, (const short*)w2t, as2w, ad2w, h2, a_s2, a_d2, N);

    // --- fused layer-2 gather + head ---
    gat2_final_kernel<<<(M + 3) / 4, 256, 0, stream>>>(
        rowptr, eslot, h2, a_s2, a_d2, b2, mask, text_out, fcf_w, fcf_b,
        (float*)d_out, M);
}